// Round 10
// baseline (350.139 us; speedup 1.0000x reference)
//
#include <hip/hip_runtime.h>
#include <hip/hip_bf16.h>

#define B_    16
#define L_    1024
#define DM    384
#define DIP   1676
#define NIP   1664
#define DI    768
#define CONVD 896
#define NH    12
#define HD    64
#define DS    64
#define NCH   4
#define CH    256
#define EPS_  1e-5f

typedef unsigned short u16;
typedef unsigned int   u32;
typedef __attribute__((ext_vector_type(8))) short bf16x8;
typedef __attribute__((ext_vector_type(8))) _Float16 f16x8;
typedef __attribute__((ext_vector_type(4))) float f32x4;

union U4 { uint4 v; u16 s[8]; };

// byte offset of 16B slot `slot` in row `row` of a [64][64]-16bit LDS tile (128B rows, XOR swizzle)
#define SWZ(row, slot) (((row) << 7) + ((((slot) ^ ((row) & 7)) & 7) << 4))

// ---- bf16 split helpers (out_proj path) ----
__device__ __forceinline__ u16 f2b(float v) {
  u32 u = __float_as_uint(v);
  u32 r = (u + 0x7FFFu + ((u >> 16) & 1u)) >> 16;
  return (u16)r;
}
__device__ __forceinline__ float b2f(u16 h) { return __uint_as_float(((u32)h) << 16); }
__device__ __forceinline__ void bsplit(float v, u16& h, u16& l) {
  u16 hh = f2b(v);
  l = f2b(v - b2f(hh));
  h = hh;
}
// ---- fp16 split helpers ----
__device__ __forceinline__ u16 f2h(float v) { return __builtin_bit_cast(u16, (_Float16)v); }
__device__ __forceinline__ float h2f(u16 h) { return (float)__builtin_bit_cast(_Float16, h); }
__device__ __forceinline__ void hsplit(float v, u16& h, u16& l) {
  _Float16 hh = (_Float16)v;
  _Float16 ll = (_Float16)(v - (float)hh);
  h = __builtin_bit_cast(u16, hh);
  l = __builtin_bit_cast(u16, ll);
}

// ---------------- converters ----------------
__global__ __launch_bounds__(256) void k_cvtA(const float* __restrict__ u,
                                              u16* __restrict__ Ah, u16* __restrict__ Al)
{
  __shared__ float Ls[32][129];
  const int t  = threadIdx.x;
  const int l0 = blockIdx.x * 128;
  const int k0 = blockIdx.y * 32;
  const int b  = blockIdx.z;
#pragma unroll
  for (int r = 0; r < 4; ++r) {
    int idx = r * 256 + t;
    int kk = idx >> 5, q = idx & 31;
    float4 v = *(const float4*)&u[((size_t)(b * DM + k0 + kk)) * L_ + l0 + q * 4];
    Ls[kk][q * 4 + 0] = v.x; Ls[kk][q * 4 + 1] = v.y;
    Ls[kk][q * 4 + 2] = v.z; Ls[kk][q * 4 + 3] = v.w;
  }
  __syncthreads();
#pragma unroll
  for (int it = 0; it < 2; ++it) {
    int task = it * 256 + t;
    int l = task >> 2, kq = (task & 3) * 8;
    u32 hw[4], lw[4];
#pragma unroll
    for (int j = 0; j < 4; ++j) {
      u16 h0, l0v, h1, l1v;
      hsplit(Ls[kq + 2 * j + 0][l], h0, l0v);
      hsplit(Ls[kq + 2 * j + 1][l], h1, l1v);
      hw[j] = (u32)h0 | ((u32)h1 << 16);
      lw[j] = (u32)l0v | ((u32)l1v << 16);
    }
    size_t off = ((size_t)(b * L_ + l0 + l)) * DM + k0 + kq;
    *(uint4*)&Ah[off] = make_uint4(hw[0], hw[1], hw[2], hw[3]);
    *(uint4*)&Al[off] = make_uint4(lw[0], lw[1], lw[2], lw[3]);
  }
}

__global__ __launch_bounds__(256) void k_cvtWh(const float* __restrict__ W,
                                               u16* __restrict__ Wh, int total4)
{
  int i = blockIdx.x * 256 + threadIdx.x;
  if (i >= total4) return;
  int e = i * 4;
  float4 v = *(const float4*)&W[e];
  u16 h[4] = {f2h(v.x), f2h(v.y), f2h(v.z), f2h(v.w)};
  *(uint2*)&Wh[e] = make_uint2((u32)h[0] | ((u32)h[1] << 16), (u32)h[2] | ((u32)h[3] << 16));
}

__global__ __launch_bounds__(256) void k_cvtW(const float* __restrict__ W,
    u16* __restrict__ Wh, u16* __restrict__ Wl, int nsrc, int K, int total4)
{
  int i = blockIdx.x * 256 + threadIdx.x;
  if (i >= total4) return;
  int e = i * 4;
  int row = e / K;
  float4 v = make_float4(0.f, 0.f, 0.f, 0.f);
  if (row < nsrc) v = *(const float4*)&W[e];
  u16 h[4], l[4];
  bsplit(v.x, h[0], l[0]); bsplit(v.y, h[1], l[1]);
  bsplit(v.z, h[2], l[2]); bsplit(v.w, h[3], l[3]);
  *(uint2*)&Wh[e] = make_uint2((u32)h[0] | ((u32)h[1] << 16), (u32)h[2] | ((u32)h[3] << 16));
  *(uint2*)&Wl[e] = make_uint2((u32)l[0] | ((u32)l[1] << 16), (u32)l[2] | ((u32)l[3] << 16));
}

// ---------------- k_cvtX: x fp32 -> per-(bc,hh,jblk) [64p][64j] fp16 hi/lo tiles ----------------
__global__ __launch_bounds__(256) void k_cvtX(const float* __restrict__ x,
                                              u16* __restrict__ XTh, u16* __restrict__ XTl)
{
  __shared__ float xf2[64][65];
  const int t  = threadIdx.x;
  const int bc = blockIdx.x;
  const int jb = blockIdx.y;
  const int hh = blockIdx.z;
  const size_t rbase = (size_t)bc * 256 + jb * 64;
#pragma unroll
  for (int i = 0; i < 4; ++i) {
    int idx = i * 256 + t;
    int j = idx >> 4, p4 = (idx & 15) * 4;
    float4 v = *(const float4*)&x[(rbase + j) * DI + hh * HD + p4];
    xf2[p4 + 0][j] = v.x; xf2[p4 + 1][j] = v.y;
    xf2[p4 + 2][j] = v.z; xf2[p4 + 3][j] = v.w;
  }
  __syncthreads();
  const size_t tile = ((size_t)(bc * NH + hh) * 4 + jb) * 4096;
#pragma unroll
  for (int i = 0; i < 2; ++i) {
    int task = i * 256 + t;
    int p = task >> 3, jg = (task & 7) * 8;
    U4 H, L;
#pragma unroll
    for (int k = 0; k < 8; ++k) {
      u16 h, l; hsplit(xf2[p][jg + k], h, l);
      H.s[k] = h; L.s[k] = l;
    }
    *(uint4*)&XTh[tile + p * 64 + jg] = H.v;
    *(uint4*)&XTl[tile + p * 64 + jg] = L.v;
  }
}

// ---------------- K_dtp: dt logits from u (fp32) + softplus + chunk cumsum ----------------
__global__ __launch_bounds__(256) void k_dtp(
    const float* __restrict__ u, const float* __restrict__ ipw,
    const float* __restrict__ dtb, const float* __restrict__ A_log,
    float* __restrict__ dt, float* __restrict__ dAcs, float* __restrict__ cdecay)
{
  __shared__ float Ls[64][256];
  __shared__ float wdt[NH * DM];
  __shared__ float ws4[4];
  const int bc = blockIdx.x;
  const int b  = bc >> 2, l0 = (bc & 3) * 256;
  const int t  = threadIdx.x;
  const int lane = t & 63, w = t >> 6;
#pragma unroll
  for (int i = 0; i < 18; ++i) wdt[i * 256 + t] = ipw[(size_t)NIP * DM + i * 256 + t];
  float acc[NH] = {};
  for (int k0 = 0; k0 < DM; k0 += 64) {
    __syncthreads();
#pragma unroll
    for (int it = 0; it < 16; ++it) {
      int idx = it * 256 + t;
      int kk = idx >> 6, q4 = (idx & 63) * 4;
      *(float4*)&Ls[kk][q4] = *(const float4*)&u[((size_t)(b * DM + k0 + kk)) * L_ + l0 + q4];
    }
    __syncthreads();
    for (int k = 0; k < 64; ++k) {
      float uv = Ls[k][t];
#pragma unroll
      for (int h = 0; h < NH; ++h)
        acc[h] = fmaf(uv, wdt[h * DM + k0 + k], acc[h]);
    }
  }
  const size_t row = (size_t)bc * 256 + t;
#pragma unroll
  for (int h = 0; h < NH; ++h) {
    float logit = acc[h] + dtb[h];
    float dtv = (logit > 20.f) ? logit : log1pf(expf(logit));
    dt[row * NH + h] = dtv;
    float xv = dtv * (-expf(A_log[h]));
#pragma unroll
    for (int off = 1; off < 64; off <<= 1) {
      float y = __shfl_up(xv, off, 64);
      if (lane >= off) xv += y;
    }
    __syncthreads();
    if (lane == 63) ws4[w] = xv;
    __syncthreads();
    float add = 0.f;
#pragma unroll
    for (int i = 0; i < 4; ++i) if (i < w) add += ws4[i];
    xv += add;
    dAcs[row * NH + h] = xv;
    if (t == 255) cdecay[bc * NH + h] = expf(xv);
  }
}

// 3-stream staging (A-hi, A-lo, W) of one 128x32 u16 K-tile set
#define STAGE3(bufbase, k0) do {                                                                \
  _Pragma("unroll")                                                                             \
  for (int i_ = 0; i_ < 2; ++i_) {                                                              \
    int S_ = i_ * 256 + t;                                                                      \
    int m_ = S_ >> 2;                                                                           \
    int g_ = (S_ ^ (m_ >> 1)) & 3;                                                              \
    size_t goff_ = (size_t)m_ * DM + (k0) + g_ * 8;                                             \
    __builtin_amdgcn_global_load_lds((const __attribute__((address_space(1))) u32*)(g0 + goff_),\
        (__attribute__((address_space(3))) u32*)(lds + (bufbase) + S_ * 8), 16, 0, 0);          \
    __builtin_amdgcn_global_load_lds((const __attribute__((address_space(1))) u32*)(g1 + goff_),\
        (__attribute__((address_space(3))) u32*)(lds + (bufbase) + 4096 + S_ * 8), 16, 0, 0);   \
    __builtin_amdgcn_global_load_lds((const __attribute__((address_space(1))) u32*)(g2 + goff_),\
        (__attribute__((address_space(3))) u32*)(lds + (bufbase) + 8192 + S_ * 8), 16, 0, 0);   \
  }                                                                                             \
} while (0)

// ---------------- fp16x2 MFMA GEMM: in_proj ----------------
__global__ __launch_bounds__(256) void k_gemm1(
    const u16* __restrict__ Ah, const u16* __restrict__ Al,
    const u16* __restrict__ Wh,
    float* __restrict__ z, float* __restrict__ xBC)
{
  __shared__ u16 lds[24576];
  const int t = threadIdx.x;
  const int lane = t & 63, wid = t >> 6;
  const int wr = wid >> 1, wc = wid & 1;
  const int gg = lane >> 4, mlo = lane & 15;
  const int m0 = blockIdx.x * 128, n0 = blockIdx.y * 128;
  f32x4 acc[4][4];
#pragma unroll
  for (int i = 0; i < 4; ++i)
#pragma unroll
    for (int j = 0; j < 4; ++j) acc[i][j] = (f32x4){0.f, 0.f, 0.f, 0.f};
  const u16* g0 = Ah + (size_t)m0 * DM;
  const u16* g1 = Al + (size_t)m0 * DM;
  const u16* g2 = Wh + (size_t)n0 * DM;
  STAGE3(0, 0);
  __syncthreads();
  int cur = 0;
  for (int kt = 0; kt < DM / 32; ++kt) {
    if (kt + 1 < DM / 32) STAGE3((cur ^ 1) * 12288, (kt + 1) * 32);
    const char* ldsb = (const char*)lds + cur * 24576;
    f16x8 fa[4], fal[4], fb[4];
#pragma unroll
    for (int mf = 0; mf < 4; ++mf) {
      int m = wr * 64 + mf * 16 + mlo;
      int off = m * 64 + (((gg ^ (m >> 1)) & 3) << 4);
      fa[mf]  = *(const f16x8*)(ldsb + off);
      fal[mf] = *(const f16x8*)(ldsb + 8192 + off);
    }
#pragma unroll
    for (int nf = 0; nf < 4; ++nf) {
      int n = wc * 64 + nf * 16 + mlo;
      int off = n * 64 + (((gg ^ (n >> 1)) & 3) << 4);
      fb[nf]  = *(const f16x8*)(ldsb + 16384 + off);
    }
#pragma unroll
    for (int mf = 0; mf < 4; ++mf)
#pragma unroll
      for (int nf = 0; nf < 4; ++nf) {
        acc[mf][nf] = __builtin_amdgcn_mfma_f32_16x16x32_f16(fa[mf],  fb[nf], acc[mf][nf], 0, 0, 0);
        acc[mf][nf] = __builtin_amdgcn_mfma_f32_16x16x32_f16(fal[mf], fb[nf], acc[mf][nf], 0, 0, 0);
      }
    __syncthreads();
    cur ^= 1;
  }
  const int rb = m0 + wr * 64 + (lane >> 4) * 4;
  const int cb = n0 + wc * 64 + mlo;
#pragma unroll
  for (int mf = 0; mf < 4; ++mf)
#pragma unroll
    for (int nf = 0; nf < 4; ++nf) {
      int col = cb + nf * 16;
#pragma unroll
      for (int r = 0; r < 4; ++r) {
        int row = rb + mf * 16 + r;
        float v = acc[mf][nf][r];
        if (col < DI) z[(size_t)row * DI + col] = v;
        else xBC[(size_t)row * CONVD + (col - DI)] = v;
      }
    }
}

// 4-stream bf16 staging for gemm2
#define STAGE4(bufbase, k0, KS) do {                                                            \
  _Pragma("unroll")                                                                             \
  for (int i_ = 0; i_ < 2; ++i_) {                                                              \
    int S_ = i_ * 256 + t;                                                                      \
    int m_ = S_ >> 2;                                                                           \
    int g_ = (S_ ^ (m_ >> 1)) & 3;                                                              \
    size_t goff_ = (size_t)m_ * (KS) + (k0) + g_ * 8;                                           \
    __builtin_amdgcn_global_load_lds((const __attribute__((address_space(1))) u32*)(g0 + goff_),\
        (__attribute__((address_space(3))) u32*)(lds + (bufbase) + S_ * 8), 16, 0, 0);          \
    __builtin_amdgcn_global_load_lds((const __attribute__((address_space(1))) u32*)(g1 + goff_),\
        (__attribute__((address_space(3))) u32*)(lds + (bufbase) + 4096 + S_ * 8), 16, 0, 0);   \
    __builtin_amdgcn_global_load_lds((const __attribute__((address_space(1))) u32*)(g2 + goff_),\
        (__attribute__((address_space(3))) u32*)(lds + (bufbase) + 8192 + S_ * 8), 16, 0, 0);   \
    __builtin_amdgcn_global_load_lds((const __attribute__((address_space(1))) u32*)(g3 + goff_),\
        (__attribute__((address_space(3))) u32*)(lds + (bufbase) + 12288 + S_ * 8), 16, 0, 0);  \
  }                                                                                             \
} while (0)

// ---------------- bf16x3 MFMA GEMM: out_proj ----------------
__global__ __launch_bounds__(256) void k_gemm2(
    const u16* __restrict__ Ah, const u16* __restrict__ Al,
    const u16* __restrict__ Bh, const u16* __restrict__ Bl,
    float* __restrict__ out)
{
  __shared__ u16 lds[32768];
  const int t = threadIdx.x;
  const int lane = t & 63, wid = t >> 6;
  const int wr = wid >> 1, wc = wid & 1;
  const int gg = lane >> 4, mlo = lane & 15;
  const int m0 = blockIdx.x * 128, n0 = blockIdx.y * 128;
  f32x4 acc[4][4];
#pragma unroll
  for (int i = 0; i < 4; ++i)
#pragma unroll
    for (int j = 0; j < 4; ++j) acc[i][j] = (f32x4){0.f, 0.f, 0.f, 0.f};
  const u16* g0 = Ah + (size_t)m0 * DI;
  const u16* g1 = Al + (size_t)m0 * DI;
  const u16* g2 = Bh + (size_t)n0 * DI;
  const u16* g3 = Bl + (size_t)n0 * DI;
  STAGE4(0, 0, DI);
  __syncthreads();
  int cur = 0;
  for (int kt = 0; kt < DI / 32; ++kt) {
    if (kt + 1 < DI / 32) STAGE4((cur ^ 1) * 16384, (kt + 1) * 32, DI);
    const char* ldsb = (const char*)lds + cur * 32768;
    bf16x8 fa[4], fal[4], fb[4], fbl[4];
#pragma unroll
    for (int mf = 0; mf < 4; ++mf) {
      int m = wr * 64 + mf * 16 + mlo;
      int off = m * 64 + (((gg ^ (m >> 1)) & 3) << 4);
      fa[mf]  = *(const bf16x8*)(ldsb + off);
      fal[mf] = *(const bf16x8*)(ldsb + 8192 + off);
    }
#pragma unroll
    for (int nf = 0; nf < 4; ++nf) {
      int n = wc * 64 + nf * 16 + mlo;
      int off = n * 64 + (((gg ^ (n >> 1)) & 3) << 4);
      fb[nf]  = *(const bf16x8*)(ldsb + 16384 + off);
      fbl[nf] = *(const bf16x8*)(ldsb + 24576 + off);
    }
#pragma unroll
    for (int mf = 0; mf < 4; ++mf)
#pragma unroll
      for (int nf = 0; nf < 4; ++nf) {
        acc[mf][nf] = __builtin_amdgcn_mfma_f32_16x16x32_bf16(fa[mf],  fb[nf],  acc[mf][nf], 0, 0, 0);
        acc[mf][nf] = __builtin_amdgcn_mfma_f32_16x16x32_bf16(fa[mf],  fbl[nf], acc[mf][nf], 0, 0, 0);
        acc[mf][nf] = __builtin_amdgcn_mfma_f32_16x16x32_bf16(fal[mf], fb[nf],  acc[mf][nf], 0, 0, 0);
      }
    __syncthreads();
    cur ^= 1;
  }
  const int rb = m0 + wr * 64 + (lane >> 4) * 4;
  const int cb = n0 + wc * 64 + mlo;
#pragma unroll
  for (int mf = 0; mf < 4; ++mf)
#pragma unroll
    for (int nf = 0; nf < 4; ++nf) {
      int col = cb + nf * 16;
#pragma unroll
      for (int r = 0; r < 4; ++r) {
        int row = rb + mf * 16 + r;
        int b = row >> 10, l = row & 1023;
        out[((size_t)(b * DM + col)) * L_ + l] = acc[mf][nf][r];
      }
    }
}

// ---------------- K2: LDS-tiled depthwise conv; x fp32, B single fp16, C single fp16 ----------------
#define CC 16
__global__ __launch_bounds__(256) void k_conv(
    const float* __restrict__ xBC, const float* __restrict__ cw,
    const float* __restrict__ cb,
    float* __restrict__ x,
    u16* __restrict__ Bh,
    u16* __restrict__ Chh)
{
  __shared__ float Ls[18][32][CC];
  const int t  = threadIdx.x;
  const int c0 = blockIdx.x * CC;
  const int h0 = blockIdx.y * 16;
  const int b  = blockIdx.z;
#pragma unroll
  for (int k = 0; k < 9; ++k) {
    int f = k * 256 + t;
    int fc4 = f & 3, fw = (f >> 2) & 31, fr = f >> 7;
    int h = h0 + fr - 1;
    float4 v = make_float4(0.f, 0.f, 0.f, 0.f);
    if (h >= 0 && h < 32)
      v = *(const float4*)&xBC[((size_t)(b * 1024 + h * 32 + fw)) * CONVD + c0 + fc4 * 4];
    *(float4*)&Ls[fr][fw][fc4 * 4] = v;
  }
  const int c4 = t & 3;
  const int w  = (t >> 2) & 31;
  const int hb = t >> 7;
  float wt[4][9];
  float bias[4];
#pragma unroll
  for (int j = 0; j < 4; ++j) {
    int c = c0 + c4 * 4 + j;
    bias[j] = cb[c];
#pragma unroll
    for (int kb = 0; kb < 9; ++kb) wt[j][kb] = cw[c * 9 + kb];
  }
  __syncthreads();
#pragma unroll
  for (int k = 0; k < 8; ++k) {
    int h = hb * 8 + k;
    float acc[4] = {bias[0], bias[1], bias[2], bias[3]};
#pragma unroll
    for (int dh = 0; dh < 3; ++dh) {
#pragma unroll
      for (int dw = -1; dw <= 1; ++dw) {
        int ww = w + dw;
        if (ww < 0 || ww > 31) continue;
        const float* p = &Ls[h + dh][ww][c4 * 4];
        int kb = dh * 3 + (dw + 1);
#pragma unroll
        for (int j = 0; j < 4; ++j) acc[j] = fmaf(p[j], wt[j][kb], acc[j]);
      }
    }
    float s4[4];
#pragma unroll
    for (int j = 0; j < 4; ++j) { float v = acc[j]; s4[j] = v / (1.f + expf(-v)); }
    size_t row = (size_t)b * 1024 + (h0 + h) * 32 + w;
    int c = c0 + c4 * 4;
    if (c < DI) {
      *(float4*)&x[row * DI + c] = make_float4(s4[0], s4[1], s4[2], s4[3]);
    } else {
      u16 hv[4] = {f2h(s4[0]), f2h(s4[1]), f2h(s4[2]), f2h(s4[3])};
      uint2 hp = make_uint2((u32)hv[0] | ((u32)hv[1] << 16), (u32)hv[2] | ((u32)hv[3] << 16));
      if (c < DI + DS) *(uint2*)&Bh[row * DS + (c - DI)] = hp;
      else             *(uint2*)&Chh[row * DS + (c - DI - DS)] = hp;
    }
  }
}

// ---------------- K5: chunk states via MFMA; X frags direct from XT, w folded into B ----------------
__global__ __launch_bounds__(256) void k_states(
    const u16* __restrict__ XTh, const u16* __restrict__ XTl,
    const u16* __restrict__ Bh,
    const float* __restrict__ dt, const float* __restrict__ dAcs,
    float* __restrict__ states)
{
  __shared__ u32 bpack[64 * 65];
  __shared__ u16 BTh_t[4096];
  __shared__ float wall[256];
  const int bc = blockIdx.x;
  const int hh = blockIdx.y;
  const int t  = threadIdx.x;
  const int lane = t & 63, w = t >> 6;
  const int mlo = lane & 15, gg = lane >> 4;
  const int r = t >> 2, q = (t & 3) * 16;
  const size_t base = (size_t)bc * 256;
  const float last = dAcs[(base + 255) * NH + hh];
  wall[t] = expf(last - dAcs[(base + t) * NH + hh]) * dt[(base + t) * NH + hh];
  f32x4 acc[4];
#pragma unroll
  for (int i = 0; i < 4; ++i) acc[i] = (f32x4){0.f, 0.f, 0.f, 0.f};
  for (int jt = 0; jt < 4; ++jt) {
    const int j0 = jt * 64;
    __syncthreads();
    {
      const u16* bhp = &Bh[(size_t)(base + j0 + r) * DS + q];
      U4 H0, H1;
      H0.v = *(const uint4*)bhp; H1.v = *(const uint4*)(bhp + 8);
#pragma unroll
      for (int k = 0; k < 8; ++k) {
        bpack[r * 65 + q + k]     = H0.s[k];
        bpack[r * 65 + q + 8 + k] = H1.s[k];
      }
    }
    __syncthreads();
#pragma unroll
    for (int c = 0; c < 2; ++c) {
      U4 BH;
#pragma unroll
      for (int jj = 0; jj < 8; ++jj) {
        int j = q + c * 8 + jj;
        float bv = h2f((u16)bpack[j * 65 + r]) * wall[j0 + j];
        BH.s[jj] = f2h(bv);
      }
      *(uint4*)((char*)BTh_t + SWZ(r, (q >> 3) + c)) = BH.v;
    }
    __syncthreads();
    const size_t xtile = ((size_t)(bc * NH + hh) * 4 + jt) * 4096;
#pragma unroll
    for (int s = 0; s < 2; ++s) {
      f16x8 fah = *(const f16x8*)&XTh[xtile + (size_t)(w * 16 + mlo) * 64 + (s * 4 + gg) * 8];
      f16x8 fal = *(const f16x8*)&XTl[xtile + (size_t)(w * 16 + mlo) * 64 + (s * 4 + gg) * 8];
#pragma unroll
      for (int nf = 0; nf < 4; ++nf) {
        f16x8 fbh = *(const f16x8*)((const char*)BTh_t + SWZ(nf * 16 + mlo, s * 4 + gg));
        acc[nf] = __builtin_amdgcn_mfma_f32_16x16x32_f16(fah, fbh, acc[nf], 0, 0, 0);
        acc[nf] = __builtin_amdgcn_mfma_f32_16x16x32_f16(fal, fbh, acc[nf], 0, 0, 0);
      }
    }
  }
  const size_t sb = ((size_t)(bc * NH + hh)) << 12;
#pragma unroll
  for (int nf = 0; nf < 4; ++nf)
#pragma unroll
    for (int reg = 0; reg < 4; ++reg) {
      int p = w * 16 + (lane >> 4) * 4 + reg;
      int n = nf * 16 + mlo;
      states[sb + (size_t)p * 64 + n] = acc[nf][reg];
    }
}

// ---------------- K6: inter-chunk scan ----------------
__global__ __launch_bounds__(256) void k_scanc(
    const float* __restrict__ states, const float* __restrict__ cdecay,
    float* __restrict__ prev)
{
  int tid = blockIdx.x * 256 + threadIdx.x;
  int pn  = tid & 4095;
  int rem = tid >> 12;
  int hh  = rem % NH;
  int b   = rem / NH;
  float carry = 0.f;
#pragma unroll
  for (int c = 0; c < 4; ++c) {
    size_t idx = ((size_t)((b * 4 + c) * NH + hh) << 12) + pn;
    prev[idx] = carry;
    carry = carry * cdecay[(b * 4 + c) * NH + hh] + states[idx];
  }
}

// ---------------- K7: y = intra + inter + D*x; all operands direct from global ----------------
// grid (bc, hh, it); only att tile (wave-private rows) + scalars in LDS; no syncs in jt loop.
__global__ __launch_bounds__(256) void k_y(
    const u16* __restrict__ XTh, const u16* __restrict__ XTl,
    const float* __restrict__ x,
    const u16* __restrict__ Chg, const u16* __restrict__ Bhg,
    const float* __restrict__ dtp, const float* __restrict__ dAcs,
    const float* __restrict__ prev, const float* __restrict__ Dp,
    float* __restrict__ y)
{
  __shared__ u16 att_t[4096];
  __shared__ float dAc_s[256], dt_s[256], ei_s[64];
  const int bc = blockIdx.x;
  const int hh = blockIdx.y;
  const int it = blockIdx.z;
  const int t  = threadIdx.x;
  const int lane = t & 63, w = t >> 6;
  const int mlo = lane & 15, gg = lane >> 4;
  const size_t base = (size_t)bc * 256;
  const int i0 = it * 64;
  {
    float da = dAcs[(base + t) * NH + hh];
    dAc_s[t] = da;
    dt_s[t]  = dtp[(base + t) * NH + hh];
    if (t < 64) ei_s[t] = expf(dAcs[(base + i0 + t) * NH + hh]);
  }
  __syncthreads();
  // C fragments (single fp16) for this i-tile, direct from global
  f16x8 fc[2];
#pragma unroll
  for (int s = 0; s < 2; ++s)
    fc[s] = *(const f16x8*)&Chg[(size_t)(base + i0 + w * 16 + mlo) * DS + (s * 4 + gg) * 8];
  // inter: y = C . prev^T (prev fp32 direct, cvt to fp16 in regs)
  f32x4 accy[4];
#pragma unroll
  for (int i = 0; i < 4; ++i) accy[i] = (f32x4){0.f, 0.f, 0.f, 0.f};
#pragma unroll
  for (int s = 0; s < 2; ++s)
#pragma unroll
    for (int pf = 0; pf < 4; ++pf) {
      const float* pp = &prev[(((size_t)(bc * NH + hh)) << 12) +
                              (size_t)(pf * 16 + mlo) * 64 + (s * 4 + gg) * 8];
      float4 a = *(const float4*)pp;
      float4 b = *(const float4*)(pp + 4);
      f16x8 fph;
      fph[0] = (_Float16)a.x; fph[1] = (_Float16)a.y;
      fph[2] = (_Float16)a.z; fph[3] = (_Float16)a.w;
      fph[4] = (_Float16)b.x; fph[5] = (_Float16)b.y;
      fph[6] = (_Float16)b.z; fph[7] = (_Float16)b.w;
      accy[pf] = __builtin_amdgcn_mfma_f32_16x16x32_f16(fc[s], fph, accy[pf], 0, 0, 0);
    }
  const int ilb = w * 16 + (lane >> 4) * 4;
#pragma unroll
  for (int pf = 0; pf < 4; ++pf)
#pragma unroll
    for (int reg = 0; reg < 4; ++reg)
      accy[pf][reg] *= ei_s[ilb + reg];

  for (int jt = 0; jt <= it; ++jt) {
    const size_t xtile = ((size_t)(bc * NH + hh) * 4 + jt) * 4096;
    // G tile via MFMA, B fragments direct from global
    f32x4 g[4];
#pragma unroll
    for (int i = 0; i < 4; ++i) g[i] = (f32x4){0.f, 0.f, 0.f, 0.f};
#pragma unroll
    for (int s = 0; s < 2; ++s)
#pragma unroll
      for (int jf = 0; jf < 4; ++jf) {
        f16x8 fbh = *(const f16x8*)&Bhg[(size_t)(base + jt * 64 + jf * 16 + mlo) * DS +
                                        (s * 4 + gg) * 8];
        g[jf] = __builtin_amdgcn_mfma_f32_16x16x32_f16(fc[s], fbh, g[jf], 0, 0, 0);
      }
    // att = G * exp(dAi - dAj) * dtj, causal mask -> fp16 tile (wave-private rows)
#pragma unroll
    for (int jf = 0; jf < 4; ++jf)
#pragma unroll
      for (int reg = 0; reg < 4; ++reg) {
        int il = i0 + ilb + reg;
        int jl = jt * 64 + jf * 16 + mlo;
        float av = (jl <= il) ? g[jf][reg] * expf(dAc_s[il] - dAc_s[jl]) * dt_s[jl] : 0.f;
        *(u16*)((char*)att_t + SWZ(il & 63, (jl & 63) >> 3) + (jl & 7) * 2) = f2h(av);
      }
    // intra: y += att . X^T (X fragments direct from XT tiles)
#pragma unroll
    for (int s = 0; s < 2; ++s) {
      f16x8 fa = *(const f16x8*)((const char*)att_t + SWZ(w * 16 + mlo, s * 4 + gg));
#pragma unroll
      for (int pf = 0; pf < 4; ++pf) {
        f16x8 fxh = *(const f16x8*)&XTh[xtile + (size_t)(pf * 16 + mlo) * 64 + (s * 4 + gg) * 8];
        f16x8 fxl = *(const f16x8*)&XTl[xtile + (size_t)(pf * 16 + mlo) * 64 + (s * 4 + gg) * 8];
        accy[pf] = __builtin_amdgcn_mfma_f32_16x16x32_f16(fa, fxh, accy[pf], 0, 0, 0);
        accy[pf] = __builtin_amdgcn_mfma_f32_16x16x32_f16(fa, fxl, accy[pf], 0, 0, 0);
      }
    }
  }
  // epilogue: + D*x, store
  const float Dh = Dp[hh];
#pragma unroll
  for (int pf = 0; pf < 4; ++pf)
#pragma unroll
    for (int reg = 0; reg < 4; ++reg) {
      size_t row = base + i0 + ilb + reg;
      int col = hh * HD + pf * 16 + mlo;
      y[row * DI + col] = accy[pf][reg] + Dh * x[row * DI + col];
    }
}

// ---------------- K8: LayerNorm * z -> bf16 hi/lo pair ----------------
__global__ __launch_bounds__(256) void k_norm(
    const float* __restrict__ z, const float* __restrict__ nw,
    const float* __restrict__ nb, const float* __restrict__ y,
    u16* __restrict__ yh, u16* __restrict__ yl)
{
  __shared__ float rs[4], rq[4];
  const size_t row = blockIdx.x;
  const int t = threadIdx.x;
  float v[3];
  float s = 0.f, sq = 0.f;
#pragma unroll
  for (int r = 0; r < 3; ++r) {
    v[r] = y[row * DI + r * 256 + t];
    s += v[r];
    sq = fmaf(v[r], v[r], sq);
  }
#pragma unroll
  for (int off = 32; off > 0; off >>= 1) {
    s  += __shfl_down(s, off, 64);
    sq += __shfl_down(sq, off, 64);
  }
  const int wid = t >> 6, lane = t & 63;
  if (lane == 0) { rs[wid] = s; rq[wid] = sq; }
  __syncthreads();
  if (t == 0) {
    rs[0] = rs[0] + rs[1] + rs[2] + rs[3];
    rq[0] = rq[0] + rq[1] + rq[2] + rq[3];
  }
  __syncthreads();
  const float mu   = rs[0] * (1.f / DI);
  const float var  = rq[0] * (1.f / DI) - mu * mu;
  const float rstd = 1.f / sqrtf(var + EPS_);
#pragma unroll
  for (int r = 0; r < 3; ++r) {
    int d = r * 256 + t;
    float o = (v[r] - mu) * rstd * nw[d] + nb[d];
    float p = o * z[row * DI + d];
    u16 h, l;
    bsplit(p, h, l);
    yh[row * DI + d] = h;
    yl[row * DI + d] = l;
  }
}

extern "C" void kernel_launch(void* const* d_in, const int* in_sizes, int n_in,
                              void* d_out, int out_size, void* d_ws, size_t ws_size,
                              hipStream_t stream)
{
  const float* u    = (const float*)d_in[0];
  const float* ipw  = (const float*)d_in[1];
  const float* cw   = (const float*)d_in[2];
  const float* cb   = (const float*)d_in[3];
  const float* dtb  = (const float*)d_in[4];
  const float* Alog = (const float*)d_in[5];
  const float* Dp   = (const float*)d_in[6];
  const float* nw   = (const float*)d_in[7];
  const float* nb   = (const float*)d_in[8];
  const float* opw  = (const float*)d_in[9];
  float* out = (float*)d_out;

  float* ws = (float*)d_ws;
  size_t off = 0;
  float* z_buf   = ws + off; off += (size_t)B_ * L_ * DI;
  float* xBC_buf = ws + off; off += (size_t)B_ * L_ * CONVD;
  float* y_buf   = xBC_buf;                       // alias: xBC dead after conv
  float* dt_buf  = ws + off; off += (size_t)B_ * L_ * NH;
  float* x_buf   = ws + off; off += (size_t)B_ * L_ * DI;
  u16*   Bh_buf  = (u16*)(ws + off); off += (size_t)B_ * L_ * DS / 2;
  u16*   Ch_buf  = (u16*)(ws + off); off += (size_t)B_ * L_ * DS / 2;
  float* dAcs    = ws + off; off += (size_t)B_ * L_ * NH;
  float* cdec    = ws + off; off += (size_t)B_ * NCH * NH;
  float* st_buf  = ws + off; off += (size_t)B_ * NCH * NH * HD * DS;
  float* pv_buf  = ws + off; off += (size_t)B_ * NCH * NH * HD * DS;
  u16*   Woh     = (u16*)(ws + off); off += (size_t)DM * DI / 2;
  u16*   Wol     = (u16*)(ws + off); off += (size_t)DM * DI / 2;
  u16*   XTh_buf = (u16*)(ws + off); off += (size_t)B_ * NCH * NH * 4 * 4096 / 2;
  u16*   XTl_buf = (u16*)(ws + off); off += (size_t)B_ * NCH * NH * 4 * 4096 / 2;

  // aliases inside x_buf (dead/live windows don't overlap)
  u16* Ah = (u16*)x_buf;
  u16* Al = Ah + (size_t)B_ * L_ * DM;
  u16* Whip = Al + (size_t)B_ * L_ * DM;
  u16* yh = (u16*)x_buf;
  u16* yl = yh + (size_t)B_ * L_ * DI;

  hipLaunchKernelGGL(k_cvtA, dim3(8, 12, 16), dim3(256), 0, stream, u, Ah, Al);
  hipLaunchKernelGGL(k_cvtWh, dim3((NIP * DM / 4 + 255) / 256), dim3(256), 0, stream,
                     ipw, Whip, NIP * DM / 4);
  hipLaunchKernelGGL(k_cvtW, dim3((DM * DI / 4 + 255) / 256), dim3(256), 0, stream,
                     opw, Woh, Wol, DM, DI, DM * DI / 4);
  hipLaunchKernelGGL(k_dtp, dim3(64), dim3(256), 0, stream,
                     u, ipw, dtb, Alog, dt_buf, dAcs, cdec);
  hipLaunchKernelGGL(k_gemm1, dim3(128, 13), dim3(256), 0, stream,
                     Ah, Al, Whip, z_buf, xBC_buf);
  hipLaunchKernelGGL(k_conv, dim3(56, 2, 16), dim3(256), 0, stream,
                     xBC_buf, cw, cb, x_buf, Bh_buf, Ch_buf);
  hipLaunchKernelGGL(k_cvtX, dim3(64, 4, 12), dim3(256), 0, stream,
                     x_buf, XTh_buf, XTl_buf);
  hipLaunchKernelGGL(k_states, dim3(64, 12), dim3(256), 0, stream,
                     XTh_buf, XTl_buf, Bh_buf, dt_buf, dAcs, st_buf);
  hipLaunchKernelGGL(k_scanc, dim3(3072), dim3(256), 0, stream, st_buf, cdec, pv_buf);
  hipLaunchKernelGGL(k_y, dim3(64, 12, 4), dim3(256), 0, stream,
                     XTh_buf, XTl_buf, x_buf, Ch_buf, Bh_buf, dt_buf, dAcs, pv_buf, Dp, y_buf);
  hipLaunchKernelGGL(k_norm, dim3(16384), dim3(256), 0, stream, z_buf, nw, nb, y_buf, yh, yl);
  hipLaunchKernelGGL(k_gemm2, dim3(128, 3), dim3(256), 0, stream, yh, yl, Woh, Wol, out);
}

// Round 11
// 288.564 us; speedup vs baseline: 1.2134x; 1.2134x over previous
//
#include <hip/hip_runtime.h>
#include <hip/hip_bf16.h>

#define B_    16
#define L_    1024
#define DM    384
#define DIP   1676
#define NIP   1664
#define DI    768
#define CONVD 896
#define NH    12
#define HD    64
#define DS    64
#define NCH   4
#define CH    256
#define EPS_  1e-5f

typedef unsigned short u16;
typedef unsigned int   u32;
typedef __attribute__((ext_vector_type(8))) short bf16x8;
typedef __attribute__((ext_vector_type(8))) _Float16 f16x8;
typedef __attribute__((ext_vector_type(4))) float f32x4;

union U4 { uint4 v; u16 s[8]; };

// byte offset of 16B slot `slot` in row `row` of a [64][64]-16bit LDS tile (128B rows, XOR swizzle)
#define SWZ(row, slot) (((row) << 7) + ((((slot) ^ ((row) & 7)) & 7) << 4))

// ---- bf16 split helpers (out_proj path) ----
__device__ __forceinline__ u16 f2b(float v) {
  u32 u = __float_as_uint(v);
  u32 r = (u + 0x7FFFu + ((u >> 16) & 1u)) >> 16;
  return (u16)r;
}
__device__ __forceinline__ float b2f(u16 h) { return __uint_as_float(((u32)h) << 16); }
__device__ __forceinline__ void bsplit(float v, u16& h, u16& l) {
  u16 hh = f2b(v);
  l = f2b(v - b2f(hh));
  h = hh;
}
// ---- fp16 split helpers ----
__device__ __forceinline__ u16 f2h(float v) { return __builtin_bit_cast(u16, (_Float16)v); }
__device__ __forceinline__ float h2f(u16 h) { return (float)__builtin_bit_cast(_Float16, h); }
__device__ __forceinline__ void hsplit(float v, u16& h, u16& l) {
  _Float16 hh = (_Float16)v;
  _Float16 ll = (_Float16)(v - (float)hh);
  h = __builtin_bit_cast(u16, hh);
  l = __builtin_bit_cast(u16, ll);
}

// ---------------- converters ----------------
__global__ __launch_bounds__(256) void k_cvtA(const float* __restrict__ u,
                                              u16* __restrict__ Ah, u16* __restrict__ Al)
{
  __shared__ float Ls[32][129];
  const int t  = threadIdx.x;
  const int l0 = blockIdx.x * 128;
  const int k0 = blockIdx.y * 32;
  const int b  = blockIdx.z;
#pragma unroll
  for (int r = 0; r < 4; ++r) {
    int idx = r * 256 + t;
    int kk = idx >> 5, q = idx & 31;
    float4 v = *(const float4*)&u[((size_t)(b * DM + k0 + kk)) * L_ + l0 + q * 4];
    Ls[kk][q * 4 + 0] = v.x; Ls[kk][q * 4 + 1] = v.y;
    Ls[kk][q * 4 + 2] = v.z; Ls[kk][q * 4 + 3] = v.w;
  }
  __syncthreads();
#pragma unroll
  for (int it = 0; it < 2; ++it) {
    int task = it * 256 + t;
    int l = task >> 2, kq = (task & 3) * 8;
    u32 hw[4], lw[4];
#pragma unroll
    for (int j = 0; j < 4; ++j) {
      u16 h0, l0v, h1, l1v;
      hsplit(Ls[kq + 2 * j + 0][l], h0, l0v);
      hsplit(Ls[kq + 2 * j + 1][l], h1, l1v);
      hw[j] = (u32)h0 | ((u32)h1 << 16);
      lw[j] = (u32)l0v | ((u32)l1v << 16);
    }
    size_t off = ((size_t)(b * L_ + l0 + l)) * DM + k0 + kq;
    *(uint4*)&Ah[off] = make_uint4(hw[0], hw[1], hw[2], hw[3]);
    *(uint4*)&Al[off] = make_uint4(lw[0], lw[1], lw[2], lw[3]);
  }
}

__global__ __launch_bounds__(256) void k_cvtWh(const float* __restrict__ W,
                                               u16* __restrict__ Wh, int total4)
{
  int i = blockIdx.x * 256 + threadIdx.x;
  if (i >= total4) return;
  int e = i * 4;
  float4 v = *(const float4*)&W[e];
  u16 h[4] = {f2h(v.x), f2h(v.y), f2h(v.z), f2h(v.w)};
  *(uint2*)&Wh[e] = make_uint2((u32)h[0] | ((u32)h[1] << 16), (u32)h[2] | ((u32)h[3] << 16));
}

__global__ __launch_bounds__(256) void k_cvtW(const float* __restrict__ W,
    u16* __restrict__ Wh, u16* __restrict__ Wl, int nsrc, int K, int total4)
{
  int i = blockIdx.x * 256 + threadIdx.x;
  if (i >= total4) return;
  int e = i * 4;
  int row = e / K;
  float4 v = make_float4(0.f, 0.f, 0.f, 0.f);
  if (row < nsrc) v = *(const float4*)&W[e];
  u16 h[4], l[4];
  bsplit(v.x, h[0], l[0]); bsplit(v.y, h[1], l[1]);
  bsplit(v.z, h[2], l[2]); bsplit(v.w, h[3], l[3]);
  *(uint2*)&Wh[e] = make_uint2((u32)h[0] | ((u32)h[1] << 16), (u32)h[2] | ((u32)h[3] << 16));
  *(uint2*)&Wl[e] = make_uint2((u32)l[0] | ((u32)l[1] << 16), (u32)l[2] | ((u32)l[3] << 16));
}

// ---------------- k_cvtX: x fp32 -> per-(bc,hh,jblk) [64p][64j] fp16 hi/lo tiles,
// stored PRE-SWIZZLED so a linear global_load_lds lands them in SWZ layout ----------------
__global__ __launch_bounds__(256) void k_cvtX(const float* __restrict__ x,
                                              u16* __restrict__ XTh, u16* __restrict__ XTl)
{
  __shared__ float xf2[64][65];
  const int t  = threadIdx.x;
  const int bc = blockIdx.x;
  const int jb = blockIdx.y;
  const int hh = blockIdx.z;
  const size_t rbase = (size_t)bc * 256 + jb * 64;
#pragma unroll
  for (int i = 0; i < 4; ++i) {
    int idx = i * 256 + t;
    int j = idx >> 4, p4 = (idx & 15) * 4;
    float4 v = *(const float4*)&x[(rbase + j) * DI + hh * HD + p4];
    xf2[p4 + 0][j] = v.x; xf2[p4 + 1][j] = v.y;
    xf2[p4 + 2][j] = v.z; xf2[p4 + 3][j] = v.w;
  }
  __syncthreads();
  const size_t tileByte = ((size_t)(bc * NH + hh) * 4 + jb) * 8192;
#pragma unroll
  for (int i = 0; i < 2; ++i) {
    int task = i * 256 + t;
    int p = task >> 3, slot = task & 7, jg = slot * 8;
    U4 H, L;
#pragma unroll
    for (int k = 0; k < 8; ++k) {
      u16 h, l; hsplit(xf2[p][jg + k], h, l);
      H.s[k] = h; L.s[k] = l;
    }
    *(uint4*)((char*)XTh + tileByte + SWZ(p, slot)) = H.v;
    *(uint4*)((char*)XTl + tileByte + SWZ(p, slot)) = L.v;
  }
}

// ---------------- K_dtp: dt logits from u (fp32) + softplus + chunk cumsum ----------------
__global__ __launch_bounds__(256) void k_dtp(
    const float* __restrict__ u, const float* __restrict__ ipw,
    const float* __restrict__ dtb, const float* __restrict__ A_log,
    float* __restrict__ dt, float* __restrict__ dAcs, float* __restrict__ cdecay)
{
  __shared__ float Ls[64][256];
  __shared__ float wdt[NH * DM];
  __shared__ float ws4[4];
  const int bc = blockIdx.x;
  const int b  = bc >> 2, l0 = (bc & 3) * 256;
  const int t  = threadIdx.x;
  const int lane = t & 63, w = t >> 6;
#pragma unroll
  for (int i = 0; i < 18; ++i) wdt[i * 256 + t] = ipw[(size_t)NIP * DM + i * 256 + t];
  float acc[NH] = {};
  for (int k0 = 0; k0 < DM; k0 += 64) {
    __syncthreads();
#pragma unroll
    for (int it = 0; it < 16; ++it) {
      int idx = it * 256 + t;
      int kk = idx >> 6, q4 = (idx & 63) * 4;
      *(float4*)&Ls[kk][q4] = *(const float4*)&u[((size_t)(b * DM + k0 + kk)) * L_ + l0 + q4];
    }
    __syncthreads();
    for (int k = 0; k < 64; ++k) {
      float uv = Ls[k][t];
#pragma unroll
      for (int h = 0; h < NH; ++h)
        acc[h] = fmaf(uv, wdt[h * DM + k0 + k], acc[h]);
    }
  }
  const size_t row = (size_t)bc * 256 + t;
#pragma unroll
  for (int h = 0; h < NH; ++h) {
    float logit = acc[h] + dtb[h];
    float dtv = (logit > 20.f) ? logit : log1pf(expf(logit));
    dt[row * NH + h] = dtv;
    float xv = dtv * (-expf(A_log[h]));
#pragma unroll
    for (int off = 1; off < 64; off <<= 1) {
      float y = __shfl_up(xv, off, 64);
      if (lane >= off) xv += y;
    }
    __syncthreads();
    if (lane == 63) ws4[w] = xv;
    __syncthreads();
    float add = 0.f;
#pragma unroll
    for (int i = 0; i < 4; ++i) if (i < w) add += ws4[i];
    xv += add;
    dAcs[row * NH + h] = xv;
    if (t == 255) cdecay[bc * NH + h] = expf(xv);
  }
}

// 3-stream staging (A-hi, A-lo, W) of one 128x32 u16 K-tile set
#define STAGE3(bufbase, k0) do {                                                                \
  _Pragma("unroll")                                                                             \
  for (int i_ = 0; i_ < 2; ++i_) {                                                              \
    int S_ = i_ * 256 + t;                                                                      \
    int m_ = S_ >> 2;                                                                           \
    int g_ = (S_ ^ (m_ >> 1)) & 3;                                                              \
    size_t goff_ = (size_t)m_ * DM + (k0) + g_ * 8;                                             \
    __builtin_amdgcn_global_load_lds((const __attribute__((address_space(1))) u32*)(g0 + goff_),\
        (__attribute__((address_space(3))) u32*)(lds + (bufbase) + S_ * 8), 16, 0, 0);          \
    __builtin_amdgcn_global_load_lds((const __attribute__((address_space(1))) u32*)(g1 + goff_),\
        (__attribute__((address_space(3))) u32*)(lds + (bufbase) + 4096 + S_ * 8), 16, 0, 0);   \
    __builtin_amdgcn_global_load_lds((const __attribute__((address_space(1))) u32*)(g2 + goff_),\
        (__attribute__((address_space(3))) u32*)(lds + (bufbase) + 8192 + S_ * 8), 16, 0, 0);   \
  }                                                                                             \
} while (0)

// ---------------- fp16x2 MFMA GEMM: in_proj ----------------
__global__ __launch_bounds__(256) void k_gemm1(
    const u16* __restrict__ Ah, const u16* __restrict__ Al,
    const u16* __restrict__ Wh,
    float* __restrict__ z, float* __restrict__ xBC)
{
  __shared__ u16 lds[24576];
  const int t = threadIdx.x;
  const int lane = t & 63, wid = t >> 6;
  const int wr = wid >> 1, wc = wid & 1;
  const int gg = lane >> 4, mlo = lane & 15;
  const int m0 = blockIdx.x * 128, n0 = blockIdx.y * 128;
  f32x4 acc[4][4];
#pragma unroll
  for (int i = 0; i < 4; ++i)
#pragma unroll
    for (int j = 0; j < 4; ++j) acc[i][j] = (f32x4){0.f, 0.f, 0.f, 0.f};
  const u16* g0 = Ah + (size_t)m0 * DM;
  const u16* g1 = Al + (size_t)m0 * DM;
  const u16* g2 = Wh + (size_t)n0 * DM;
  STAGE3(0, 0);
  __syncthreads();
  int cur = 0;
  for (int kt = 0; kt < DM / 32; ++kt) {
    if (kt + 1 < DM / 32) STAGE3((cur ^ 1) * 12288, (kt + 1) * 32);
    const char* ldsb = (const char*)lds + cur * 24576;
    f16x8 fa[4], fal[4], fb[4];
#pragma unroll
    for (int mf = 0; mf < 4; ++mf) {
      int m = wr * 64 + mf * 16 + mlo;
      int off = m * 64 + (((gg ^ (m >> 1)) & 3) << 4);
      fa[mf]  = *(const f16x8*)(ldsb + off);
      fal[mf] = *(const f16x8*)(ldsb + 8192 + off);
    }
#pragma unroll
    for (int nf = 0; nf < 4; ++nf) {
      int n = wc * 64 + nf * 16 + mlo;
      int off = n * 64 + (((gg ^ (n >> 1)) & 3) << 4);
      fb[nf]  = *(const f16x8*)(ldsb + 16384 + off);
    }
#pragma unroll
    for (int mf = 0; mf < 4; ++mf)
#pragma unroll
      for (int nf = 0; nf < 4; ++nf) {
        acc[mf][nf] = __builtin_amdgcn_mfma_f32_16x16x32_f16(fa[mf],  fb[nf], acc[mf][nf], 0, 0, 0);
        acc[mf][nf] = __builtin_amdgcn_mfma_f32_16x16x32_f16(fal[mf], fb[nf], acc[mf][nf], 0, 0, 0);
      }
    __syncthreads();
    cur ^= 1;
  }
  const int rb = m0 + wr * 64 + (lane >> 4) * 4;
  const int cb = n0 + wc * 64 + mlo;
#pragma unroll
  for (int mf = 0; mf < 4; ++mf)
#pragma unroll
    for (int nf = 0; nf < 4; ++nf) {
      int col = cb + nf * 16;
#pragma unroll
      for (int r = 0; r < 4; ++r) {
        int row = rb + mf * 16 + r;
        float v = acc[mf][nf][r];
        if (col < DI) z[(size_t)row * DI + col] = v;
        else xBC[(size_t)row * CONVD + (col - DI)] = v;
      }
    }
}

// 4-stream bf16 staging for gemm2
#define STAGE4(bufbase, k0, KS) do {                                                            \
  _Pragma("unroll")                                                                             \
  for (int i_ = 0; i_ < 2; ++i_) {                                                              \
    int S_ = i_ * 256 + t;                                                                      \
    int m_ = S_ >> 2;                                                                           \
    int g_ = (S_ ^ (m_ >> 1)) & 3;                                                              \
    size_t goff_ = (size_t)m_ * (KS) + (k0) + g_ * 8;                                           \
    __builtin_amdgcn_global_load_lds((const __attribute__((address_space(1))) u32*)(g0 + goff_),\
        (__attribute__((address_space(3))) u32*)(lds + (bufbase) + S_ * 8), 16, 0, 0);          \
    __builtin_amdgcn_global_load_lds((const __attribute__((address_space(1))) u32*)(g1 + goff_),\
        (__attribute__((address_space(3))) u32*)(lds + (bufbase) + 4096 + S_ * 8), 16, 0, 0);   \
    __builtin_amdgcn_global_load_lds((const __attribute__((address_space(1))) u32*)(g2 + goff_),\
        (__attribute__((address_space(3))) u32*)(lds + (bufbase) + 8192 + S_ * 8), 16, 0, 0);   \
    __builtin_amdgcn_global_load_lds((const __attribute__((address_space(1))) u32*)(g3 + goff_),\
        (__attribute__((address_space(3))) u32*)(lds + (bufbase) + 12288 + S_ * 8), 16, 0, 0);  \
  }                                                                                             \
} while (0)

// ---------------- bf16x3 MFMA GEMM: out_proj ----------------
__global__ __launch_bounds__(256) void k_gemm2(
    const u16* __restrict__ Ah, const u16* __restrict__ Al,
    const u16* __restrict__ Bh, const u16* __restrict__ Bl,
    float* __restrict__ out)
{
  __shared__ u16 lds[32768];
  const int t = threadIdx.x;
  const int lane = t & 63, wid = t >> 6;
  const int wr = wid >> 1, wc = wid & 1;
  const int gg = lane >> 4, mlo = lane & 15;
  const int m0 = blockIdx.x * 128, n0 = blockIdx.y * 128;
  f32x4 acc[4][4];
#pragma unroll
  for (int i = 0; i < 4; ++i)
#pragma unroll
    for (int j = 0; j < 4; ++j) acc[i][j] = (f32x4){0.f, 0.f, 0.f, 0.f};
  const u16* g0 = Ah + (size_t)m0 * DI;
  const u16* g1 = Al + (size_t)m0 * DI;
  const u16* g2 = Bh + (size_t)n0 * DI;
  const u16* g3 = Bl + (size_t)n0 * DI;
  STAGE4(0, 0, DI);
  __syncthreads();
  int cur = 0;
  for (int kt = 0; kt < DI / 32; ++kt) {
    if (kt + 1 < DI / 32) STAGE4((cur ^ 1) * 16384, (kt + 1) * 32, DI);
    const char* ldsb = (const char*)lds + cur * 32768;
    bf16x8 fa[4], fal[4], fb[4], fbl[4];
#pragma unroll
    for (int mf = 0; mf < 4; ++mf) {
      int m = wr * 64 + mf * 16 + mlo;
      int off = m * 64 + (((gg ^ (m >> 1)) & 3) << 4);
      fa[mf]  = *(const bf16x8*)(ldsb + off);
      fal[mf] = *(const bf16x8*)(ldsb + 8192 + off);
    }
#pragma unroll
    for (int nf = 0; nf < 4; ++nf) {
      int n = wc * 64 + nf * 16 + mlo;
      int off = n * 64 + (((gg ^ (n >> 1)) & 3) << 4);
      fb[nf]  = *(const bf16x8*)(ldsb + 16384 + off);
      fbl[nf] = *(const bf16x8*)(ldsb + 24576 + off);
    }
#pragma unroll
    for (int mf = 0; mf < 4; ++mf)
#pragma unroll
      for (int nf = 0; nf < 4; ++nf) {
        acc[mf][nf] = __builtin_amdgcn_mfma_f32_16x16x32_bf16(fa[mf],  fb[nf],  acc[mf][nf], 0, 0, 0);
        acc[mf][nf] = __builtin_amdgcn_mfma_f32_16x16x32_bf16(fa[mf],  fbl[nf], acc[mf][nf], 0, 0, 0);
        acc[mf][nf] = __builtin_amdgcn_mfma_f32_16x16x32_bf16(fal[mf], fb[nf],  acc[mf][nf], 0, 0, 0);
      }
    __syncthreads();
    cur ^= 1;
  }
  const int rb = m0 + wr * 64 + (lane >> 4) * 4;
  const int cb = n0 + wc * 64 + mlo;
#pragma unroll
  for (int mf = 0; mf < 4; ++mf)
#pragma unroll
    for (int nf = 0; nf < 4; ++nf) {
      int col = cb + nf * 16;
#pragma unroll
      for (int r = 0; r < 4; ++r) {
        int row = rb + mf * 16 + r;
        int b = row >> 10, l = row & 1023;
        out[((size_t)(b * DM + col)) * L_ + l] = acc[mf][nf][r];
      }
    }
}

// ---------------- K2: LDS-tiled depthwise conv; x fp32, B single fp16, C single fp16 ----------------
#define CC 16
__global__ __launch_bounds__(256) void k_conv(
    const float* __restrict__ xBC, const float* __restrict__ cw,
    const float* __restrict__ cb,
    float* __restrict__ x,
    u16* __restrict__ Bh,
    u16* __restrict__ Chh)
{
  __shared__ float Ls[18][32][CC];
  const int t  = threadIdx.x;
  const int c0 = blockIdx.x * CC;
  const int h0 = blockIdx.y * 16;
  const int b  = blockIdx.z;
#pragma unroll
  for (int k = 0; k < 9; ++k) {
    int f = k * 256 + t;
    int fc4 = f & 3, fw = (f >> 2) & 31, fr = f >> 7;
    int h = h0 + fr - 1;
    float4 v = make_float4(0.f, 0.f, 0.f, 0.f);
    if (h >= 0 && h < 32)
      v = *(const float4*)&xBC[((size_t)(b * 1024 + h * 32 + fw)) * CONVD + c0 + fc4 * 4];
    *(float4*)&Ls[fr][fw][fc4 * 4] = v;
  }
  const int c4 = t & 3;
  const int w  = (t >> 2) & 31;
  const int hb = t >> 7;
  float wt[4][9];
  float bias[4];
#pragma unroll
  for (int j = 0; j < 4; ++j) {
    int c = c0 + c4 * 4 + j;
    bias[j] = cb[c];
#pragma unroll
    for (int kb = 0; kb < 9; ++kb) wt[j][kb] = cw[c * 9 + kb];
  }
  __syncthreads();
#pragma unroll
  for (int k = 0; k < 8; ++k) {
    int h = hb * 8 + k;
    float acc[4] = {bias[0], bias[1], bias[2], bias[3]};
#pragma unroll
    for (int dh = 0; dh < 3; ++dh) {
#pragma unroll
      for (int dw = -1; dw <= 1; ++dw) {
        int ww = w + dw;
        if (ww < 0 || ww > 31) continue;
        const float* p = &Ls[h + dh][ww][c4 * 4];
        int kb = dh * 3 + (dw + 1);
#pragma unroll
        for (int j = 0; j < 4; ++j) acc[j] = fmaf(p[j], wt[j][kb], acc[j]);
      }
    }
    float s4[4];
#pragma unroll
    for (int j = 0; j < 4; ++j) { float v = acc[j]; s4[j] = v / (1.f + expf(-v)); }
    size_t row = (size_t)b * 1024 + (h0 + h) * 32 + w;
    int c = c0 + c4 * 4;
    if (c < DI) {
      *(float4*)&x[row * DI + c] = make_float4(s4[0], s4[1], s4[2], s4[3]);
    } else {
      u16 hv[4] = {f2h(s4[0]), f2h(s4[1]), f2h(s4[2]), f2h(s4[3])};
      uint2 hp = make_uint2((u32)hv[0] | ((u32)hv[1] << 16), (u32)hv[2] | ((u32)hv[3] << 16));
      if (c < DI + DS) *(uint2*)&Bh[row * DS + (c - DI)] = hp;
      else             *(uint2*)&Chh[row * DS + (c - DI - DS)] = hp;
    }
  }
}

// stage one pre-swizzled 8KB XT tile pair into LDS via linear DMA
#define STAGE_XT(tileByte) do {                                                                   \
  _Pragma("unroll")                                                                               \
  for (int i_ = 0; i_ < 2; ++i_) {                                                                \
    int S_ = i_ * 256 + t;                                                                        \
    __builtin_amdgcn_global_load_lds(                                                             \
        (const __attribute__((address_space(1))) u32*)((const char*)XTh + (tileByte) + S_ * 16),  \
        (__attribute__((address_space(3))) u32*)((char*)Xh_t + S_ * 16), 16, 0, 0);               \
    __builtin_amdgcn_global_load_lds(                                                             \
        (const __attribute__((address_space(1))) u32*)((const char*)XTl + (tileByte) + S_ * 16),  \
        (__attribute__((address_space(3))) u32*)((char*)Xl_t + S_ * 16), 16, 0, 0);               \
  }                                                                                               \
} while (0)

// ---------------- K5: chunk states via MFMA; XT via DMA, decay weight folded into B ----------------
__global__ __launch_bounds__(256) void k_states(
    const u16* __restrict__ XTh, const u16* __restrict__ XTl,
    const u16* __restrict__ Bh,
    const float* __restrict__ dt, const float* __restrict__ dAcs,
    float* __restrict__ states)
{
  __shared__ u16 bpackB[64 * 65];
  __shared__ u16 BTh_t[4096];
  __shared__ u16 Xh_t[4096], Xl_t[4096];
  __shared__ float wall[256];
  const int bc = blockIdx.x;
  const int hh = blockIdx.y;
  const int t  = threadIdx.x;
  const int lane = t & 63, w = t >> 6;
  const int mlo = lane & 15, gg = lane >> 4;
  const int r = t >> 2, q = (t & 3) * 16;
  const size_t base = (size_t)bc * 256;
  const float last = dAcs[(base + 255) * NH + hh];
  wall[t] = expf(last - dAcs[(base + t) * NH + hh]) * dt[(base + t) * NH + hh];
  f32x4 acc[4];
#pragma unroll
  for (int i = 0; i < 4; ++i) acc[i] = (f32x4){0.f, 0.f, 0.f, 0.f};
  for (int jt = 0; jt < 4; ++jt) {
    const int j0 = jt * 64;
    __syncthreads();
    STAGE_XT(((size_t)(bc * NH + hh) * 4 + jt) * 8192);
    {
      const u16* bhp = &Bh[(size_t)(base + j0 + r) * DS + q];
      U4 H0, H1;
      H0.v = *(const uint4*)bhp; H1.v = *(const uint4*)(bhp + 8);
#pragma unroll
      for (int k = 0; k < 8; ++k) {
        bpackB[r * 65 + q + k]     = H0.s[k];
        bpackB[r * 65 + q + 8 + k] = H1.s[k];
      }
    }
    __syncthreads();
    // fold decay weight + transpose B -> BT tile
#pragma unroll
    for (int c = 0; c < 2; ++c) {
      U4 BH;
#pragma unroll
      for (int jj = 0; jj < 8; ++jj) {
        int j = q + c * 8 + jj;
        BH.s[jj] = f2h(h2f(bpackB[j * 65 + r]) * wall[j0 + j]);
      }
      *(uint4*)((char*)BTh_t + SWZ(r, (q >> 3) + c)) = BH.v;
    }
    __syncthreads();
#pragma unroll
    for (int s = 0; s < 2; ++s) {
      f16x8 fah = *(const f16x8*)((const char*)Xh_t + SWZ(w * 16 + mlo, s * 4 + gg));
      f16x8 fal = *(const f16x8*)((const char*)Xl_t + SWZ(w * 16 + mlo, s * 4 + gg));
#pragma unroll
      for (int nf = 0; nf < 4; ++nf) {
        f16x8 fbh = *(const f16x8*)((const char*)BTh_t + SWZ(nf * 16 + mlo, s * 4 + gg));
        acc[nf] = __builtin_amdgcn_mfma_f32_16x16x32_f16(fah, fbh, acc[nf], 0, 0, 0);
        acc[nf] = __builtin_amdgcn_mfma_f32_16x16x32_f16(fal, fbh, acc[nf], 0, 0, 0);
      }
    }
  }
  const size_t sb = ((size_t)(bc * NH + hh)) << 12;
#pragma unroll
  for (int nf = 0; nf < 4; ++nf)
#pragma unroll
    for (int reg = 0; reg < 4; ++reg) {
      int p = w * 16 + (lane >> 4) * 4 + reg;
      int n = nf * 16 + mlo;
      states[sb + (size_t)p * 64 + n] = acc[nf][reg];
    }
}

// ---------------- K6: inter-chunk scan ----------------
__global__ __launch_bounds__(256) void k_scanc(
    const float* __restrict__ states, const float* __restrict__ cdecay,
    float* __restrict__ prev)
{
  int tid = blockIdx.x * 256 + threadIdx.x;
  int pn  = tid & 4095;
  int rem = tid >> 12;
  int hh  = rem % NH;
  int b   = rem / NH;
  float carry = 0.f;
#pragma unroll
  for (int c = 0; c < 4; ++c) {
    size_t idx = ((size_t)((b * 4 + c) * NH + hh) << 12) + pn;
    prev[idx] = carry;
    carry = carry * cdecay[(b * 4 + c) * NH + hh] + states[idx];
  }
}

// ---------------- K7: y = intra + inter + D*x; X tiles via DMA, B tile copied, no xf ----------------
__global__ __launch_bounds__(256) void k_y(
    const u16* __restrict__ XTh, const u16* __restrict__ XTl,
    const float* __restrict__ x,
    const u16* __restrict__ Chg, const u16* __restrict__ Bhg,
    const float* __restrict__ dtp, const float* __restrict__ dAcs,
    const float* __restrict__ prev, const float* __restrict__ Dp,
    float* __restrict__ y)
{
  __shared__ u16 Pb_t[4096];              // prev (prologue), then B tile per jt
  __shared__ u16 Xh_t[4096], Xl_t[4096];
  __shared__ u16 att_t[4096];
  __shared__ float dAc_s[256], dt_s[256], ei_s[64];
  const int bc = blockIdx.x;
  const int hh = blockIdx.y;
  const int it = blockIdx.z;
  const int t  = threadIdx.x;
  const int lane = t & 63, w = t >> 6;
  const int mlo = lane & 15, gg = lane >> 4;
  const int r = t >> 2, q = (t & 3) * 16;
  const int slot0 = q >> 3;
  const size_t base = (size_t)bc * 256;
  const int i0 = it * 64;
  {
    float da = dAcs[(base + t) * NH + hh];
    dAc_s[t] = da;
    dt_s[t]  = dtp[(base + t) * NH + hh];
    if (t < 64) ei_s[t] = expf(dAcs[(base + i0 + t) * NH + hh]);
  }
  // stage prev -> single fp16, swizzled
  {
    const float* pp = &prev[(((size_t)(bc * NH + hh)) << 12) + (size_t)r * 64 + q];
    U4 H0, H1;
#pragma unroll
    for (int k = 0; k < 16; ++k) {
      u16 h = f2h(pp[k]);
      if (k < 8) H0.s[k] = h; else H1.s[k - 8] = h;
    }
    *(uint4*)((char*)Pb_t + SWZ(r, slot0))     = H0.v;
    *(uint4*)((char*)Pb_t + SWZ(r, slot0 + 1)) = H1.v;
  }
  __syncthreads();
  // C fragments (single fp16) for this i-tile, direct from global
  f16x8 fc[2];
#pragma unroll
  for (int s = 0; s < 2; ++s)
    fc[s] = *(const f16x8*)&Chg[(size_t)(base + i0 + w * 16 + mlo) * DS + (s * 4 + gg) * 8];
  // inter: y = C . prev^T, scaled by exp(dAcs_i)
  f32x4 accy[4];
#pragma unroll
  for (int i = 0; i < 4; ++i) accy[i] = (f32x4){0.f, 0.f, 0.f, 0.f};
#pragma unroll
  for (int s = 0; s < 2; ++s)
#pragma unroll
    for (int pf = 0; pf < 4; ++pf) {
      f16x8 fph = *(const f16x8*)((const char*)Pb_t + SWZ(pf * 16 + mlo, s * 4 + gg));
      accy[pf] = __builtin_amdgcn_mfma_f32_16x16x32_f16(fc[s], fph, accy[pf], 0, 0, 0);
    }
  const int ilb = w * 16 + (lane >> 4) * 4;
#pragma unroll
  for (int pf = 0; pf < 4; ++pf)
#pragma unroll
    for (int reg = 0; reg < 4; ++reg)
      accy[pf][reg] *= ei_s[ilb + reg];

  for (int jt = 0; jt <= it; ++jt) {
    __syncthreads();   // prior iteration's reads of Pb/Xh/Xl done
    STAGE_XT(((size_t)(bc * NH + hh) * 4 + jt) * 8192);
    {
      const u16* bh = &Bhg[(size_t)(base + jt * 64 + r) * DS + q];
      *(uint4*)((char*)Pb_t + SWZ(r, slot0))     = *(const uint4*)bh;
      *(uint4*)((char*)Pb_t + SWZ(r, slot0 + 1)) = *(const uint4*)(bh + 8);
    }
    __syncthreads();   // drains DMA + B stores
    // G tile via MFMA (C frags cached in regs)
    f32x4 g[4];
#pragma unroll
    for (int i = 0; i < 4; ++i) g[i] = (f32x4){0.f, 0.f, 0.f, 0.f};
#pragma unroll
    for (int s = 0; s < 2; ++s)
#pragma unroll
      for (int jf = 0; jf < 4; ++jf) {
        f16x8 fbh = *(const f16x8*)((const char*)Pb_t + SWZ(jf * 16 + mlo, s * 4 + gg));
        g[jf] = __builtin_amdgcn_mfma_f32_16x16x32_f16(fc[s], fbh, g[jf], 0, 0, 0);
      }
    // att = G * exp(dAi - dAj) * dtj, causal mask -> fp16 tile (wave-private rows)
#pragma unroll
    for (int jf = 0; jf < 4; ++jf)
#pragma unroll
      for (int reg = 0; reg < 4; ++reg) {
        int il = i0 + ilb + reg;
        int jl = jt * 64 + jf * 16 + mlo;
        float av = (jl <= il) ? g[jf][reg] * expf(dAc_s[il] - dAc_s[jl]) * dt_s[jl] : 0.f;
        *(u16*)((char*)att_t + SWZ(il & 63, (jl & 63) >> 3) + (jl & 7) * 2) = f2h(av);
      }
    // intra: y += att . X^T (att rows wave-private, no sync needed)
#pragma unroll
    for (int s = 0; s < 2; ++s) {
      f16x8 fa = *(const f16x8*)((const char*)att_t + SWZ(w * 16 + mlo, s * 4 + gg));
#pragma unroll
      for (int pf = 0; pf < 4; ++pf) {
        f16x8 fxh = *(const f16x8*)((const char*)Xh_t + SWZ(pf * 16 + mlo, s * 4 + gg));
        f16x8 fxl = *(const f16x8*)((const char*)Xl_t + SWZ(pf * 16 + mlo, s * 4 + gg));
        accy[pf] = __builtin_amdgcn_mfma_f32_16x16x32_f16(fa, fxh, accy[pf], 0, 0, 0);
        accy[pf] = __builtin_amdgcn_mfma_f32_16x16x32_f16(fa, fxl, accy[pf], 0, 0, 0);
      }
    }
  }
  // epilogue: + D*x, store
  const float Dh = Dp[hh];
#pragma unroll
  for (int pf = 0; pf < 4; ++pf)
#pragma unroll
    for (int reg = 0; reg < 4; ++reg) {
      size_t row = base + i0 + ilb + reg;
      int col = hh * HD + pf * 16 + mlo;
      y[row * DI + col] = accy[pf][reg] + Dh * x[row * DI + col];
    }
}

// ---------------- K8: LayerNorm * z -> bf16 hi/lo pair ----------------
__global__ __launch_bounds__(256) void k_norm(
    const float* __restrict__ z, const float* __restrict__ nw,
    const float* __restrict__ nb, const float* __restrict__ y,
    u16* __restrict__ yh, u16* __restrict__ yl)
{
  __shared__ float rs[4], rq[4];
  const size_t row = blockIdx.x;
  const int t = threadIdx.x;
  float v[3];
  float s = 0.f, sq = 0.f;
#pragma unroll
  for (int r = 0; r < 3; ++r) {
    v[r] = y[row * DI + r * 256 + t];
    s += v[r];
    sq = fmaf(v[r], v[r], sq);
  }
#pragma unroll
  for (int off = 32; off > 0; off >>= 1) {
    s  += __shfl_down(s, off, 64);
    sq += __shfl_down(sq, off, 64);
  }
  const int wid = t >> 6, lane = t & 63;
  if (lane == 0) { rs[wid] = s; rq[wid] = sq; }
  __syncthreads();
  if (t == 0) {
    rs[0] = rs[0] + rs[1] + rs[2] + rs[3];
    rq[0] = rq[0] + rq[1] + rq[2] + rq[3];
  }
  __syncthreads();
  const float mu   = rs[0] * (1.f / DI);
  const float var  = rq[0] * (1.f / DI) - mu * mu;
  const float rstd = 1.f / sqrtf(var + EPS_);
#pragma unroll
  for (int r = 0; r < 3; ++r) {
    int d = r * 256 + t;
    float o = (v[r] - mu) * rstd * nw[d] + nb[d];
    float p = o * z[row * DI + d];
    u16 h, l;
    bsplit(p, h, l);
    yh[row * DI + d] = h;
    yl[row * DI + d] = l;
  }
}

extern "C" void kernel_launch(void* const* d_in, const int* in_sizes, int n_in,
                              void* d_out, int out_size, void* d_ws, size_t ws_size,
                              hipStream_t stream)
{
  const float* u    = (const float*)d_in[0];
  const float* ipw  = (const float*)d_in[1];
  const float* cw   = (const float*)d_in[2];
  const float* cb   = (const float*)d_in[3];
  const float* dtb  = (const float*)d_in[4];
  const float* Alog = (const float*)d_in[5];
  const float* Dp   = (const float*)d_in[6];
  const float* nw   = (const float*)d_in[7];
  const float* nb   = (const float*)d_in[8];
  const float* opw  = (const float*)d_in[9];
  float* out = (float*)d_out;

  float* ws = (float*)d_ws;
  size_t off = 0;
  float* z_buf   = ws + off; off += (size_t)B_ * L_ * DI;
  float* xBC_buf = ws + off; off += (size_t)B_ * L_ * CONVD;
  float* y_buf   = xBC_buf;                       // alias: xBC dead after conv
  float* dt_buf  = ws + off; off += (size_t)B_ * L_ * NH;
  float* x_buf   = ws + off; off += (size_t)B_ * L_ * DI;
  u16*   Bh_buf  = (u16*)(ws + off); off += (size_t)B_ * L_ * DS / 2;
  u16*   Ch_buf  = (u16*)(ws + off); off += (size_t)B_ * L_ * DS / 2;
  float* dAcs    = ws + off; off += (size_t)B_ * L_ * NH;
  float* cdec    = ws + off; off += (size_t)B_ * NCH * NH;
  float* st_buf  = ws + off; off += (size_t)B_ * NCH * NH * HD * DS;
  float* pv_buf  = ws + off; off += (size_t)B_ * NCH * NH * HD * DS;
  u16*   Woh     = (u16*)(ws + off); off += (size_t)DM * DI / 2;
  u16*   Wol     = (u16*)(ws + off); off += (size_t)DM * DI / 2;
  u16*   XTh_buf = (u16*)(ws + off); off += (size_t)B_ * NCH * NH * 4 * 4096 / 2;
  u16*   XTl_buf = (u16*)(ws + off); off += (size_t)B_ * NCH * NH * 4 * 4096 / 2;

  // aliases inside x_buf (dead/live windows don't overlap)
  u16* Ah = (u16*)x_buf;
  u16* Al = Ah + (size_t)B_ * L_ * DM;
  u16* Whip = Al + (size_t)B_ * L_ * DM;
  u16* yh = (u16*)x_buf;
  u16* yl = yh + (size_t)B_ * L_ * DI;

  hipLaunchKernelGGL(k_cvtA, dim3(8, 12, 16), dim3(256), 0, stream, u, Ah, Al);
  hipLaunchKernelGGL(k_cvtWh, dim3((NIP * DM / 4 + 255) / 256), dim3(256), 0, stream,
                     ipw, Whip, NIP * DM / 4);
  hipLaunchKernelGGL(k_cvtW, dim3((DM * DI / 4 + 255) / 256), dim3(256), 0, stream,
                     opw, Woh, Wol, DM, DI, DM * DI / 4);
  hipLaunchKernelGGL(k_dtp, dim3(64), dim3(256), 0, stream,
                     u, ipw, dtb, Alog, dt_buf, dAcs, cdec);
  hipLaunchKernelGGL(k_gemm1, dim3(128, 13), dim3(256), 0, stream,
                     Ah, Al, Whip, z_buf, xBC_buf);
  hipLaunchKernelGGL(k_conv, dim3(56, 2, 16), dim3(256), 0, stream,
                     xBC_buf, cw, cb, x_buf, Bh_buf, Ch_buf);
  hipLaunchKernelGGL(k_cvtX, dim3(64, 4, 12), dim3(256), 0, stream,
                     x_buf, XTh_buf, XTl_buf);
  hipLaunchKernelGGL(k_states, dim3(64, 12), dim3(256), 0, stream,
                     XTh_buf, XTl_buf, Bh_buf, dt_buf, dAcs, st_buf);
  hipLaunchKernelGGL(k_scanc, dim3(3072), dim3(256), 0, stream, st_buf, cdec, pv_buf);
  hipLaunchKernelGGL(k_y, dim3(64, 12, 4), dim3(256), 0, stream,
                     XTh_buf, XTl_buf, x_buf, Ch_buf, Bh_buf, dt_buf, dAcs, pv_buf, Dp, y_buf);
  hipLaunchKernelGGL(k_norm, dim3(16384), dim3(256), 0, stream, z_buf, nw, nb, y_buf, yh, yl);
  hipLaunchKernelGGL(k_gemm2, dim3(128, 3), dim3(256), 0, stream, yh, yl, Woh, Wol, out);
}

// Round 12
// 274.066 us; speedup vs baseline: 1.2776x; 1.0529x over previous
//
#include <hip/hip_runtime.h>
#include <hip/hip_bf16.h>

#define B_    16
#define L_    1024
#define DM    384
#define DIP   1676
#define NIP   1664
#define DI    768
#define CONVD 896
#define NH    12
#define HD    64
#define DS    64
#define NCH   4
#define CH    256
#define EPS_  1e-5f

typedef unsigned short u16;
typedef unsigned int   u32;
typedef __attribute__((ext_vector_type(8))) short bf16x8;
typedef __attribute__((ext_vector_type(8))) _Float16 f16x8;
typedef __attribute__((ext_vector_type(4))) float f32x4;

union U4 { uint4 v; u16 s[8]; };

// byte offset of 16B slot `slot` in row `row` of a [64][64]-16bit LDS tile (128B rows, XOR swizzle)
#define SWZ(row, slot) (((row) << 7) + ((((slot) ^ ((row) & 7)) & 7) << 4))

// ---- bf16 split helpers (out_proj path) ----
__device__ __forceinline__ u16 f2b(float v) {
  u32 u = __float_as_uint(v);
  u32 r = (u + 0x7FFFu + ((u >> 16) & 1u)) >> 16;
  return (u16)r;
}
__device__ __forceinline__ float b2f(u16 h) { return __uint_as_float(((u32)h) << 16); }
__device__ __forceinline__ void bsplit(float v, u16& h, u16& l) {
  u16 hh = f2b(v);
  l = f2b(v - b2f(hh));
  h = hh;
}
// ---- fp16 helpers ----
__device__ __forceinline__ u16 f2h(float v) { return __builtin_bit_cast(u16, (_Float16)v); }
__device__ __forceinline__ float h2f(u16 h) { return (float)__builtin_bit_cast(_Float16, h); }
__device__ __forceinline__ void hsplit(float v, u16& h, u16& l) {
  _Float16 hh = (_Float16)v;
  _Float16 ll = (_Float16)(v - (float)hh);
  h = __builtin_bit_cast(u16, hh);
  l = __builtin_bit_cast(u16, ll);
}

// ---------------- converters ----------------
__global__ __launch_bounds__(256) void k_cvtA(const float* __restrict__ u,
                                              u16* __restrict__ Ah, u16* __restrict__ Al)
{
  __shared__ float Ls[32][129];
  const int t  = threadIdx.x;
  const int l0 = blockIdx.x * 128;
  const int k0 = blockIdx.y * 32;
  const int b  = blockIdx.z;
#pragma unroll
  for (int r = 0; r < 4; ++r) {
    int idx = r * 256 + t;
    int kk = idx >> 5, q = idx & 31;
    float4 v = *(const float4*)&u[((size_t)(b * DM + k0 + kk)) * L_ + l0 + q * 4];
    Ls[kk][q * 4 + 0] = v.x; Ls[kk][q * 4 + 1] = v.y;
    Ls[kk][q * 4 + 2] = v.z; Ls[kk][q * 4 + 3] = v.w;
  }
  __syncthreads();
#pragma unroll
  for (int it = 0; it < 2; ++it) {
    int task = it * 256 + t;
    int l = task >> 2, kq = (task & 3) * 8;
    u32 hw[4], lw[4];
#pragma unroll
    for (int j = 0; j < 4; ++j) {
      u16 h0, l0v, h1, l1v;
      hsplit(Ls[kq + 2 * j + 0][l], h0, l0v);
      hsplit(Ls[kq + 2 * j + 1][l], h1, l1v);
      hw[j] = (u32)h0 | ((u32)h1 << 16);
      lw[j] = (u32)l0v | ((u32)l1v << 16);
    }
    size_t off = ((size_t)(b * L_ + l0 + l)) * DM + k0 + kq;
    *(uint4*)&Ah[off] = make_uint4(hw[0], hw[1], hw[2], hw[3]);
    *(uint4*)&Al[off] = make_uint4(lw[0], lw[1], lw[2], lw[3]);
  }
}

__global__ __launch_bounds__(256) void k_cvtWh(const float* __restrict__ W,
                                               u16* __restrict__ Wh, int total4)
{
  int i = blockIdx.x * 256 + threadIdx.x;
  if (i >= total4) return;
  int e = i * 4;
  float4 v = *(const float4*)&W[e];
  u16 h[4] = {f2h(v.x), f2h(v.y), f2h(v.z), f2h(v.w)};
  *(uint2*)&Wh[e] = make_uint2((u32)h[0] | ((u32)h[1] << 16), (u32)h[2] | ((u32)h[3] << 16));
}

__global__ __launch_bounds__(256) void k_cvtW(const float* __restrict__ W,
    u16* __restrict__ Wh, u16* __restrict__ Wl, int nsrc, int K, int total4)
{
  int i = blockIdx.x * 256 + threadIdx.x;
  if (i >= total4) return;
  int e = i * 4;
  int row = e / K;
  float4 v = make_float4(0.f, 0.f, 0.f, 0.f);
  if (row < nsrc) v = *(const float4*)&W[e];
  u16 h[4], l[4];
  bsplit(v.x, h[0], l[0]); bsplit(v.y, h[1], l[1]);
  bsplit(v.z, h[2], l[2]); bsplit(v.w, h[3], l[3]);
  *(uint2*)&Wh[e] = make_uint2((u32)h[0] | ((u32)h[1] << 16), (u32)h[2] | ((u32)h[3] << 16));
  *(uint2*)&Wl[e] = make_uint2((u32)l[0] | ((u32)l[1] << 16), (u32)l[2] | ((u32)l[3] << 16));
}

// ---------------- k_cvtX: x fp32 -> per-(bc,hh,jblk) [64p][64j] fp16 tile (pre-swizzled) ----------------
__global__ __launch_bounds__(256) void k_cvtX(const float* __restrict__ x,
                                              u16* __restrict__ XTh)
{
  __shared__ float xf2[64][65];
  const int t  = threadIdx.x;
  const int bc = blockIdx.x;
  const int jb = blockIdx.y;
  const int hh = blockIdx.z;
  const size_t rbase = (size_t)bc * 256 + jb * 64;
#pragma unroll
  for (int i = 0; i < 4; ++i) {
    int idx = i * 256 + t;
    int j = idx >> 4, p4 = (idx & 15) * 4;
    float4 v = *(const float4*)&x[(rbase + j) * DI + hh * HD + p4];
    xf2[p4 + 0][j] = v.x; xf2[p4 + 1][j] = v.y;
    xf2[p4 + 2][j] = v.z; xf2[p4 + 3][j] = v.w;
  }
  __syncthreads();
  const size_t tileByte = ((size_t)(bc * NH + hh) * 4 + jb) * 8192;
#pragma unroll
  for (int i = 0; i < 2; ++i) {
    int task = i * 256 + t;
    int p = task >> 3, slot = task & 7, jg = slot * 8;
    U4 H;
#pragma unroll
    for (int k = 0; k < 8; ++k) H.s[k] = f2h(xf2[p][jg + k]);
    *(uint4*)((char*)XTh + tileByte + SWZ(p, slot)) = H.v;
  }
}

// ---------------- K_dtp: dt logits from u (fp32) + softplus + chunk cumsum ----------------
__global__ __launch_bounds__(256) void k_dtp(
    const float* __restrict__ u, const float* __restrict__ ipw,
    const float* __restrict__ dtb, const float* __restrict__ A_log,
    float* __restrict__ dt, float* __restrict__ dAcs, float* __restrict__ cdecay)
{
  __shared__ float Ls[64][256];
  __shared__ float wdt[NH * DM];
  __shared__ float ws4[4];
  const int bc = blockIdx.x;
  const int b  = bc >> 2, l0 = (bc & 3) * 256;
  const int t  = threadIdx.x;
  const int lane = t & 63, w = t >> 6;
#pragma unroll
  for (int i = 0; i < 18; ++i) wdt[i * 256 + t] = ipw[(size_t)NIP * DM + i * 256 + t];
  float acc[NH] = {};
  for (int k0 = 0; k0 < DM; k0 += 64) {
    __syncthreads();
#pragma unroll
    for (int it = 0; it < 16; ++it) {
      int idx = it * 256 + t;
      int kk = idx >> 6, q4 = (idx & 63) * 4;
      *(float4*)&Ls[kk][q4] = *(const float4*)&u[((size_t)(b * DM + k0 + kk)) * L_ + l0 + q4];
    }
    __syncthreads();
    for (int k = 0; k < 64; ++k) {
      float uv = Ls[k][t];
#pragma unroll
      for (int h = 0; h < NH; ++h)
        acc[h] = fmaf(uv, wdt[h * DM + k0 + k], acc[h]);
    }
  }
  const size_t row = (size_t)bc * 256 + t;
#pragma unroll
  for (int h = 0; h < NH; ++h) {
    float logit = acc[h] + dtb[h];
    float dtv = (logit > 20.f) ? logit : log1pf(expf(logit));
    dt[row * NH + h] = dtv;
    float xv = dtv * (-expf(A_log[h]));
#pragma unroll
    for (int off = 1; off < 64; off <<= 1) {
      float y = __shfl_up(xv, off, 64);
      if (lane >= off) xv += y;
    }
    __syncthreads();
    if (lane == 63) ws4[w] = xv;
    __syncthreads();
    float add = 0.f;
#pragma unroll
    for (int i = 0; i < 4; ++i) if (i < w) add += ws4[i];
    xv += add;
    dAcs[row * NH + h] = xv;
    if (t == 255) cdecay[bc * NH + h] = expf(xv);
  }
}

// 3-stream staging (A-hi, A-lo, W) of one 128x32 u16 K-tile set
#define STAGE3(bufbase, k0) do {                                                                \
  _Pragma("unroll")                                                                             \
  for (int i_ = 0; i_ < 2; ++i_) {                                                              \
    int S_ = i_ * 256 + t;                                                                      \
    int m_ = S_ >> 2;                                                                           \
    int g_ = (S_ ^ (m_ >> 1)) & 3;                                                              \
    size_t goff_ = (size_t)m_ * DM + (k0) + g_ * 8;                                             \
    __builtin_amdgcn_global_load_lds((const __attribute__((address_space(1))) u32*)(g0 + goff_),\
        (__attribute__((address_space(3))) u32*)(lds + (bufbase) + S_ * 8), 16, 0, 0);          \
    __builtin_amdgcn_global_load_lds((const __attribute__((address_space(1))) u32*)(g1 + goff_),\
        (__attribute__((address_space(3))) u32*)(lds + (bufbase) + 4096 + S_ * 8), 16, 0, 0);   \
    __builtin_amdgcn_global_load_lds((const __attribute__((address_space(1))) u32*)(g2 + goff_),\
        (__attribute__((address_space(3))) u32*)(lds + (bufbase) + 8192 + S_ * 8), 16, 0, 0);   \
  }                                                                                             \
} while (0)

// ---------------- fp16x2 MFMA GEMM: in_proj (z fp32, xBC fp16) ----------------
__global__ __launch_bounds__(256) void k_gemm1(
    const u16* __restrict__ Ah, const u16* __restrict__ Al,
    const u16* __restrict__ Wh,
    float* __restrict__ z, u16* __restrict__ xBC)
{
  __shared__ u16 lds[24576];
  const int t = threadIdx.x;
  const int lane = t & 63, wid = t >> 6;
  const int wr = wid >> 1, wc = wid & 1;
  const int gg = lane >> 4, mlo = lane & 15;
  const int m0 = blockIdx.x * 128, n0 = blockIdx.y * 128;
  f32x4 acc[4][4];
#pragma unroll
  for (int i = 0; i < 4; ++i)
#pragma unroll
    for (int j = 0; j < 4; ++j) acc[i][j] = (f32x4){0.f, 0.f, 0.f, 0.f};
  const u16* g0 = Ah + (size_t)m0 * DM;
  const u16* g1 = Al + (size_t)m0 * DM;
  const u16* g2 = Wh + (size_t)n0 * DM;
  STAGE3(0, 0);
  __syncthreads();
  int cur = 0;
  for (int kt = 0; kt < DM / 32; ++kt) {
    if (kt + 1 < DM / 32) STAGE3((cur ^ 1) * 12288, (kt + 1) * 32);
    const char* ldsb = (const char*)lds + cur * 24576;
    f16x8 fa[4], fal[4], fb[4];
#pragma unroll
    for (int mf = 0; mf < 4; ++mf) {
      int m = wr * 64 + mf * 16 + mlo;
      int off = m * 64 + (((gg ^ (m >> 1)) & 3) << 4);
      fa[mf]  = *(const f16x8*)(ldsb + off);
      fal[mf] = *(const f16x8*)(ldsb + 8192 + off);
    }
#pragma unroll
    for (int nf = 0; nf < 4; ++nf) {
      int n = wc * 64 + nf * 16 + mlo;
      int off = n * 64 + (((gg ^ (n >> 1)) & 3) << 4);
      fb[nf]  = *(const f16x8*)(ldsb + 16384 + off);
    }
#pragma unroll
    for (int mf = 0; mf < 4; ++mf)
#pragma unroll
      for (int nf = 0; nf < 4; ++nf) {
        acc[mf][nf] = __builtin_amdgcn_mfma_f32_16x16x32_f16(fa[mf],  fb[nf], acc[mf][nf], 0, 0, 0);
        acc[mf][nf] = __builtin_amdgcn_mfma_f32_16x16x32_f16(fal[mf], fb[nf], acc[mf][nf], 0, 0, 0);
      }
    __syncthreads();
    cur ^= 1;
  }
  const int rb = m0 + wr * 64 + (lane >> 4) * 4;
  const int cb = n0 + wc * 64 + mlo;
#pragma unroll
  for (int mf = 0; mf < 4; ++mf)
#pragma unroll
    for (int nf = 0; nf < 4; ++nf) {
      int col = cb + nf * 16;
#pragma unroll
      for (int r = 0; r < 4; ++r) {
        int row = rb + mf * 16 + r;
        float v = acc[mf][nf][r];
        if (col < DI) z[(size_t)row * DI + col] = v;
        else xBC[(size_t)row * CONVD + (col - DI)] = f2h(v);
      }
    }
}

// 4-stream bf16 staging for gemm2
#define STAGE4(bufbase, k0, KS) do {                                                            \
  _Pragma("unroll")                                                                             \
  for (int i_ = 0; i_ < 2; ++i_) {                                                              \
    int S_ = i_ * 256 + t;                                                                      \
    int m_ = S_ >> 2;                                                                           \
    int g_ = (S_ ^ (m_ >> 1)) & 3;                                                              \
    size_t goff_ = (size_t)m_ * (KS) + (k0) + g_ * 8;                                           \
    __builtin_amdgcn_global_load_lds((const __attribute__((address_space(1))) u32*)(g0 + goff_),\
        (__attribute__((address_space(3))) u32*)(lds + (bufbase) + S_ * 8), 16, 0, 0);          \
    __builtin_amdgcn_global_load_lds((const __attribute__((address_space(1))) u32*)(g1 + goff_),\
        (__attribute__((address_space(3))) u32*)(lds + (bufbase) + 4096 + S_ * 8), 16, 0, 0);   \
    __builtin_amdgcn_global_load_lds((const __attribute__((address_space(1))) u32*)(g2 + goff_),\
        (__attribute__((address_space(3))) u32*)(lds + (bufbase) + 8192 + S_ * 8), 16, 0, 0);   \
    __builtin_amdgcn_global_load_lds((const __attribute__((address_space(1))) u32*)(g3 + goff_),\
        (__attribute__((address_space(3))) u32*)(lds + (bufbase) + 12288 + S_ * 8), 16, 0, 0);  \
  }                                                                                             \
} while (0)

// ---------------- bf16x3 MFMA GEMM: out_proj ----------------
__global__ __launch_bounds__(256) void k_gemm2(
    const u16* __restrict__ Ah, const u16* __restrict__ Al,
    const u16* __restrict__ Bh, const u16* __restrict__ Bl,
    float* __restrict__ out)
{
  __shared__ u16 lds[32768];
  const int t = threadIdx.x;
  const int lane = t & 63, wid = t >> 6;
  const int wr = wid >> 1, wc = wid & 1;
  const int gg = lane >> 4, mlo = lane & 15;
  const int m0 = blockIdx.x * 128, n0 = blockIdx.y * 128;
  f32x4 acc[4][4];
#pragma unroll
  for (int i = 0; i < 4; ++i)
#pragma unroll
    for (int j = 0; j < 4; ++j) acc[i][j] = (f32x4){0.f, 0.f, 0.f, 0.f};
  const u16* g0 = Ah + (size_t)m0 * DI;
  const u16* g1 = Al + (size_t)m0 * DI;
  const u16* g2 = Bh + (size_t)n0 * DI;
  const u16* g3 = Bl + (size_t)n0 * DI;
  STAGE4(0, 0, DI);
  __syncthreads();
  int cur = 0;
  for (int kt = 0; kt < DI / 32; ++kt) {
    if (kt + 1 < DI / 32) STAGE4((cur ^ 1) * 16384, (kt + 1) * 32, DI);
    const char* ldsb = (const char*)lds + cur * 32768;
    bf16x8 fa[4], fal[4], fb[4], fbl[4];
#pragma unroll
    for (int mf = 0; mf < 4; ++mf) {
      int m = wr * 64 + mf * 16 + mlo;
      int off = m * 64 + (((gg ^ (m >> 1)) & 3) << 4);
      fa[mf]  = *(const bf16x8*)(ldsb + off);
      fal[mf] = *(const bf16x8*)(ldsb + 8192 + off);
    }
#pragma unroll
    for (int nf = 0; nf < 4; ++nf) {
      int n = wc * 64 + nf * 16 + mlo;
      int off = n * 64 + (((gg ^ (n >> 1)) & 3) << 4);
      fb[nf]  = *(const bf16x8*)(ldsb + 16384 + off);
      fbl[nf] = *(const bf16x8*)(ldsb + 24576 + off);
    }
#pragma unroll
    for (int mf = 0; mf < 4; ++mf)
#pragma unroll
      for (int nf = 0; nf < 4; ++nf) {
        acc[mf][nf] = __builtin_amdgcn_mfma_f32_16x16x32_bf16(fa[mf],  fb[nf],  acc[mf][nf], 0, 0, 0);
        acc[mf][nf] = __builtin_amdgcn_mfma_f32_16x16x32_bf16(fa[mf],  fbl[nf], acc[mf][nf], 0, 0, 0);
        acc[mf][nf] = __builtin_amdgcn_mfma_f32_16x16x32_bf16(fal[mf], fb[nf],  acc[mf][nf], 0, 0, 0);
      }
    __syncthreads();
    cur ^= 1;
  }
  const int rb = m0 + wr * 64 + (lane >> 4) * 4;
  const int cb = n0 + wc * 64 + mlo;
#pragma unroll
  for (int mf = 0; mf < 4; ++mf)
#pragma unroll
    for (int nf = 0; nf < 4; ++nf) {
      int col = cb + nf * 16;
#pragma unroll
      for (int r = 0; r < 4; ++r) {
        int row = rb + mf * 16 + r;
        int b = row >> 10, l = row & 1023;
        out[((size_t)(b * DM + col)) * L_ + l] = acc[mf][nf][r];
      }
    }
}

// ---------------- K2: LDS-tiled depthwise conv; xBC fp16 in; x fp32, B/C single fp16 out ----------------
#define CC 16
__global__ __launch_bounds__(256) void k_conv(
    const u16* __restrict__ xBC, const float* __restrict__ cw,
    const float* __restrict__ cb,
    float* __restrict__ x,
    u16* __restrict__ Bh,
    u16* __restrict__ Chh)
{
  __shared__ float Ls[18][32][CC];
  const int t  = threadIdx.x;
  const int c0 = blockIdx.x * CC;
  const int h0 = blockIdx.y * 16;
  const int b  = blockIdx.z;
#pragma unroll
  for (int k = 0; k < 9; ++k) {
    int f = k * 256 + t;
    int fc4 = f & 3, fw = (f >> 2) & 31, fr = f >> 7;
    int h = h0 + fr - 1;
    U4 v; v.v = make_uint4(0, 0, 0, 0);
    if (h >= 0 && h < 32) {
      uint2 p = *(const uint2*)&xBC[((size_t)(b * 1024 + h * 32 + fw)) * CONVD + c0 + fc4 * 4];
      v.v.x = p.x; v.v.y = p.y;
    }
    Ls[fr][fw][fc4 * 4 + 0] = h2f(v.s[0]);
    Ls[fr][fw][fc4 * 4 + 1] = h2f(v.s[1]);
    Ls[fr][fw][fc4 * 4 + 2] = h2f(v.s[2]);
    Ls[fr][fw][fc4 * 4 + 3] = h2f(v.s[3]);
  }
  const int c4 = t & 3;
  const int w  = (t >> 2) & 31;
  const int hb = t >> 7;
  float wt[4][9];
  float bias[4];
#pragma unroll
  for (int j = 0; j < 4; ++j) {
    int c = c0 + c4 * 4 + j;
    bias[j] = cb[c];
#pragma unroll
    for (int kb = 0; kb < 9; ++kb) wt[j][kb] = cw[c * 9 + kb];
  }
  __syncthreads();
#pragma unroll
  for (int k = 0; k < 8; ++k) {
    int h = hb * 8 + k;
    float acc[4] = {bias[0], bias[1], bias[2], bias[3]};
#pragma unroll
    for (int dh = 0; dh < 3; ++dh) {
#pragma unroll
      for (int dw = -1; dw <= 1; ++dw) {
        int ww = w + dw;
        if (ww < 0 || ww > 31) continue;
        const float* p = &Ls[h + dh][ww][c4 * 4];
        int kb = dh * 3 + (dw + 1);
#pragma unroll
        for (int j = 0; j < 4; ++j) acc[j] = fmaf(p[j], wt[j][kb], acc[j]);
      }
    }
    float s4[4];
#pragma unroll
    for (int j = 0; j < 4; ++j) { float v = acc[j]; s4[j] = v / (1.f + expf(-v)); }
    size_t row = (size_t)b * 1024 + (h0 + h) * 32 + w;
    int c = c0 + c4 * 4;
    if (c < DI) {
      *(float4*)&x[row * DI + c] = make_float4(s4[0], s4[1], s4[2], s4[3]);
    } else {
      u16 hv[4] = {f2h(s4[0]), f2h(s4[1]), f2h(s4[2]), f2h(s4[3])};
      uint2 hp = make_uint2((u32)hv[0] | ((u32)hv[1] << 16), (u32)hv[2] | ((u32)hv[3] << 16));
      if (c < DI + DS) *(uint2*)&Bh[row * DS + (c - DI)] = hp;
      else             *(uint2*)&Chh[row * DS + (c - DI - DS)] = hp;
    }
  }
}

// stage one pre-swizzled 8KB XT tile into LDS via linear DMA
#define STAGE_XT(tileByte) do {                                                                   \
  _Pragma("unroll")                                                                               \
  for (int i_ = 0; i_ < 2; ++i_) {                                                                \
    int S_ = i_ * 256 + t;                                                                        \
    __builtin_amdgcn_global_load_lds(                                                             \
        (const __attribute__((address_space(1))) u32*)((const char*)XTh + (tileByte) + S_ * 16),  \
        (__attribute__((address_space(3))) u32*)((char*)Xh_t + S_ * 16), 16, 0, 0);               \
  }                                                                                               \
} while (0)

// ---------------- K5: chunk states via MFMA; X single fp16 via DMA, weight folded into B ----------------
__global__ __launch_bounds__(256) void k_states(
    const u16* __restrict__ XTh,
    const u16* __restrict__ Bh,
    const float* __restrict__ dt, const float* __restrict__ dAcs,
    float* __restrict__ states)
{
  __shared__ u16 bpackB[64 * 65];
  __shared__ u16 BTh_t[4096];
  __shared__ u16 Xh_t[4096];
  __shared__ float wall[256];
  const int bc = blockIdx.x;
  const int hh = blockIdx.y;
  const int t  = threadIdx.x;
  const int lane = t & 63, w = t >> 6;
  const int mlo = lane & 15, gg = lane >> 4;
  const int r = t >> 2, q = (t & 3) * 16;
  const size_t base = (size_t)bc * 256;
  const float last = dAcs[(base + 255) * NH + hh];
  wall[t] = expf(last - dAcs[(base + t) * NH + hh]) * dt[(base + t) * NH + hh];
  f32x4 acc[4];
#pragma unroll
  for (int i = 0; i < 4; ++i) acc[i] = (f32x4){0.f, 0.f, 0.f, 0.f};
  for (int jt = 0; jt < 4; ++jt) {
    const int j0 = jt * 64;
    __syncthreads();
    STAGE_XT(((size_t)(bc * NH + hh) * 4 + jt) * 8192);
    {
      const u16* bhp = &Bh[(size_t)(base + j0 + r) * DS + q];
      U4 H0, H1;
      H0.v = *(const uint4*)bhp; H1.v = *(const uint4*)(bhp + 8);
#pragma unroll
      for (int k = 0; k < 8; ++k) {
        bpackB[r * 65 + q + k]     = H0.s[k];
        bpackB[r * 65 + q + 8 + k] = H1.s[k];
      }
    }
    __syncthreads();
#pragma unroll
    for (int c = 0; c < 2; ++c) {
      U4 BH;
#pragma unroll
      for (int jj = 0; jj < 8; ++jj) {
        int j = q + c * 8 + jj;
        BH.s[jj] = f2h(h2f(bpackB[j * 65 + r]) * wall[j0 + j]);
      }
      *(uint4*)((char*)BTh_t + SWZ(r, (q >> 3) + c)) = BH.v;
    }
    __syncthreads();
#pragma unroll
    for (int s = 0; s < 2; ++s) {
      f16x8 fah = *(const f16x8*)((const char*)Xh_t + SWZ(w * 16 + mlo, s * 4 + gg));
#pragma unroll
      for (int nf = 0; nf < 4; ++nf) {
        f16x8 fbh = *(const f16x8*)((const char*)BTh_t + SWZ(nf * 16 + mlo, s * 4 + gg));
        acc[nf] = __builtin_amdgcn_mfma_f32_16x16x32_f16(fah, fbh, acc[nf], 0, 0, 0);
      }
    }
  }
  const size_t sb = ((size_t)(bc * NH + hh)) << 12;
#pragma unroll
  for (int nf = 0; nf < 4; ++nf)
#pragma unroll
    for (int reg = 0; reg < 4; ++reg) {
      int p = w * 16 + (lane >> 4) * 4 + reg;
      int n = nf * 16 + mlo;
      states[sb + (size_t)p * 64 + n] = acc[nf][reg];
    }
}

// ---------------- K6: inter-chunk scan ----------------
__global__ __launch_bounds__(256) void k_scanc(
    const float* __restrict__ states, const float* __restrict__ cdecay,
    float* __restrict__ prev)
{
  int tid = blockIdx.x * 256 + threadIdx.x;
  int pn  = tid & 4095;
  int rem = tid >> 12;
  int hh  = rem % NH;
  int b   = rem / NH;
  float carry = 0.f;
#pragma unroll
  for (int c = 0; c < 4; ++c) {
    size_t idx = ((size_t)((b * 4 + c) * NH + hh) << 12) + pn;
    prev[idx] = carry;
    carry = carry * cdecay[(b * 4 + c) * NH + hh] + states[idx];
  }
}

// ---------------- K7: y = intra + inter + D*x; X single fp16 via DMA ----------------
__global__ __launch_bounds__(256) void k_y(
    const u16* __restrict__ XTh,
    const float* __restrict__ x,
    const u16* __restrict__ Chg, const u16* __restrict__ Bhg,
    const float* __restrict__ dtp, const float* __restrict__ dAcs,
    const float* __restrict__ prev, const float* __restrict__ Dp,
    float* __restrict__ y)
{
  __shared__ u16 Pb_t[4096];              // prev (prologue), then B tile per jt
  __shared__ u16 Xh_t[4096];
  __shared__ u16 att_t[4096];
  __shared__ float dAc_s[256], dt_s[256], ei_s[64];
  const int bc = blockIdx.x;
  const int hh = blockIdx.y;
  const int it = blockIdx.z;
  const int t  = threadIdx.x;
  const int lane = t & 63, w = t >> 6;
  const int mlo = lane & 15, gg = lane >> 4;
  const int r = t >> 2, q = (t & 3) * 16;
  const int slot0 = q >> 3;
  const size_t base = (size_t)bc * 256;
  const int i0 = it * 64;
  {
    float da = dAcs[(base + t) * NH + hh];
    dAc_s[t] = da;
    dt_s[t]  = dtp[(base + t) * NH + hh];
    if (t < 64) ei_s[t] = expf(dAcs[(base + i0 + t) * NH + hh]);
  }
  // stage prev -> single fp16, swizzled
  {
    const float* pp = &prev[(((size_t)(bc * NH + hh)) << 12) + (size_t)r * 64 + q];
    U4 H0, H1;
#pragma unroll
    for (int k = 0; k < 16; ++k) {
      u16 h = f2h(pp[k]);
      if (k < 8) H0.s[k] = h; else H1.s[k - 8] = h;
    }
    *(uint4*)((char*)Pb_t + SWZ(r, slot0))     = H0.v;
    *(uint4*)((char*)Pb_t + SWZ(r, slot0 + 1)) = H1.v;
  }
  __syncthreads();
  // C fragments (single fp16) for this i-tile, direct from global
  f16x8 fc[2];
#pragma unroll
  for (int s = 0; s < 2; ++s)
    fc[s] = *(const f16x8*)&Chg[(size_t)(base + i0 + w * 16 + mlo) * DS + (s * 4 + gg) * 8];
  // inter: y = C . prev^T, scaled by exp(dAcs_i)
  f32x4 accy[4];
#pragma unroll
  for (int i = 0; i < 4; ++i) accy[i] = (f32x4){0.f, 0.f, 0.f, 0.f};
#pragma unroll
  for (int s = 0; s < 2; ++s)
#pragma unroll
    for (int pf = 0; pf < 4; ++pf) {
      f16x8 fph = *(const f16x8*)((const char*)Pb_t + SWZ(pf * 16 + mlo, s * 4 + gg));
      accy[pf] = __builtin_amdgcn_mfma_f32_16x16x32_f16(fc[s], fph, accy[pf], 0, 0, 0);
    }
  const int ilb = w * 16 + (lane >> 4) * 4;
#pragma unroll
  for (int pf = 0; pf < 4; ++pf)
#pragma unroll
    for (int reg = 0; reg < 4; ++reg)
      accy[pf][reg] *= ei_s[ilb + reg];

  for (int jt = 0; jt <= it; ++jt) {
    __syncthreads();   // prior iteration's reads of Pb/Xh done
    STAGE_XT(((size_t)(bc * NH + hh) * 4 + jt) * 8192);
    {
      const u16* bh = &Bhg[(size_t)(base + jt * 64 + r) * DS + q];
      *(uint4*)((char*)Pb_t + SWZ(r, slot0))     = *(const uint4*)bh;
      *(uint4*)((char*)Pb_t + SWZ(r, slot0 + 1)) = *(const uint4*)(bh + 8);
    }
    __syncthreads();   // drains DMA + B stores
    // G tile via MFMA (C frags cached in regs)
    f32x4 g[4];
#pragma unroll
    for (int i = 0; i < 4; ++i) g[i] = (f32x4){0.f, 0.f, 0.f, 0.f};
#pragma unroll
    for (int s = 0; s < 2; ++s)
#pragma unroll
      for (int jf = 0; jf < 4; ++jf) {
        f16x8 fbh = *(const f16x8*)((const char*)Pb_t + SWZ(jf * 16 + mlo, s * 4 + gg));
        g[jf] = __builtin_amdgcn_mfma_f32_16x16x32_f16(fc[s], fbh, g[jf], 0, 0, 0);
      }
    // att = G * exp(dAi - dAj) * dtj, causal mask -> fp16 tile (wave-private rows)
#pragma unroll
    for (int jf = 0; jf < 4; ++jf)
#pragma unroll
      for (int reg = 0; reg < 4; ++reg) {
        int il = i0 + ilb + reg;
        int jl = jt * 64 + jf * 16 + mlo;
        float av = (jl <= il) ? g[jf][reg] * expf(dAc_s[il] - dAc_s[jl]) * dt_s[jl] : 0.f;
        *(u16*)((char*)att_t + SWZ(il & 63, (jl & 63) >> 3) + (jl & 7) * 2) = f2h(av);
      }
    // intra: y += att . X^T (att rows wave-private, no sync needed)
#pragma unroll
    for (int s = 0; s < 2; ++s) {
      f16x8 fa = *(const f16x8*)((const char*)att_t + SWZ(w * 16 + mlo, s * 4 + gg));
#pragma unroll
      for (int pf = 0; pf < 4; ++pf) {
        f16x8 fxh = *(const f16x8*)((const char*)Xh_t + SWZ(pf * 16 + mlo, s * 4 + gg));
        accy[pf] = __builtin_amdgcn_mfma_f32_16x16x32_f16(fa, fxh, accy[pf], 0, 0, 0);
      }
    }
  }
  // epilogue: + D*x, store
  const float Dh = Dp[hh];
#pragma unroll
  for (int pf = 0; pf < 4; ++pf)
#pragma unroll
    for (int reg = 0; reg < 4; ++reg) {
      size_t row = base + i0 + ilb + reg;
      int col = hh * HD + pf * 16 + mlo;
      y[row * DI + col] = accy[pf][reg] + Dh * x[row * DI + col];
    }
}

// ---------------- K8: LayerNorm * z -> bf16 hi/lo pair ----------------
__global__ __launch_bounds__(256) void k_norm(
    const float* __restrict__ z, const float* __restrict__ nw,
    const float* __restrict__ nb, const float* __restrict__ y,
    u16* __restrict__ yh, u16* __restrict__ yl)
{
  __shared__ float rs[4], rq[4];
  const size_t row = blockIdx.x;
  const int t = threadIdx.x;
  float v[3];
  float s = 0.f, sq = 0.f;
#pragma unroll
  for (int r = 0; r < 3; ++r) {
    v[r] = y[row * DI + r * 256 + t];
    s += v[r];
    sq = fmaf(v[r], v[r], sq);
  }
#pragma unroll
  for (int off = 32; off > 0; off >>= 1) {
    s  += __shfl_down(s, off, 64);
    sq += __shfl_down(sq, off, 64);
  }
  const int wid = t >> 6, lane = t & 63;
  if (lane == 0) { rs[wid] = s; rq[wid] = sq; }
  __syncthreads();
  if (t == 0) {
    rs[0] = rs[0] + rs[1] + rs[2] + rs[3];
    rq[0] = rq[0] + rq[1] + rq[2] + rq[3];
  }
  __syncthreads();
  const float mu   = rs[0] * (1.f / DI);
  const float var  = rq[0] * (1.f / DI) - mu * mu;
  const float rstd = 1.f / sqrtf(var + EPS_);
#pragma unroll
  for (int r = 0; r < 3; ++r) {
    int d = r * 256 + t;
    float o = (v[r] - mu) * rstd * nw[d] + nb[d];
    float p = o * z[row * DI + d];
    u16 h, l;
    bsplit(p, h, l);
    yh[row * DI + d] = h;
    yl[row * DI + d] = l;
  }
}

extern "C" void kernel_launch(void* const* d_in, const int* in_sizes, int n_in,
                              void* d_out, int out_size, void* d_ws, size_t ws_size,
                              hipStream_t stream)
{
  const float* u    = (const float*)d_in[0];
  const float* ipw  = (const float*)d_in[1];
  const float* cw   = (const float*)d_in[2];
  const float* cb   = (const float*)d_in[3];
  const float* dtb  = (const float*)d_in[4];
  const float* Alog = (const float*)d_in[5];
  const float* Dp   = (const float*)d_in[6];
  const float* nw   = (const float*)d_in[7];
  const float* nb   = (const float*)d_in[8];
  const float* opw  = (const float*)d_in[9];
  float* out = (float*)d_out;

  float* ws = (float*)d_ws;
  size_t off = 0;
  float* z_buf   = ws + off; off += (size_t)B_ * L_ * DI;
  u16*   xBC16   = (u16*)(ws + off); off += (size_t)B_ * L_ * CONVD / 2;
  float* dt_buf  = ws + off; off += (size_t)B_ * L_ * NH;
  float* x_buf   = ws + off; off += (size_t)B_ * L_ * DI;
  float* y_buf   = ws + off; off += (size_t)B_ * L_ * DI;
  u16*   Bh_buf  = (u16*)(ws + off); off += (size_t)B_ * L_ * DS / 2;
  u16*   Ch_buf  = (u16*)(ws + off); off += (size_t)B_ * L_ * DS / 2;
  float* dAcs    = ws + off; off += (size_t)B_ * L_ * NH;
  float* cdec    = ws + off; off += (size_t)B_ * NCH * NH;
  float* st_buf  = ws + off; off += (size_t)B_ * NCH * NH * HD * DS;
  float* pv_buf  = ws + off; off += (size_t)B_ * NCH * NH * HD * DS;
  u16*   Woh     = (u16*)(ws + off); off += (size_t)DM * DI / 2;
  u16*   Wol     = (u16*)(ws + off); off += (size_t)DM * DI / 2;
  u16*   XTh_buf = (u16*)(ws + off); off += (size_t)B_ * NCH * NH * 4 * 4096 / 2;

  // aliases inside x_buf/y_buf (dead/live windows don't overlap):
  // Ah/Al/Whip live before k_conv writes x; yh/yl live after k_y consumed x via XT
  u16* Ah = (u16*)x_buf;
  u16* Al = Ah + (size_t)B_ * L_ * DM;
  u16* Whip = Al + (size_t)B_ * L_ * DM;
  u16* yh = (u16*)x_buf;
  u16* yl = yh + (size_t)B_ * L_ * DI;

  hipLaunchKernelGGL(k_cvtA, dim3(8, 12, 16), dim3(256), 0, stream, u, Ah, Al);
  hipLaunchKernelGGL(k_cvtWh, dim3((NIP * DM / 4 + 255) / 256), dim3(256), 0, stream,
                     ipw, Whip, NIP * DM / 4);
  hipLaunchKernelGGL(k_cvtW, dim3((DM * DI / 4 + 255) / 256), dim3(256), 0, stream,
                     opw, Woh, Wol, DM, DI, DM * DI / 4);
  hipLaunchKernelGGL(k_dtp, dim3(64), dim3(256), 0, stream,
                     u, ipw, dtb, Alog, dt_buf, dAcs, cdec);
  hipLaunchKernelGGL(k_gemm1, dim3(128, 13), dim3(256), 0, stream,
                     Ah, Al, Whip, z_buf, xBC16);
  hipLaunchKernelGGL(k_conv, dim3(56, 2, 16), dim3(256), 0, stream,
                     xBC16, cw, cb, x_buf, Bh_buf, Ch_buf);
  hipLaunchKernelGGL(k_cvtX, dim3(64, 4, 12), dim3(256), 0, stream,
                     x_buf, XTh_buf);
  hipLaunchKernelGGL(k_states, dim3(64, 12), dim3(256), 0, stream,
                     XTh_buf, Bh_buf, dt_buf, dAcs, st_buf);
  hipLaunchKernelGGL(k_scanc, dim3(3072), dim3(256), 0, stream, st_buf, cdec, pv_buf);
  hipLaunchKernelGGL(k_y, dim3(64, 12, 4), dim3(256), 0, stream,
                     XTh_buf, x_buf, Ch_buf, Bh_buf, dt_buf, dAcs, pv_buf, Dp, y_buf);
  hipLaunchKernelGGL(k_norm, dim3(16384), dim3(256), 0, stream, z_buf, nw, nb, y_buf, yh, yl);
  hipLaunchKernelGGL(k_gemm2, dim3(128, 3), dim3(256), 0, stream, yh, yl, Woh, Wol, out);
}

// Round 13
// 254.005 us; speedup vs baseline: 1.3785x; 1.0790x over previous
//
#include <hip/hip_runtime.h>
#include <hip/hip_bf16.h>

#define B_    16
#define L_    1024
#define DM    384
#define DIP   1676
#define NIP   1664
#define DI    768
#define CONVD 896
#define NH    12
#define HD    64
#define DS    64
#define NCH   4
#define CH    256
#define EPS_  1e-5f

typedef unsigned short u16;
typedef unsigned int   u32;
typedef __attribute__((ext_vector_type(8))) _Float16 f16x8;
typedef __attribute__((ext_vector_type(4))) float f32x4;

union U4 { uint4 v; u16 s[8]; };

// byte offset of 16B slot `slot` in row `row` of a [64][64]-16bit LDS tile (128B rows, XOR swizzle)
#define SWZ(row, slot) (((row) << 7) + ((((slot) ^ ((row) & 7)) & 7) << 4))

// ---- fp16 helpers ----
__device__ __forceinline__ u16 f2h(float v) { return __builtin_bit_cast(u16, (_Float16)v); }
__device__ __forceinline__ float h2f(u16 h) { return (float)__builtin_bit_cast(_Float16, h); }
__device__ __forceinline__ void hsplit(float v, u16& h, u16& l) {
  _Float16 hh = (_Float16)v;
  _Float16 ll = (_Float16)(v - (float)hh);
  h = __builtin_bit_cast(u16, hh);
  l = __builtin_bit_cast(u16, ll);
}

// ---------------- converters ----------------
// u[b,k,l] -> single fp16, transposed to [m][k]
__global__ __launch_bounds__(256) void k_cvtA(const float* __restrict__ u,
                                              u16* __restrict__ Ah)
{
  __shared__ float Ls[32][129];
  const int t  = threadIdx.x;
  const int l0 = blockIdx.x * 128;
  const int k0 = blockIdx.y * 32;
  const int b  = blockIdx.z;
#pragma unroll
  for (int r = 0; r < 4; ++r) {
    int idx = r * 256 + t;
    int kk = idx >> 5, q = idx & 31;
    float4 v = *(const float4*)&u[((size_t)(b * DM + k0 + kk)) * L_ + l0 + q * 4];
    Ls[kk][q * 4 + 0] = v.x; Ls[kk][q * 4 + 1] = v.y;
    Ls[kk][q * 4 + 2] = v.z; Ls[kk][q * 4 + 3] = v.w;
  }
  __syncthreads();
#pragma unroll
  for (int it = 0; it < 2; ++it) {
    int task = it * 256 + t;
    int l = task >> 2, kq = (task & 3) * 8;
    u32 hw[4];
#pragma unroll
    for (int j = 0; j < 4; ++j) {
      u16 h0 = f2h(Ls[kq + 2 * j + 0][l]);
      u16 h1 = f2h(Ls[kq + 2 * j + 1][l]);
      hw[j] = (u32)h0 | ((u32)h1 << 16);
    }
    size_t off = ((size_t)(b * L_ + l0 + l)) * DM + k0 + kq;
    *(uint4*)&Ah[off] = make_uint4(hw[0], hw[1], hw[2], hw[3]);
  }
}

__global__ __launch_bounds__(256) void k_cvtWh(const float* __restrict__ W,
                                               u16* __restrict__ Wh, int total4)
{
  int i = blockIdx.x * 256 + threadIdx.x;
  if (i >= total4) return;
  int e = i * 4;
  float4 v = *(const float4*)&W[e];
  u16 h[4] = {f2h(v.x), f2h(v.y), f2h(v.z), f2h(v.w)};
  *(uint2*)&Wh[e] = make_uint2((u32)h[0] | ((u32)h[1] << 16), (u32)h[2] | ((u32)h[3] << 16));
}

// ---------------- k_cvtX: x fp32 -> per-(bc,hh,jblk) [64p][64j] fp16 tile (pre-swizzled) ----------------
__global__ __launch_bounds__(256) void k_cvtX(const float* __restrict__ x,
                                              u16* __restrict__ XTh)
{
  __shared__ float xf2[64][65];
  const int t  = threadIdx.x;
  const int bc = blockIdx.x;
  const int jb = blockIdx.y;
  const int hh = blockIdx.z;
  const size_t rbase = (size_t)bc * 256 + jb * 64;
#pragma unroll
  for (int i = 0; i < 4; ++i) {
    int idx = i * 256 + t;
    int j = idx >> 4, p4 = (idx & 15) * 4;
    float4 v = *(const float4*)&x[(rbase + j) * DI + hh * HD + p4];
    xf2[p4 + 0][j] = v.x; xf2[p4 + 1][j] = v.y;
    xf2[p4 + 2][j] = v.z; xf2[p4 + 3][j] = v.w;
  }
  __syncthreads();
  const size_t tileByte = ((size_t)(bc * NH + hh) * 4 + jb) * 8192;
#pragma unroll
  for (int i = 0; i < 2; ++i) {
    int task = i * 256 + t;
    int p = task >> 3, slot = task & 7, jg = slot * 8;
    U4 H;
#pragma unroll
    for (int k = 0; k < 8; ++k) H.s[k] = f2h(xf2[p][jg + k]);
    *(uint4*)((char*)XTh + tileByte + SWZ(p, slot)) = H.v;
  }
}

// ---------------- K_dtp: dt logits from u (fp32) + softplus + chunk cumsum ----------------
__global__ __launch_bounds__(256) void k_dtp(
    const float* __restrict__ u, const float* __restrict__ ipw,
    const float* __restrict__ dtb, const float* __restrict__ A_log,
    float* __restrict__ dt, float* __restrict__ dAcs, float* __restrict__ cdecay)
{
  __shared__ float Ls[64][256];
  __shared__ float wdt[NH * DM];
  __shared__ float ws4[4];
  const int bc = blockIdx.x;
  const int b  = bc >> 2, l0 = (bc & 3) * 256;
  const int t  = threadIdx.x;
  const int lane = t & 63, w = t >> 6;
#pragma unroll
  for (int i = 0; i < 18; ++i) wdt[i * 256 + t] = ipw[(size_t)NIP * DM + i * 256 + t];
  float acc[NH] = {};
  for (int k0 = 0; k0 < DM; k0 += 64) {
    __syncthreads();
#pragma unroll
    for (int it = 0; it < 16; ++it) {
      int idx = it * 256 + t;
      int kk = idx >> 6, q4 = (idx & 63) * 4;
      *(float4*)&Ls[kk][q4] = *(const float4*)&u[((size_t)(b * DM + k0 + kk)) * L_ + l0 + q4];
    }
    __syncthreads();
    for (int k = 0; k < 64; ++k) {
      float uv = Ls[k][t];
#pragma unroll
      for (int h = 0; h < NH; ++h)
        acc[h] = fmaf(uv, wdt[h * DM + k0 + k], acc[h]);
    }
  }
  const size_t row = (size_t)bc * 256 + t;
#pragma unroll
  for (int h = 0; h < NH; ++h) {
    float logit = acc[h] + dtb[h];
    float dtv = (logit > 20.f) ? logit : log1pf(expf(logit));
    dt[row * NH + h] = dtv;
    float xv = dtv * (-expf(A_log[h]));
#pragma unroll
    for (int off = 1; off < 64; off <<= 1) {
      float y = __shfl_up(xv, off, 64);
      if (lane >= off) xv += y;
    }
    __syncthreads();
    if (lane == 63) ws4[w] = xv;
    __syncthreads();
    float add = 0.f;
#pragma unroll
    for (int i = 0; i < 4; ++i) if (i < w) add += ws4[i];
    xv += add;
    dAcs[row * NH + h] = xv;
    if (t == 255) cdecay[bc * NH + h] = expf(xv);
  }
}

// 2-stream staging (A, W) of one 128x32 u16 K-tile set
#define STAGE2(bufbase, k0) do {                                                                \
  _Pragma("unroll")                                                                             \
  for (int i_ = 0; i_ < 2; ++i_) {                                                              \
    int S_ = i_ * 256 + t;                                                                      \
    int m_ = S_ >> 2;                                                                           \
    int g_ = (S_ ^ (m_ >> 1)) & 3;                                                              \
    size_t goff_ = (size_t)m_ * DM + (k0) + g_ * 8;                                             \
    __builtin_amdgcn_global_load_lds((const __attribute__((address_space(1))) u32*)(g0 + goff_),\
        (__attribute__((address_space(3))) u32*)(lds + (bufbase) + S_ * 8), 16, 0, 0);          \
    __builtin_amdgcn_global_load_lds((const __attribute__((address_space(1))) u32*)(g2 + goff_),\
        (__attribute__((address_space(3))) u32*)(lds + (bufbase) + 4096 + S_ * 8), 16, 0, 0);   \
  }                                                                                             \
} while (0)

// ---------------- fp16 single MFMA GEMM: in_proj ----------------
__global__ __launch_bounds__(256) void k_gemm1(
    const u16* __restrict__ Ah,
    const u16* __restrict__ Wh,
    float* __restrict__ z, u16* __restrict__ xBC)
{
  __shared__ u16 lds[16384];   // 2 x 16KB buffers (2 streams x 8KB)
  const int t = threadIdx.x;
  const int lane = t & 63, wid = t >> 6;
  const int wr = wid >> 1, wc = wid & 1;
  const int gg = lane >> 4, mlo = lane & 15;
  const int m0 = blockIdx.x * 128, n0 = blockIdx.y * 128;
  f32x4 acc[4][4];
#pragma unroll
  for (int i = 0; i < 4; ++i)
#pragma unroll
    for (int j = 0; j < 4; ++j) acc[i][j] = (f32x4){0.f, 0.f, 0.f, 0.f};
  const u16* g0 = Ah + (size_t)m0 * DM;
  const u16* g2 = Wh + (size_t)n0 * DM;
  STAGE2(0, 0);
  __syncthreads();
  int cur = 0;
  for (int kt = 0; kt < DM / 32; ++kt) {
    if (kt + 1 < DM / 32) STAGE2((cur ^ 1) * 8192, (kt + 1) * 32);
    const char* ldsb = (const char*)lds + cur * 16384;
    f16x8 fa[4], fb[4];
#pragma unroll
    for (int mf = 0; mf < 4; ++mf) {
      int m = wr * 64 + mf * 16 + mlo;
      int off = m * 64 + (((gg ^ (m >> 1)) & 3) << 4);
      fa[mf]  = *(const f16x8*)(ldsb + off);
    }
#pragma unroll
    for (int nf = 0; nf < 4; ++nf) {
      int n = wc * 64 + nf * 16 + mlo;
      int off = n * 64 + (((gg ^ (n >> 1)) & 3) << 4);
      fb[nf]  = *(const f16x8*)(ldsb + 8192 + off);
    }
#pragma unroll
    for (int mf = 0; mf < 4; ++mf)
#pragma unroll
      for (int nf = 0; nf < 4; ++nf)
        acc[mf][nf] = __builtin_amdgcn_mfma_f32_16x16x32_f16(fa[mf], fb[nf], acc[mf][nf], 0, 0, 0);
    __syncthreads();
    cur ^= 1;
  }
  const int rb = m0 + wr * 64 + (lane >> 4) * 4;
  const int cb = n0 + wc * 64 + mlo;
#pragma unroll
  for (int mf = 0; mf < 4; ++mf)
#pragma unroll
    for (int nf = 0; nf < 4; ++nf) {
      int col = cb + nf * 16;
#pragma unroll
      for (int r = 0; r < 4; ++r) {
        int row = rb + mf * 16 + r;
        float v = acc[mf][nf][r];
        if (col < DI) z[(size_t)row * DI + col] = v;
        else xBC[(size_t)row * CONVD + (col - DI)] = f2h(v);
      }
    }
}

// 3-stream staging for gemm2 (yh, yl, W)
#define STAGE3B(bufbase, k0) do {                                                               \
  _Pragma("unroll")                                                                             \
  for (int i_ = 0; i_ < 2; ++i_) {                                                              \
    int S_ = i_ * 256 + t;                                                                      \
    int m_ = S_ >> 2;                                                                           \
    int g_ = (S_ ^ (m_ >> 1)) & 3;                                                              \
    size_t goff_ = (size_t)m_ * DI + (k0) + g_ * 8;                                             \
    __builtin_amdgcn_global_load_lds((const __attribute__((address_space(1))) u32*)(g0 + goff_),\
        (__attribute__((address_space(3))) u32*)(lds + (bufbase) + S_ * 8), 16, 0, 0);          \
    __builtin_amdgcn_global_load_lds((const __attribute__((address_space(1))) u32*)(g1 + goff_),\
        (__attribute__((address_space(3))) u32*)(lds + (bufbase) + 4096 + S_ * 8), 16, 0, 0);   \
    __builtin_amdgcn_global_load_lds((const __attribute__((address_space(1))) u32*)(g2 + goff_),\
        (__attribute__((address_space(3))) u32*)(lds + (bufbase) + 8192 + S_ * 8), 16, 0, 0);   \
  }                                                                                             \
} while (0)

// ---------------- fp16x2 MFMA GEMM: out_proj (y pair x W single) ----------------
__global__ __launch_bounds__(256) void k_gemm2(
    const u16* __restrict__ Ah, const u16* __restrict__ Al,
    const u16* __restrict__ Bh,
    float* __restrict__ out)
{
  __shared__ u16 lds[24576];
  const int t = threadIdx.x;
  const int lane = t & 63, wid = t >> 6;
  const int wr = wid >> 1, wc = wid & 1;
  const int gg = lane >> 4, mlo = lane & 15;
  const int m0 = blockIdx.x * 128, n0 = blockIdx.y * 128;
  f32x4 acc[4][4];
#pragma unroll
  for (int i = 0; i < 4; ++i)
#pragma unroll
    for (int j = 0; j < 4; ++j) acc[i][j] = (f32x4){0.f, 0.f, 0.f, 0.f};
  const u16* g0 = Ah + (size_t)m0 * DI;
  const u16* g1 = Al + (size_t)m0 * DI;
  const u16* g2 = Bh + (size_t)n0 * DI;
  STAGE3B(0, 0);
  __syncthreads();
  int cur = 0;
  for (int kt = 0; kt < DI / 32; ++kt) {
    if (kt + 1 < DI / 32) STAGE3B((cur ^ 1) * 12288, (kt + 1) * 32);
    const char* ldsb = (const char*)lds + cur * 24576;
    f16x8 fa[4], fal[4], fb[4];
#pragma unroll
    for (int mf = 0; mf < 4; ++mf) {
      int m = wr * 64 + mf * 16 + mlo;
      int off = m * 64 + (((gg ^ (m >> 1)) & 3) << 4);
      fa[mf]  = *(const f16x8*)(ldsb + off);
      fal[mf] = *(const f16x8*)(ldsb + 8192 + off);
    }
#pragma unroll
    for (int nf = 0; nf < 4; ++nf) {
      int n = wc * 64 + nf * 16 + mlo;
      int off = n * 64 + (((gg ^ (n >> 1)) & 3) << 4);
      fb[nf]  = *(const f16x8*)(ldsb + 16384 + off);
    }
#pragma unroll
    for (int mf = 0; mf < 4; ++mf)
#pragma unroll
      for (int nf = 0; nf < 4; ++nf) {
        acc[mf][nf] = __builtin_amdgcn_mfma_f32_16x16x32_f16(fa[mf],  fb[nf], acc[mf][nf], 0, 0, 0);
        acc[mf][nf] = __builtin_amdgcn_mfma_f32_16x16x32_f16(fal[mf], fb[nf], acc[mf][nf], 0, 0, 0);
      }
    __syncthreads();
    cur ^= 1;
  }
  const int rb = m0 + wr * 64 + (lane >> 4) * 4;
  const int cb = n0 + wc * 64 + mlo;
#pragma unroll
  for (int mf = 0; mf < 4; ++mf)
#pragma unroll
    for (int nf = 0; nf < 4; ++nf) {
      int col = cb + nf * 16;
#pragma unroll
      for (int r = 0; r < 4; ++r) {
        int row = rb + mf * 16 + r;
        int b = row >> 10, l = row & 1023;
        out[((size_t)(b * DM + col)) * L_ + l] = acc[mf][nf][r];
      }
    }
}

// ---------------- K2: LDS-tiled depthwise conv; xBC fp16 in; x fp32, B/C single fp16 out ----------------
#define CC 16
__global__ __launch_bounds__(256) void k_conv(
    const u16* __restrict__ xBC, const float* __restrict__ cw,
    const float* __restrict__ cb,
    float* __restrict__ x,
    u16* __restrict__ Bh,
    u16* __restrict__ Chh)
{
  __shared__ float Ls[18][32][CC];
  const int t  = threadIdx.x;
  const int c0 = blockIdx.x * CC;
  const int h0 = blockIdx.y * 16;
  const int b  = blockIdx.z;
#pragma unroll
  for (int k = 0; k < 9; ++k) {
    int f = k * 256 + t;
    int fc4 = f & 3, fw = (f >> 2) & 31, fr = f >> 7;
    int h = h0 + fr - 1;
    U4 v; v.v = make_uint4(0, 0, 0, 0);
    if (h >= 0 && h < 32) {
      uint2 p = *(const uint2*)&xBC[((size_t)(b * 1024 + h * 32 + fw)) * CONVD + c0 + fc4 * 4];
      v.v.x = p.x; v.v.y = p.y;
    }
    Ls[fr][fw][fc4 * 4 + 0] = h2f(v.s[0]);
    Ls[fr][fw][fc4 * 4 + 1] = h2f(v.s[1]);
    Ls[fr][fw][fc4 * 4 + 2] = h2f(v.s[2]);
    Ls[fr][fw][fc4 * 4 + 3] = h2f(v.s[3]);
  }
  const int c4 = t & 3;
  const int w  = (t >> 2) & 31;
  const int hb = t >> 7;
  float wt[4][9];
  float bias[4];
#pragma unroll
  for (int j = 0; j < 4; ++j) {
    int c = c0 + c4 * 4 + j;
    bias[j] = cb[c];
#pragma unroll
    for (int kb = 0; kb < 9; ++kb) wt[j][kb] = cw[c * 9 + kb];
  }
  __syncthreads();
#pragma unroll
  for (int k = 0; k < 8; ++k) {
    int h = hb * 8 + k;
    float acc[4] = {bias[0], bias[1], bias[2], bias[3]};
#pragma unroll
    for (int dh = 0; dh < 3; ++dh) {
#pragma unroll
      for (int dw = -1; dw <= 1; ++dw) {
        int ww = w + dw;
        if (ww < 0 || ww > 31) continue;
        const float* p = &Ls[h + dh][ww][c4 * 4];
        int kb = dh * 3 + (dw + 1);
#pragma unroll
        for (int j = 0; j < 4; ++j) acc[j] = fmaf(p[j], wt[j][kb], acc[j]);
      }
    }
    float s4[4];
#pragma unroll
    for (int j = 0; j < 4; ++j) { float v = acc[j]; s4[j] = v / (1.f + expf(-v)); }
    size_t row = (size_t)b * 1024 + (h0 + h) * 32 + w;
    int c = c0 + c4 * 4;
    if (c < DI) {
      *(float4*)&x[row * DI + c] = make_float4(s4[0], s4[1], s4[2], s4[3]);
    } else {
      u16 hv[4] = {f2h(s4[0]), f2h(s4[1]), f2h(s4[2]), f2h(s4[3])};
      uint2 hp = make_uint2((u32)hv[0] | ((u32)hv[1] << 16), (u32)hv[2] | ((u32)hv[3] << 16));
      if (c < DI + DS) *(uint2*)&Bh[row * DS + (c - DI)] = hp;
      else             *(uint2*)&Chh[row * DS + (c - DI - DS)] = hp;
    }
  }
}

// stage one pre-swizzled 8KB XT tile into LDS via linear DMA
#define STAGE_XT(tileByte) do {                                                                   \
  _Pragma("unroll")                                                                               \
  for (int i_ = 0; i_ < 2; ++i_) {                                                                \
    int S_ = i_ * 256 + t;                                                                        \
    __builtin_amdgcn_global_load_lds(                                                             \
        (const __attribute__((address_space(1))) u32*)((const char*)XTh + (tileByte) + S_ * 16),  \
        (__attribute__((address_space(3))) u32*)((char*)Xh_t + S_ * 16), 16, 0, 0);               \
  }                                                                                               \
} while (0)

// ---------------- K5: chunk states via MFMA ----------------
__global__ __launch_bounds__(256) void k_states(
    const u16* __restrict__ XTh,
    const u16* __restrict__ Bh,
    const float* __restrict__ dt, const float* __restrict__ dAcs,
    float* __restrict__ states)
{
  __shared__ u16 bpackB[64 * 65];
  __shared__ u16 BTh_t[4096];
  __shared__ u16 Xh_t[4096];
  __shared__ float wall[256];
  const int bc = blockIdx.x;
  const int hh = blockIdx.y;
  const int t  = threadIdx.x;
  const int lane = t & 63, w = t >> 6;
  const int mlo = lane & 15, gg = lane >> 4;
  const int r = t >> 2, q = (t & 3) * 16;
  const size_t base = (size_t)bc * 256;
  const float last = dAcs[(base + 255) * NH + hh];
  wall[t] = expf(last - dAcs[(base + t) * NH + hh]) * dt[(base + t) * NH + hh];
  f32x4 acc[4];
#pragma unroll
  for (int i = 0; i < 4; ++i) acc[i] = (f32x4){0.f, 0.f, 0.f, 0.f};
  for (int jt = 0; jt < 4; ++jt) {
    const int j0 = jt * 64;
    __syncthreads();
    STAGE_XT(((size_t)(bc * NH + hh) * 4 + jt) * 8192);
    {
      const u16* bhp = &Bh[(size_t)(base + j0 + r) * DS + q];
      U4 H0, H1;
      H0.v = *(const uint4*)bhp; H1.v = *(const uint4*)(bhp + 8);
#pragma unroll
      for (int k = 0; k < 8; ++k) {
        bpackB[r * 65 + q + k]     = H0.s[k];
        bpackB[r * 65 + q + 8 + k] = H1.s[k];
      }
    }
    __syncthreads();
#pragma unroll
    for (int c = 0; c < 2; ++c) {
      U4 BH;
#pragma unroll
      for (int jj = 0; jj < 8; ++jj) {
        int j = q + c * 8 + jj;
        BH.s[jj] = f2h(h2f(bpackB[j * 65 + r]) * wall[j0 + j]);
      }
      *(uint4*)((char*)BTh_t + SWZ(r, (q >> 3) + c)) = BH.v;
    }
    __syncthreads();
#pragma unroll
    for (int s = 0; s < 2; ++s) {
      f16x8 fah = *(const f16x8*)((const char*)Xh_t + SWZ(w * 16 + mlo, s * 4 + gg));
#pragma unroll
      for (int nf = 0; nf < 4; ++nf) {
        f16x8 fbh = *(const f16x8*)((const char*)BTh_t + SWZ(nf * 16 + mlo, s * 4 + gg));
        acc[nf] = __builtin_amdgcn_mfma_f32_16x16x32_f16(fah, fbh, acc[nf], 0, 0, 0);
      }
    }
  }
  const size_t sb = ((size_t)(bc * NH + hh)) << 12;
#pragma unroll
  for (int nf = 0; nf < 4; ++nf)
#pragma unroll
    for (int reg = 0; reg < 4; ++reg) {
      int p = w * 16 + (lane >> 4) * 4 + reg;
      int n = nf * 16 + mlo;
      states[sb + (size_t)p * 64 + n] = acc[nf][reg];
    }
}

// ---------------- K6: inter-chunk scan ----------------
__global__ __launch_bounds__(256) void k_scanc(
    const float* __restrict__ states, const float* __restrict__ cdecay,
    float* __restrict__ prev)
{
  int tid = blockIdx.x * 256 + threadIdx.x;
  int pn  = tid & 4095;
  int rem = tid >> 12;
  int hh  = rem % NH;
  int b   = rem / NH;
  float carry = 0.f;
#pragma unroll
  for (int c = 0; c < 4; ++c) {
    size_t idx = ((size_t)((b * 4 + c) * NH + hh) << 12) + pn;
    prev[idx] = carry;
    carry = carry * cdecay[(b * 4 + c) * NH + hh] + states[idx];
  }
}

// ---------------- K7: y = intra + inter + D*x ----------------
__global__ __launch_bounds__(256) void k_y(
    const u16* __restrict__ XTh,
    const float* __restrict__ x,
    const u16* __restrict__ Chg, const u16* __restrict__ Bhg,
    const float* __restrict__ dtp, const float* __restrict__ dAcs,
    const float* __restrict__ prev, const float* __restrict__ Dp,
    float* __restrict__ y)
{
  __shared__ u16 Pb_t[4096];
  __shared__ u16 Xh_t[4096];
  __shared__ u16 att_t[4096];
  __shared__ float dAc_s[256], dt_s[256], ei_s[64];
  const int bc = blockIdx.x;
  const int hh = blockIdx.y;
  const int it = blockIdx.z;
  const int t  = threadIdx.x;
  const int lane = t & 63, w = t >> 6;
  const int mlo = lane & 15, gg = lane >> 4;
  const int r = t >> 2, q = (t & 3) * 16;
  const int slot0 = q >> 3;
  const size_t base = (size_t)bc * 256;
  const int i0 = it * 64;
  {
    float da = dAcs[(base + t) * NH + hh];
    dAc_s[t] = da;
    dt_s[t]  = dtp[(base + t) * NH + hh];
    if (t < 64) ei_s[t] = expf(dAcs[(base + i0 + t) * NH + hh]);
  }
  {
    const float* pp = &prev[(((size_t)(bc * NH + hh)) << 12) + (size_t)r * 64 + q];
    U4 H0, H1;
#pragma unroll
    for (int k = 0; k < 16; ++k) {
      u16 h = f2h(pp[k]);
      if (k < 8) H0.s[k] = h; else H1.s[k - 8] = h;
    }
    *(uint4*)((char*)Pb_t + SWZ(r, slot0))     = H0.v;
    *(uint4*)((char*)Pb_t + SWZ(r, slot0 + 1)) = H1.v;
  }
  __syncthreads();
  f16x8 fc[2];
#pragma unroll
  for (int s = 0; s < 2; ++s)
    fc[s] = *(const f16x8*)&Chg[(size_t)(base + i0 + w * 16 + mlo) * DS + (s * 4 + gg) * 8];
  f32x4 accy[4];
#pragma unroll
  for (int i = 0; i < 4; ++i) accy[i] = (f32x4){0.f, 0.f, 0.f, 0.f};
#pragma unroll
  for (int s = 0; s < 2; ++s)
#pragma unroll
    for (int pf = 0; pf < 4; ++pf) {
      f16x8 fph = *(const f16x8*)((const char*)Pb_t + SWZ(pf * 16 + mlo, s * 4 + gg));
      accy[pf] = __builtin_amdgcn_mfma_f32_16x16x32_f16(fc[s], fph, accy[pf], 0, 0, 0);
    }
  const int ilb = w * 16 + (lane >> 4) * 4;
#pragma unroll
  for (int pf = 0; pf < 4; ++pf)
#pragma unroll
    for (int reg = 0; reg < 4; ++reg)
      accy[pf][reg] *= ei_s[ilb + reg];

  for (int jt = 0; jt <= it; ++jt) {
    __syncthreads();
    STAGE_XT(((size_t)(bc * NH + hh) * 4 + jt) * 8192);
    {
      const u16* bh = &Bhg[(size_t)(base + jt * 64 + r) * DS + q];
      *(uint4*)((char*)Pb_t + SWZ(r, slot0))     = *(const uint4*)bh;
      *(uint4*)((char*)Pb_t + SWZ(r, slot0 + 1)) = *(const uint4*)(bh + 8);
    }
    __syncthreads();
    f32x4 g[4];
#pragma unroll
    for (int i = 0; i < 4; ++i) g[i] = (f32x4){0.f, 0.f, 0.f, 0.f};
#pragma unroll
    for (int s = 0; s < 2; ++s)
#pragma unroll
      for (int jf = 0; jf < 4; ++jf) {
        f16x8 fbh = *(const f16x8*)((const char*)Pb_t + SWZ(jf * 16 + mlo, s * 4 + gg));
        g[jf] = __builtin_amdgcn_mfma_f32_16x16x32_f16(fc[s], fbh, g[jf], 0, 0, 0);
      }
#pragma unroll
    for (int jf = 0; jf < 4; ++jf)
#pragma unroll
      for (int reg = 0; reg < 4; ++reg) {
        int il = i0 + ilb + reg;
        int jl = jt * 64 + jf * 16 + mlo;
        float av = (jl <= il) ? g[jf][reg] * expf(dAc_s[il] - dAc_s[jl]) * dt_s[jl] : 0.f;
        *(u16*)((char*)att_t + SWZ(il & 63, (jl & 63) >> 3) + (jl & 7) * 2) = f2h(av);
      }
#pragma unroll
    for (int s = 0; s < 2; ++s) {
      f16x8 fa = *(const f16x8*)((const char*)att_t + SWZ(w * 16 + mlo, s * 4 + gg));
#pragma unroll
      for (int pf = 0; pf < 4; ++pf) {
        f16x8 fxh = *(const f16x8*)((const char*)Xh_t + SWZ(pf * 16 + mlo, s * 4 + gg));
        accy[pf] = __builtin_amdgcn_mfma_f32_16x16x32_f16(fa, fxh, accy[pf], 0, 0, 0);
      }
    }
  }
  const float Dh = Dp[hh];
#pragma unroll
  for (int pf = 0; pf < 4; ++pf)
#pragma unroll
    for (int reg = 0; reg < 4; ++reg) {
      size_t row = base + i0 + ilb + reg;
      int col = hh * HD + pf * 16 + mlo;
      y[row * DI + col] = accy[pf][reg] + Dh * x[row * DI + col];
    }
}

// ---------------- K8: LayerNorm * z -> fp16 hi/lo pair ----------------
__global__ __launch_bounds__(256) void k_norm(
    const float* __restrict__ z, const float* __restrict__ nw,
    const float* __restrict__ nb, const float* __restrict__ y,
    u16* __restrict__ yh, u16* __restrict__ yl)
{
  __shared__ float rs[4], rq[4];
  const size_t row = blockIdx.x;
  const int t = threadIdx.x;
  float v[3];
  float s = 0.f, sq = 0.f;
#pragma unroll
  for (int r = 0; r < 3; ++r) {
    v[r] = y[row * DI + r * 256 + t];
    s += v[r];
    sq = fmaf(v[r], v[r], sq);
  }
#pragma unroll
  for (int off = 32; off > 0; off >>= 1) {
    s  += __shfl_down(s, off, 64);
    sq += __shfl_down(sq, off, 64);
  }
  const int wid = t >> 6, lane = t & 63;
  if (lane == 0) { rs[wid] = s; rq[wid] = sq; }
  __syncthreads();
  if (t == 0) {
    rs[0] = rs[0] + rs[1] + rs[2] + rs[3];
    rq[0] = rq[0] + rq[1] + rq[2] + rq[3];
  }
  __syncthreads();
  const float mu   = rs[0] * (1.f / DI);
  const float var  = rq[0] * (1.f / DI) - mu * mu;
  const float rstd = 1.f / sqrtf(var + EPS_);
#pragma unroll
  for (int r = 0; r < 3; ++r) {
    int d = r * 256 + t;
    float o = (v[r] - mu) * rstd * nw[d] + nb[d];
    float p = o * z[row * DI + d];
    u16 h, l;
    hsplit(p, h, l);
    yh[row * DI + d] = h;
    yl[row * DI + d] = l;
  }
}

extern "C" void kernel_launch(void* const* d_in, const int* in_sizes, int n_in,
                              void* d_out, int out_size, void* d_ws, size_t ws_size,
                              hipStream_t stream)
{
  const float* u    = (const float*)d_in[0];
  const float* ipw  = (const float*)d_in[1];
  const float* cw   = (const float*)d_in[2];
  const float* cb   = (const float*)d_in[3];
  const float* dtb  = (const float*)d_in[4];
  const float* Alog = (const float*)d_in[5];
  const float* Dp   = (const float*)d_in[6];
  const float* nw   = (const float*)d_in[7];
  const float* nb   = (const float*)d_in[8];
  const float* opw  = (const float*)d_in[9];
  float* out = (float*)d_out;

  float* ws = (float*)d_ws;
  size_t off = 0;
  float* z_buf   = ws + off; off += (size_t)B_ * L_ * DI;
  u16*   xBC16   = (u16*)(ws + off); off += (size_t)B_ * L_ * CONVD / 2;
  float* dt_buf  = ws + off; off += (size_t)B_ * L_ * NH;
  float* x_buf   = ws + off; off += (size_t)B_ * L_ * DI;
  float* y_buf   = ws + off; off += (size_t)B_ * L_ * DI;
  u16*   Bh_buf  = (u16*)(ws + off); off += (size_t)B_ * L_ * DS / 2;
  u16*   Ch_buf  = (u16*)(ws + off); off += (size_t)B_ * L_ * DS / 2;
  float* dAcs    = ws + off; off += (size_t)B_ * L_ * NH;
  float* cdec    = ws + off; off += (size_t)B_ * NCH * NH;
  float* st_buf  = ws + off; off += (size_t)B_ * NCH * NH * HD * DS;
  float* pv_buf  = ws + off; off += (size_t)B_ * NCH * NH * HD * DS;
  u16*   Woh     = (u16*)(ws + off); off += (size_t)DM * DI / 2;
  u16*   XTh_buf = (u16*)(ws + off); off += (size_t)B_ * NCH * NH * 4 * 4096 / 2;

  // aliases inside x_buf (dead/live windows don't overlap):
  u16* Ah = (u16*)x_buf;                         // 16384*384 fp16 (single)
  u16* Whip = Ah + (size_t)B_ * L_ * DM;         // 1664*384 fp16
  u16* yh = (u16*)x_buf;                         // 16384*768 fp16 pair
  u16* yl = yh + (size_t)B_ * L_ * DI;

  hipLaunchKernelGGL(k_cvtA, dim3(8, 12, 16), dim3(256), 0, stream, u, Ah);
  hipLaunchKernelGGL(k_cvtWh, dim3((NIP * DM / 4 + 255) / 256), dim3(256), 0, stream,
                     ipw, Whip, NIP * DM / 4);
  hipLaunchKernelGGL(k_cvtWh, dim3((DM * DI / 4 + 255) / 256), dim3(256), 0, stream,
                     opw, Woh, DM * DI / 4);
  hipLaunchKernelGGL(k_dtp, dim3(64), dim3(256), 0, stream,
                     u, ipw, dtb, Alog, dt_buf, dAcs, cdec);
  hipLaunchKernelGGL(k_gemm1, dim3(128, 13), dim3(256), 0, stream,
                     Ah, Whip, z_buf, xBC16);
  hipLaunchKernelGGL(k_conv, dim3(56, 2, 16), dim3(256), 0, stream,
                     xBC16, cw, cb, x_buf, Bh_buf, Ch_buf);
  hipLaunchKernelGGL(k_cvtX, dim3(64, 4, 12), dim3(256), 0, stream,
                     x_buf, XTh_buf);
  hipLaunchKernelGGL(k_states, dim3(64, 12), dim3(256), 0, stream,
                     XTh_buf, Bh_buf, dt_buf, dAcs, st_buf);
  hipLaunchKernelGGL(k_scanc, dim3(3072), dim3(256), 0, stream, st_buf, cdec, pv_buf);
  hipLaunchKernelGGL(k_y, dim3(64, 12, 4), dim3(256), 0, stream,
                     XTh_buf, x_buf, Ch_buf, Bh_buf, dt_buf, dAcs, pv_buf, Dp, y_buf);
  hipLaunchKernelGGL(k_norm, dim3(16384), dim3(256), 0, stream, z_buf, nw, nb, y_buf, yh, yl);
  hipLaunchKernelGGL(k_gemm2, dim3(128, 3), dim3(256), 0, stream, yh, yl, Woh, out);
}

// Round 14
// 239.167 us; speedup vs baseline: 1.4640x; 1.0620x over previous
//
#include <hip/hip_runtime.h>
#include <hip/hip_bf16.h>

#define B_    16
#define L_    1024
#define DM    384
#define DIP   1676
#define NIP   1664
#define DI    768
#define CONVD 896
#define NH    12
#define HD    64
#define DS    64
#define NCH   4
#define CH    256
#define EPS_  1e-5f

typedef unsigned short u16;
typedef unsigned int   u32;
typedef __attribute__((ext_vector_type(8))) _Float16 f16x8;
typedef __attribute__((ext_vector_type(4))) float f32x4;

union U4 { uint4 v; u16 s[8]; };

// byte offset of 16B slot `slot` in row `row` of a [64][64]-16bit LDS tile (128B rows, XOR swizzle)
#define SWZ(row, slot) (((row) << 7) + ((((slot) ^ ((row) & 7)) & 7) << 4))

// ---- fp16 helpers ----
__device__ __forceinline__ u16 f2h(float v) { return __builtin_bit_cast(u16, (_Float16)v); }
__device__ __forceinline__ float h2f(u16 h) { return (float)__builtin_bit_cast(_Float16, h); }
__device__ __forceinline__ void hsplit(float v, u16& h, u16& l) {
  _Float16 hh = (_Float16)v;
  _Float16 ll = (_Float16)(v - (float)hh);
  h = __builtin_bit_cast(u16, hh);
  l = __builtin_bit_cast(u16, ll);
}

// ---------------- converters ----------------
__global__ __launch_bounds__(256) void k_cvtA(const float* __restrict__ u,
                                              u16* __restrict__ Ah)
{
  __shared__ float Ls[32][129];
  const int t  = threadIdx.x;
  const int l0 = blockIdx.x * 128;
  const int k0 = blockIdx.y * 32;
  const int b  = blockIdx.z;
#pragma unroll
  for (int r = 0; r < 4; ++r) {
    int idx = r * 256 + t;
    int kk = idx >> 5, q = idx & 31;
    float4 v = *(const float4*)&u[((size_t)(b * DM + k0 + kk)) * L_ + l0 + q * 4];
    Ls[kk][q * 4 + 0] = v.x; Ls[kk][q * 4 + 1] = v.y;
    Ls[kk][q * 4 + 2] = v.z; Ls[kk][q * 4 + 3] = v.w;
  }
  __syncthreads();
#pragma unroll
  for (int it = 0; it < 2; ++it) {
    int task = it * 256 + t;
    int l = task >> 2, kq = (task & 3) * 8;
    u32 hw[4];
#pragma unroll
    for (int j = 0; j < 4; ++j) {
      u16 h0 = f2h(Ls[kq + 2 * j + 0][l]);
      u16 h1 = f2h(Ls[kq + 2 * j + 1][l]);
      hw[j] = (u32)h0 | ((u32)h1 << 16);
    }
    size_t off = ((size_t)(b * L_ + l0 + l)) * DM + k0 + kq;
    *(uint4*)&Ah[off] = make_uint4(hw[0], hw[1], hw[2], hw[3]);
  }
}

__global__ __launch_bounds__(256) void k_cvtWh(const float* __restrict__ W,
                                               u16* __restrict__ Wh, int total4)
{
  int i = blockIdx.x * 256 + threadIdx.x;
  if (i >= total4) return;
  int e = i * 4;
  float4 v = *(const float4*)&W[e];
  u16 h[4] = {f2h(v.x), f2h(v.y), f2h(v.z), f2h(v.w)};
  *(uint2*)&Wh[e] = make_uint2((u32)h[0] | ((u32)h[1] << 16), (u32)h[2] | ((u32)h[3] << 16));
}

// ---------------- K_dtp: dt logits from u (fp32) + softplus + chunk cumsum ----------------
__global__ __launch_bounds__(256) void k_dtp(
    const float* __restrict__ u, const float* __restrict__ ipw,
    const float* __restrict__ dtb, const float* __restrict__ A_log,
    float* __restrict__ dt, float* __restrict__ dAcs, float* __restrict__ cdecay)
{
  __shared__ float Ls[64][256];
  __shared__ float wdt[NH * DM];
  __shared__ float ws4[4];
  const int bc = blockIdx.x;
  const int b  = bc >> 2, l0 = (bc & 3) * 256;
  const int t  = threadIdx.x;
  const int lane = t & 63, w = t >> 6;
#pragma unroll
  for (int i = 0; i < 18; ++i) wdt[i * 256 + t] = ipw[(size_t)NIP * DM + i * 256 + t];
  float acc[NH] = {};
  for (int k0 = 0; k0 < DM; k0 += 64) {
    __syncthreads();
#pragma unroll
    for (int it = 0; it < 16; ++it) {
      int idx = it * 256 + t;
      int kk = idx >> 6, q4 = (idx & 63) * 4;
      *(float4*)&Ls[kk][q4] = *(const float4*)&u[((size_t)(b * DM + k0 + kk)) * L_ + l0 + q4];
    }
    __syncthreads();
    for (int k = 0; k < 64; ++k) {
      float uv = Ls[k][t];
#pragma unroll
      for (int h = 0; h < NH; ++h)
        acc[h] = fmaf(uv, wdt[h * DM + k0 + k], acc[h]);
    }
  }
  const size_t row = (size_t)bc * 256 + t;
#pragma unroll
  for (int h = 0; h < NH; ++h) {
    float logit = acc[h] + dtb[h];
    float dtv = (logit > 20.f) ? logit : log1pf(expf(logit));
    dt[row * NH + h] = dtv;
    float xv = dtv * (-expf(A_log[h]));
#pragma unroll
    for (int off = 1; off < 64; off <<= 1) {
      float y = __shfl_up(xv, off, 64);
      if (lane >= off) xv += y;
    }
    __syncthreads();
    if (lane == 63) ws4[w] = xv;
    __syncthreads();
    float add = 0.f;
#pragma unroll
    for (int i = 0; i < 4; ++i) if (i < w) add += ws4[i];
    xv += add;
    dAcs[row * NH + h] = xv;
    if (t == 255) cdecay[bc * NH + h] = expf(xv);
  }
}

// 2-stream staging (A, W) of one 128x32 u16 K-tile set
#define STAGE2(bufbase, k0) do {                                                                \
  _Pragma("unroll")                                                                             \
  for (int i_ = 0; i_ < 2; ++i_) {                                                              \
    int S_ = i_ * 256 + t;                                                                      \
    int m_ = S_ >> 2;                                                                           \
    int g_ = (S_ ^ (m_ >> 1)) & 3;                                                              \
    size_t goff_ = (size_t)m_ * DM + (k0) + g_ * 8;                                             \
    __builtin_amdgcn_global_load_lds((const __attribute__((address_space(1))) u32*)(g0 + goff_),\
        (__attribute__((address_space(3))) u32*)(lds + (bufbase) + S_ * 8), 16, 0, 0);          \
    __builtin_amdgcn_global_load_lds((const __attribute__((address_space(1))) u32*)(g2 + goff_),\
        (__attribute__((address_space(3))) u32*)(lds + (bufbase) + 4096 + S_ * 8), 16, 0, 0);   \
  }                                                                                             \
} while (0)

// ---------------- fp16 single MFMA GEMM: in_proj ----------------
__global__ __launch_bounds__(256) void k_gemm1(
    const u16* __restrict__ Ah,
    const u16* __restrict__ Wh,
    float* __restrict__ z, u16* __restrict__ xBC)
{
  __shared__ u16 lds[16384];
  const int t = threadIdx.x;
  const int lane = t & 63, wid = t >> 6;
  const int wr = wid >> 1, wc = wid & 1;
  const int gg = lane >> 4, mlo = lane & 15;
  const int m0 = blockIdx.x * 128, n0 = blockIdx.y * 128;
  f32x4 acc[4][4];
#pragma unroll
  for (int i = 0; i < 4; ++i)
#pragma unroll
    for (int j = 0; j < 4; ++j) acc[i][j] = (f32x4){0.f, 0.f, 0.f, 0.f};
  const u16* g0 = Ah + (size_t)m0 * DM;
  const u16* g2 = Wh + (size_t)n0 * DM;
  STAGE2(0, 0);
  __syncthreads();
  int cur = 0;
  for (int kt = 0; kt < DM / 32; ++kt) {
    if (kt + 1 < DM / 32) STAGE2((cur ^ 1) * 8192, (kt + 1) * 32);
    const char* ldsb = (const char*)lds + cur * 16384;
    f16x8 fa[4], fb[4];
#pragma unroll
    for (int mf = 0; mf < 4; ++mf) {
      int m = wr * 64 + mf * 16 + mlo;
      int off = m * 64 + (((gg ^ (m >> 1)) & 3) << 4);
      fa[mf]  = *(const f16x8*)(ldsb + off);
    }
#pragma unroll
    for (int nf = 0; nf < 4; ++nf) {
      int n = wc * 64 + nf * 16 + mlo;
      int off = n * 64 + (((gg ^ (n >> 1)) & 3) << 4);
      fb[nf]  = *(const f16x8*)(ldsb + 8192 + off);
    }
#pragma unroll
    for (int mf = 0; mf < 4; ++mf)
#pragma unroll
      for (int nf = 0; nf < 4; ++nf)
        acc[mf][nf] = __builtin_amdgcn_mfma_f32_16x16x32_f16(fa[mf], fb[nf], acc[mf][nf], 0, 0, 0);
    __syncthreads();
    cur ^= 1;
  }
  const int rb = m0 + wr * 64 + (lane >> 4) * 4;
  const int cb = n0 + wc * 64 + mlo;
#pragma unroll
  for (int mf = 0; mf < 4; ++mf)
#pragma unroll
    for (int nf = 0; nf < 4; ++nf) {
      int col = cb + nf * 16;
#pragma unroll
      for (int r = 0; r < 4; ++r) {
        int row = rb + mf * 16 + r;
        float v = acc[mf][nf][r];
        if (col < DI) z[(size_t)row * DI + col] = v;
        else xBC[(size_t)row * CONVD + (col - DI)] = f2h(v);
      }
    }
}

// 3-stream staging for gemm2 (yh, yl, W)
#define STAGE3B(bufbase, k0) do {                                                               \
  _Pragma("unroll")                                                                             \
  for (int i_ = 0; i_ < 2; ++i_) {                                                              \
    int S_ = i_ * 256 + t;                                                                      \
    int m_ = S_ >> 2;                                                                           \
    int g_ = (S_ ^ (m_ >> 1)) & 3;                                                              \
    size_t goff_ = (size_t)m_ * DI + (k0) + g_ * 8;                                             \
    __builtin_amdgcn_global_load_lds((const __attribute__((address_space(1))) u32*)(g0 + goff_),\
        (__attribute__((address_space(3))) u32*)(lds + (bufbase) + S_ * 8), 16, 0, 0);          \
    __builtin_amdgcn_global_load_lds((const __attribute__((address_space(1))) u32*)(g1 + goff_),\
        (__attribute__((address_space(3))) u32*)(lds + (bufbase) + 4096 + S_ * 8), 16, 0, 0);   \
    __builtin_amdgcn_global_load_lds((const __attribute__((address_space(1))) u32*)(g2 + goff_),\
        (__attribute__((address_space(3))) u32*)(lds + (bufbase) + 8192 + S_ * 8), 16, 0, 0);   \
  }                                                                                             \
} while (0)

// ---------------- fp16x2 MFMA GEMM: out_proj ----------------
__global__ __launch_bounds__(256) void k_gemm2(
    const u16* __restrict__ Ah, const u16* __restrict__ Al,
    const u16* __restrict__ Bh,
    float* __restrict__ out)
{
  __shared__ u16 lds[24576];
  const int t = threadIdx.x;
  const int lane = t & 63, wid = t >> 6;
  const int wr = wid >> 1, wc = wid & 1;
  const int gg = lane >> 4, mlo = lane & 15;
  const int m0 = blockIdx.x * 128, n0 = blockIdx.y * 128;
  f32x4 acc[4][4];
#pragma unroll
  for (int i = 0; i < 4; ++i)
#pragma unroll
    for (int j = 0; j < 4; ++j) acc[i][j] = (f32x4){0.f, 0.f, 0.f, 0.f};
  const u16* g0 = Ah + (size_t)m0 * DI;
  const u16* g1 = Al + (size_t)m0 * DI;
  const u16* g2 = Bh + (size_t)n0 * DI;
  STAGE3B(0, 0);
  __syncthreads();
  int cur = 0;
  for (int kt = 0; kt < DI / 32; ++kt) {
    if (kt + 1 < DI / 32) STAGE3B((cur ^ 1) * 12288, (kt + 1) * 32);
    const char* ldsb = (const char*)lds + cur * 24576;
    f16x8 fa[4], fal[4], fb[4];
#pragma unroll
    for (int mf = 0; mf < 4; ++mf) {
      int m = wr * 64 + mf * 16 + mlo;
      int off = m * 64 + (((gg ^ (m >> 1)) & 3) << 4);
      fa[mf]  = *(const f16x8*)(ldsb + off);
      fal[mf] = *(const f16x8*)(ldsb + 8192 + off);
    }
#pragma unroll
    for (int nf = 0; nf < 4; ++nf) {
      int n = wc * 64 + nf * 16 + mlo;
      int off = n * 64 + (((gg ^ (n >> 1)) & 3) << 4);
      fb[nf]  = *(const f16x8*)(ldsb + 16384 + off);
    }
#pragma unroll
    for (int mf = 0; mf < 4; ++mf)
#pragma unroll
      for (int nf = 0; nf < 4; ++nf) {
        acc[mf][nf] = __builtin_amdgcn_mfma_f32_16x16x32_f16(fa[mf],  fb[nf], acc[mf][nf], 0, 0, 0);
        acc[mf][nf] = __builtin_amdgcn_mfma_f32_16x16x32_f16(fal[mf], fb[nf], acc[mf][nf], 0, 0, 0);
      }
    __syncthreads();
    cur ^= 1;
  }
  const int rb = m0 + wr * 64 + (lane >> 4) * 4;
  const int cb = n0 + wc * 64 + mlo;
#pragma unroll
  for (int mf = 0; mf < 4; ++mf)
#pragma unroll
    for (int nf = 0; nf < 4; ++nf) {
      int col = cb + nf * 16;
#pragma unroll
      for (int r = 0; r < 4; ++r) {
        int row = rb + mf * 16 + r;
        int b = row >> 10, l = row & 1023;
        out[((size_t)(b * DM + col)) * L_ + l] = acc[mf][nf][r];
      }
    }
}

// ---------------- K2: depthwise conv; x-channels -> pre-swizzled XT fp16 tiles; B/C fp16 ----------------
#define CC 16
__global__ __launch_bounds__(256) void k_conv(
    const u16* __restrict__ xBC, const float* __restrict__ cw,
    const float* __restrict__ cb,
    u16* __restrict__ XTh,
    u16* __restrict__ Bh,
    u16* __restrict__ Chh)
{
  __shared__ float Ls[18][32][CC];   // 36,864 B; reused as u16[16][512] for transpose-out
  const int t  = threadIdx.x;
  const int c0 = blockIdx.x * CC;
  const int h0 = blockIdx.y * 16;
  const int b  = blockIdx.z;
#pragma unroll
  for (int k = 0; k < 9; ++k) {
    int f = k * 256 + t;
    int fc4 = f & 3, fw = (f >> 2) & 31, fr = f >> 7;
    int h = h0 + fr - 1;
    U4 v; v.v = make_uint4(0, 0, 0, 0);
    if (h >= 0 && h < 32) {
      uint2 p = *(const uint2*)&xBC[((size_t)(b * 1024 + h * 32 + fw)) * CONVD + c0 + fc4 * 4];
      v.v.x = p.x; v.v.y = p.y;
    }
    Ls[fr][fw][fc4 * 4 + 0] = h2f(v.s[0]);
    Ls[fr][fw][fc4 * 4 + 1] = h2f(v.s[1]);
    Ls[fr][fw][fc4 * 4 + 2] = h2f(v.s[2]);
    Ls[fr][fw][fc4 * 4 + 3] = h2f(v.s[3]);
  }
  const int c4 = t & 3;
  const int w  = (t >> 2) & 31;
  const int hb = t >> 7;
  float wt[4][9];
  float bias[4];
#pragma unroll
  for (int j = 0; j < 4; ++j) {
    int c = c0 + c4 * 4 + j;
    bias[j] = cb[c];
#pragma unroll
    for (int kb = 0; kb < 9; ++kb) wt[j][kb] = cw[c * 9 + kb];
  }
  __syncthreads();
  const bool isx = (c0 < DI);
  u16 xh16[8][4];
#pragma unroll
  for (int k = 0; k < 8; ++k) {
    int h = hb * 8 + k;
    float acc[4] = {bias[0], bias[1], bias[2], bias[3]};
#pragma unroll
    for (int dh = 0; dh < 3; ++dh) {
#pragma unroll
      for (int dw = -1; dw <= 1; ++dw) {
        int ww = w + dw;
        if (ww < 0 || ww > 31) continue;
        const float* p = &Ls[h + dh][ww][c4 * 4];
        int kb = dh * 3 + (dw + 1);
#pragma unroll
        for (int j = 0; j < 4; ++j) acc[j] = fmaf(p[j], wt[j][kb], acc[j]);
      }
    }
    float s4[4];
#pragma unroll
    for (int j = 0; j < 4; ++j) { float v = acc[j]; s4[j] = v / (1.f + expf(-v)); }
    if (isx) {
#pragma unroll
      for (int j = 0; j < 4; ++j) xh16[k][j] = f2h(s4[j]);
    } else {
      size_t row = (size_t)b * 1024 + (h0 + h) * 32 + w;
      u16 hv[4] = {f2h(s4[0]), f2h(s4[1]), f2h(s4[2]), f2h(s4[3])};
      uint2 hp = make_uint2((u32)hv[0] | ((u32)hv[1] << 16), (u32)hv[2] | ((u32)hv[3] << 16));
      int c = c0 + c4 * 4;
      if (c < DI + DS) *(uint2*)&Bh[row * DS + (c - DI)] = hp;
      else             *(uint2*)&Chh[row * DS + (c - DI - DS)] = hp;
    }
  }
  if (isx) {
    __syncthreads();          // all reads of Ls done; reuse as u16[16][512]
    u16* Ls2 = (u16*)Ls;
#pragma unroll
    for (int k = 0; k < 8; ++k) {
      int pos = (hb * 8 + k) * 32 + w;
#pragma unroll
      for (int j = 0; j < 4; ++j)
        Ls2[(c4 * 4 + j) * 512 + pos] = xh16[k][j];
    }
    __syncthreads();
    const int hh = c0 >> 6;
    const int pb = c0 & 63;
#pragma unroll
    for (int i = 0; i < 4; ++i) {
      int cid = i * 256 + t;
      int pl = cid >> 6, rem = cid & 63;
      int jbl = rem >> 3, slot = rem & 7;
      int labs = h0 * 32 + jbl * 64;
      size_t tile = ((size_t)(b * 4 + (labs >> 8)) * NH + hh) * 4 + ((labs >> 6) & 3);
      *(uint4*)((char*)XTh + tile * 8192 + SWZ(pb + pl, slot)) =
          *(const uint4*)&Ls2[pl * 512 + jbl * 64 + slot * 8];
    }
  }
}

// stage one pre-swizzled 8KB XT tile into LDS via linear DMA
#define STAGE_XT(tileByte) do {                                                                   \
  _Pragma("unroll")                                                                               \
  for (int i_ = 0; i_ < 2; ++i_) {                                                                \
    int S_ = i_ * 256 + t;                                                                        \
    __builtin_amdgcn_global_load_lds(                                                             \
        (const __attribute__((address_space(1))) u32*)((const char*)XTh + (tileByte) + S_ * 16),  \
        (__attribute__((address_space(3))) u32*)((char*)Xh_t + S_ * 16), 16, 0, 0);               \
  }                                                                                               \
} while (0)

// ---------------- K5: chunk states via MFMA ----------------
__global__ __launch_bounds__(256) void k_states(
    const u16* __restrict__ XTh,
    const u16* __restrict__ Bh,
    const float* __restrict__ dt, const float* __restrict__ dAcs,
    float* __restrict__ states)
{
  __shared__ u16 bpackB[64 * 65];
  __shared__ u16 BTh_t[4096];
  __shared__ u16 Xh_t[4096];
  __shared__ float wall[256];
  const int bc = blockIdx.x;
  const int hh = blockIdx.y;
  const int t  = threadIdx.x;
  const int lane = t & 63, w = t >> 6;
  const int mlo = lane & 15, gg = lane >> 4;
  const int r = t >> 2, q = (t & 3) * 16;
  const size_t base = (size_t)bc * 256;
  const float last = dAcs[(base + 255) * NH + hh];
  wall[t] = expf(last - dAcs[(base + t) * NH + hh]) * dt[(base + t) * NH + hh];
  f32x4 acc[4];
#pragma unroll
  for (int i = 0; i < 4; ++i) acc[i] = (f32x4){0.f, 0.f, 0.f, 0.f};
  for (int jt = 0; jt < 4; ++jt) {
    const int j0 = jt * 64;
    __syncthreads();
    STAGE_XT(((size_t)(bc * NH + hh) * 4 + jt) * 8192);
    {
      const u16* bhp = &Bh[(size_t)(base + j0 + r) * DS + q];
      U4 H0, H1;
      H0.v = *(const uint4*)bhp; H1.v = *(const uint4*)(bhp + 8);
#pragma unroll
      for (int k = 0; k < 8; ++k) {
        bpackB[r * 65 + q + k]     = H0.s[k];
        bpackB[r * 65 + q + 8 + k] = H1.s[k];
      }
    }
    __syncthreads();
#pragma unroll
    for (int c = 0; c < 2; ++c) {
      U4 BH;
#pragma unroll
      for (int jj = 0; jj < 8; ++jj) {
        int j = q + c * 8 + jj;
        BH.s[jj] = f2h(h2f(bpackB[j * 65 + r]) * wall[j0 + j]);
      }
      *(uint4*)((char*)BTh_t + SWZ(r, (q >> 3) + c)) = BH.v;
    }
    __syncthreads();
#pragma unroll
    for (int s = 0; s < 2; ++s) {
      f16x8 fah = *(const f16x8*)((const char*)Xh_t + SWZ(w * 16 + mlo, s * 4 + gg));
#pragma unroll
      for (int nf = 0; nf < 4; ++nf) {
        f16x8 fbh = *(const f16x8*)((const char*)BTh_t + SWZ(nf * 16 + mlo, s * 4 + gg));
        acc[nf] = __builtin_amdgcn_mfma_f32_16x16x32_f16(fah, fbh, acc[nf], 0, 0, 0);
      }
    }
  }
  const size_t sb = ((size_t)(bc * NH + hh)) << 12;
#pragma unroll
  for (int nf = 0; nf < 4; ++nf)
#pragma unroll
    for (int reg = 0; reg < 4; ++reg) {
      int p = w * 16 + (lane >> 4) * 4 + reg;
      int n = nf * 16 + mlo;
      states[sb + (size_t)p * 64 + n] = acc[nf][reg];
    }
}

// ---------------- K6: inter-chunk scan ----------------
__global__ __launch_bounds__(256) void k_scanc(
    const float* __restrict__ states, const float* __restrict__ cdecay,
    float* __restrict__ prev)
{
  int tid = blockIdx.x * 256 + threadIdx.x;
  int pn  = tid & 4095;
  int rem = tid >> 12;
  int hh  = rem % NH;
  int b   = rem / NH;
  float carry = 0.f;
#pragma unroll
  for (int c = 0; c < 4; ++c) {
    size_t idx = ((size_t)((b * 4 + c) * NH + hh) << 12) + pn;
    prev[idx] = carry;
    carry = carry * cdecay[(b * 4 + c) * NH + hh] + states[idx];
  }
}

// ---------------- K7: y = intra + inter + D*x; i-tile PAIR per block ----------------
__global__ __launch_bounds__(256) void k_y(
    const u16* __restrict__ XTh,
    const u16* __restrict__ Chg, const u16* __restrict__ Bhg,
    const float* __restrict__ dtp, const float* __restrict__ dAcs,
    const float* __restrict__ prev, const float* __restrict__ Dp,
    float* __restrict__ y)
{
  __shared__ u16 Pb_t[4096];
  __shared__ u16 Xh_t[4096];
  __shared__ u16 att_t[4096];
  __shared__ float dAc_s[256], dt_s[256], ei_s[128];
  const int bc = blockIdx.x;
  const int hh = blockIdx.y;
  const int z  = blockIdx.z;          // i-tile pair: it0 = 2z, it1 = 2z+1
  const int it0 = z * 2;
  const int t  = threadIdx.x;
  const int lane = t & 63, w = t >> 6;
  const int mlo = lane & 15, gg = lane >> 4;
  const int r = t >> 2, q = (t & 3) * 16;
  const int slot0 = q >> 3;
  const size_t base = (size_t)bc * 256;
  {
    float da = dAcs[(base + t) * NH + hh];
    dAc_s[t] = da;
    dt_s[t]  = dtp[(base + t) * NH + hh];
    if (t < 128) ei_s[t] = expf(dAcs[(base + z * 128 + t) * NH + hh]);
  }
  {
    const float* pp = &prev[(((size_t)(bc * NH + hh)) << 12) + (size_t)r * 64 + q];
    U4 H0, H1;
#pragma unroll
    for (int k = 0; k < 16; ++k) {
      u16 h = f2h(pp[k]);
      if (k < 8) H0.s[k] = h; else H1.s[k - 8] = h;
    }
    *(uint4*)((char*)Pb_t + SWZ(r, slot0))     = H0.v;
    *(uint4*)((char*)Pb_t + SWZ(r, slot0 + 1)) = H1.v;
  }
  __syncthreads();
  // C fragments for both i-tiles
  f16x8 fc[2][2];
#pragma unroll
  for (int iti = 0; iti < 2; ++iti)
#pragma unroll
    for (int s = 0; s < 2; ++s)
      fc[iti][s] = *(const f16x8*)&Chg[(size_t)(base + (it0 + iti) * 64 + w * 16 + mlo) * DS +
                                       (s * 4 + gg) * 8];
  // inter: both i-tiles share each prev fragment load
  f32x4 accy[2][4];
#pragma unroll
  for (int i = 0; i < 2; ++i)
#pragma unroll
    for (int j = 0; j < 4; ++j) accy[i][j] = (f32x4){0.f, 0.f, 0.f, 0.f};
#pragma unroll
  for (int s = 0; s < 2; ++s)
#pragma unroll
    for (int pf = 0; pf < 4; ++pf) {
      f16x8 fph = *(const f16x8*)((const char*)Pb_t + SWZ(pf * 16 + mlo, s * 4 + gg));
#pragma unroll
      for (int iti = 0; iti < 2; ++iti)
        accy[iti][pf] = __builtin_amdgcn_mfma_f32_16x16x32_f16(fc[iti][s], fph, accy[iti][pf], 0, 0, 0);
    }
  const int ilb = w * 16 + (lane >> 4) * 4;
#pragma unroll
  for (int iti = 0; iti < 2; ++iti)
#pragma unroll
    for (int pf = 0; pf < 4; ++pf)
#pragma unroll
      for (int reg = 0; reg < 4; ++reg)
        accy[iti][pf][reg] *= ei_s[iti * 64 + ilb + reg];

  u32 xdv[2][8];                       // captured fp16 x-values for D*x (packed pairs)
  for (int jt = 0; jt <= it0 + 1; ++jt) {
    __syncthreads();
    STAGE_XT(((size_t)(bc * NH + hh) * 4 + jt) * 8192);
    {
      const u16* bh = &Bhg[(size_t)(base + jt * 64 + r) * DS + q];
      *(uint4*)((char*)Pb_t + SWZ(r, slot0))     = *(const uint4*)bh;
      *(uint4*)((char*)Pb_t + SWZ(r, slot0 + 1)) = *(const uint4*)(bh + 8);
    }
    __syncthreads();
    // capture D*x values when jt matches an i-tile (uniform branch)
#pragma unroll
    for (int iti = 0; iti < 2; ++iti) {
      if (jt == it0 + iti) {
#pragma unroll
        for (int pf = 0; pf < 4; ++pf)
#pragma unroll
          for (int rp = 0; rp < 2; ++rp) {
            int j0l = ilb + rp * 2;
            u16 a = *(const u16*)((const char*)Xh_t + SWZ(pf * 16 + mlo, j0l >> 3) + (j0l & 7) * 2);
            u16 b2 = *(const u16*)((const char*)Xh_t + SWZ(pf * 16 + mlo, (j0l + 1) >> 3) + ((j0l + 1) & 7) * 2);
            xdv[iti][pf * 2 + rp] = (u32)a | ((u32)b2 << 16);
          }
      }
    }
#pragma unroll
    for (int iti = 0; iti < 2; ++iti) {
      const int ita = it0 + iti;
      if (jt > ita) continue;          // uniform
      f32x4 g[4];
#pragma unroll
      for (int i = 0; i < 4; ++i) g[i] = (f32x4){0.f, 0.f, 0.f, 0.f};
#pragma unroll
      for (int s = 0; s < 2; ++s)
#pragma unroll
        for (int jf = 0; jf < 4; ++jf) {
          f16x8 fbh = *(const f16x8*)((const char*)Pb_t + SWZ(jf * 16 + mlo, s * 4 + gg));
          g[jf] = __builtin_amdgcn_mfma_f32_16x16x32_f16(fc[iti][s], fbh, g[jf], 0, 0, 0);
        }
#pragma unroll
      for (int jf = 0; jf < 4; ++jf)
#pragma unroll
        for (int reg = 0; reg < 4; ++reg) {
          int il = ita * 64 + ilb + reg;
          int jl = jt * 64 + jf * 16 + mlo;
          float av = (jl <= il) ? g[jf][reg] * expf(dAc_s[il] - dAc_s[jl]) * dt_s[jl] : 0.f;
          *(u16*)((char*)att_t + SWZ(il & 63, (jl & 63) >> 3) + (jl & 7) * 2) = f2h(av);
        }
      // intra (att rows wave-private; same-wave DS ordering makes this safe)
#pragma unroll
      for (int s = 0; s < 2; ++s) {
        f16x8 fa = *(const f16x8*)((const char*)att_t + SWZ(w * 16 + mlo, s * 4 + gg));
#pragma unroll
        for (int pf = 0; pf < 4; ++pf) {
          f16x8 fxh = *(const f16x8*)((const char*)Xh_t + SWZ(pf * 16 + mlo, s * 4 + gg));
          accy[iti][pf] = __builtin_amdgcn_mfma_f32_16x16x32_f16(fa, fxh, accy[iti][pf], 0, 0, 0);
        }
      }
    }
  }
  // epilogue: + D*x from captured fp16 values
  const float Dh = Dp[hh];
#pragma unroll
  for (int iti = 0; iti < 2; ++iti)
#pragma unroll
    for (int pf = 0; pf < 4; ++pf)
#pragma unroll
      for (int reg = 0; reg < 4; ++reg) {
        size_t row = base + (it0 + iti) * 64 + ilb + reg;
        int col = hh * HD + pf * 16 + mlo;
        u32 pk = xdv[iti][pf * 2 + (reg >> 1)];
        u16 xv = (reg & 1) ? (u16)(pk >> 16) : (u16)pk;
        y[row * DI + col] = accy[iti][pf][reg] + Dh * h2f(xv);
      }
}

// ---------------- K8: LayerNorm * z -> fp16 hi/lo pair ----------------
__global__ __launch_bounds__(256) void k_norm(
    const float* __restrict__ z, const float* __restrict__ nw,
    const float* __restrict__ nb, const float* __restrict__ y,
    u16* __restrict__ yh, u16* __restrict__ yl)
{
  __shared__ float rs[4], rq[4];
  const size_t row = blockIdx.x;
  const int t = threadIdx.x;
  float v[3];
  float s = 0.f, sq = 0.f;
#pragma unroll
  for (int r = 0; r < 3; ++r) {
    v[r] = y[row * DI + r * 256 + t];
    s += v[r];
    sq = fmaf(v[r], v[r], sq);
  }
#pragma unroll
  for (int off = 32; off > 0; off >>= 1) {
    s  += __shfl_down(s, off, 64);
    sq += __shfl_down(sq, off, 64);
  }
  const int wid = t >> 6, lane = t & 63;
  if (lane == 0) { rs[wid] = s; rq[wid] = sq; }
  __syncthreads();
  if (t == 0) {
    rs[0] = rs[0] + rs[1] + rs[2] + rs[3];
    rq[0] = rq[0] + rq[1] + rq[2] + rq[3];
  }
  __syncthreads();
  const float mu   = rs[0] * (1.f / DI);
  const float var  = rq[0] * (1.f / DI) - mu * mu;
  const float rstd = 1.f / sqrtf(var + EPS_);
#pragma unroll
  for (int r = 0; r < 3; ++r) {
    int d = r * 256 + t;
    float o = (v[r] - mu) * rstd * nw[d] + nb[d];
    float p = o * z[row * DI + d];
    u16 h, l;
    hsplit(p, h, l);
    yh[row * DI + d] = h;
    yl[row * DI + d] = l;
  }
}

extern "C" void kernel_launch(void* const* d_in, const int* in_sizes, int n_in,
                              void* d_out, int out_size, void* d_ws, size_t ws_size,
                              hipStream_t stream)
{
  const float* u    = (const float*)d_in[0];
  const float* ipw  = (const float*)d_in[1];
  const float* cw   = (const float*)d_in[2];
  const float* cb   = (const float*)d_in[3];
  const float* dtb  = (const float*)d_in[4];
  const float* Alog = (const float*)d_in[5];
  const float* Dp   = (const float*)d_in[6];
  const float* nw   = (const float*)d_in[7];
  const float* nb   = (const float*)d_in[8];
  const float* opw  = (const float*)d_in[9];
  float* out = (float*)d_out;

  float* ws = (float*)d_ws;
  size_t off = 0;
  float* z_buf   = ws + off; off += (size_t)B_ * L_ * DI;
  u16*   xBC16   = (u16*)(ws + off); off += (size_t)B_ * L_ * CONVD / 2;
  float* dt_buf  = ws + off; off += (size_t)B_ * L_ * NH;
  float* x_buf   = ws + off; off += (size_t)B_ * L_ * DI;     // alias space only
  float* y_buf   = ws + off; off += (size_t)B_ * L_ * DI;
  u16*   Bh_buf  = (u16*)(ws + off); off += (size_t)B_ * L_ * DS / 2;
  u16*   Ch_buf  = (u16*)(ws + off); off += (size_t)B_ * L_ * DS / 2;
  float* dAcs    = ws + off; off += (size_t)B_ * L_ * NH;
  float* cdec    = ws + off; off += (size_t)B_ * NCH * NH;
  float* st_buf  = ws + off; off += (size_t)B_ * NCH * NH * HD * DS;
  float* pv_buf  = ws + off; off += (size_t)B_ * NCH * NH * HD * DS;
  u16*   Woh     = (u16*)(ws + off); off += (size_t)DM * DI / 2;
  u16*   XTh_buf = (u16*)(ws + off); off += (size_t)B_ * NCH * NH * 4 * 4096 / 2;

  // aliases inside x_buf (dead/live windows don't overlap)
  u16* Ah = (u16*)x_buf;                         // consumed by gemm1 (before conv)
  u16* Whip = Ah + (size_t)B_ * L_ * DM;
  u16* yh = (u16*)x_buf;                         // written by k_norm (after gemm1)
  u16* yl = yh + (size_t)B_ * L_ * DI;

  hipLaunchKernelGGL(k_cvtA, dim3(8, 12, 16), dim3(256), 0, stream, u, Ah);
  hipLaunchKernelGGL(k_cvtWh, dim3((NIP * DM / 4 + 255) / 256), dim3(256), 0, stream,
                     ipw, Whip, NIP * DM / 4);
  hipLaunchKernelGGL(k_cvtWh, dim3((DM * DI / 4 + 255) / 256), dim3(256), 0, stream,
                     opw, Woh, DM * DI / 4);
  hipLaunchKernelGGL(k_dtp, dim3(64), dim3(256), 0, stream,
                     u, ipw, dtb, Alog, dt_buf, dAcs, cdec);
  hipLaunchKernelGGL(k_gemm1, dim3(128, 13), dim3(256), 0, stream,
                     Ah, Whip, z_buf, xBC16);
  hipLaunchKernelGGL(k_conv, dim3(56, 2, 16), dim3(256), 0, stream,
                     xBC16, cw, cb, XTh_buf, Bh_buf, Ch_buf);
  hipLaunchKernelGGL(k_states, dim3(64, 12), dim3(256), 0, stream,
                     XTh_buf, Bh_buf, dt_buf, dAcs, st_buf);
  hipLaunchKernelGGL(k_scanc, dim3(3072), dim3(256), 0, stream, st_buf, cdec, pv_buf);
  hipLaunchKernelGGL(k_y, dim3(64, 12, 2), dim3(256), 0, stream,
                     XTh_buf, Ch_buf, Bh_buf, dt_buf, dAcs, pv_buf, Dp, y_buf);
  hipLaunchKernelGGL(k_norm, dim3(16384), dim3(256), 0, stream, z_buf, nw, nb, y_buf, yh, yl);
  hipLaunchKernelGGL(k_gemm2, dim3(128, 3), dim3(256), 0, stream, yh, yl, Woh, out);
}

// Round 15
// 220.990 us; speedup vs baseline: 1.5844x; 1.0822x over previous
//
#include <hip/hip_runtime.h>
#include <hip/hip_bf16.h>

#define B_    16
#define L_    1024
#define DM    384
#define DIP   1676
#define NIP   1664
#define DI    768
#define CONVD 896
#define NH    12
#define HD    64
#define DS    64
#define NCH   4
#define CH    256
#define EPS_  1e-5f

typedef unsigned short u16;
typedef unsigned int   u32;
typedef __attribute__((ext_vector_type(8))) _Float16 f16x8;
typedef __attribute__((ext_vector_type(4))) float f32x4;

union U4 { uint4 v; u16 s[8]; };

// byte offset of 16B slot `slot` in row `row` of a [64][64]-16bit LDS tile (128B rows, XOR swizzle)
#define SWZ(row, slot) (((row) << 7) + ((((slot) ^ ((row) & 7)) & 7) << 4))

// ---- fp16 helpers ----
__device__ __forceinline__ u16 f2h(float v) { return __builtin_bit_cast(u16, (_Float16)v); }
__device__ __forceinline__ float h2f(u16 h) { return (float)__builtin_bit_cast(_Float16, h); }
__device__ __forceinline__ void hsplit(float v, u16& h, u16& l) {
  _Float16 hh = (_Float16)v;
  _Float16 ll = (_Float16)(v - (float)hh);
  h = __builtin_bit_cast(u16, hh);
  l = __builtin_bit_cast(u16, ll);
}

// ---------------- converters ----------------
__global__ __launch_bounds__(256) void k_cvtA(const float* __restrict__ u,
                                              u16* __restrict__ Ah)
{
  __shared__ float Ls[32][129];
  const int t  = threadIdx.x;
  const int l0 = blockIdx.x * 128;
  const int k0 = blockIdx.y * 32;
  const int b  = blockIdx.z;
#pragma unroll
  for (int r = 0; r < 4; ++r) {
    int idx = r * 256 + t;
    int kk = idx >> 5, q = idx & 31;
    float4 v = *(const float4*)&u[((size_t)(b * DM + k0 + kk)) * L_ + l0 + q * 4];
    Ls[kk][q * 4 + 0] = v.x; Ls[kk][q * 4 + 1] = v.y;
    Ls[kk][q * 4 + 2] = v.z; Ls[kk][q * 4 + 3] = v.w;
  }
  __syncthreads();
#pragma unroll
  for (int it = 0; it < 2; ++it) {
    int task = it * 256 + t;
    int l = task >> 2, kq = (task & 3) * 8;
    u32 hw[4];
#pragma unroll
    for (int j = 0; j < 4; ++j) {
      u16 h0 = f2h(Ls[kq + 2 * j + 0][l]);
      u16 h1 = f2h(Ls[kq + 2 * j + 1][l]);
      hw[j] = (u32)h0 | ((u32)h1 << 16);
    }
    size_t off = ((size_t)(b * L_ + l0 + l)) * DM + k0 + kq;
    *(uint4*)&Ah[off] = make_uint4(hw[0], hw[1], hw[2], hw[3]);
  }
}

__global__ __launch_bounds__(256) void k_cvtWh(const float* __restrict__ W,
                                               u16* __restrict__ Wh, int total4)
{
  int i = blockIdx.x * 256 + threadIdx.x;
  if (i >= total4) return;
  int e = i * 4;
  float4 v = *(const float4*)&W[e];
  u16 h[4] = {f2h(v.x), f2h(v.y), f2h(v.z), f2h(v.w)};
  *(uint2*)&Wh[e] = make_uint2((u32)h[0] | ((u32)h[1] << 16), (u32)h[2] | ((u32)h[3] << 16));
}

// ---------------- K_dtp: dt logits from u (fp32) + softplus + chunk cumsum ----------------
__global__ __launch_bounds__(256) void k_dtp(
    const float* __restrict__ u, const float* __restrict__ ipw,
    const float* __restrict__ dtb, const float* __restrict__ A_log,
    float* __restrict__ dt, float* __restrict__ dAcs, float* __restrict__ cdecay)
{
  __shared__ float Ls[64][256];
  __shared__ float wdt[NH * DM];
  __shared__ float ws4[4];
  const int bc = blockIdx.x;
  const int b  = bc >> 2, l0 = (bc & 3) * 256;
  const int t  = threadIdx.x;
  const int lane = t & 63, w = t >> 6;
#pragma unroll
  for (int i = 0; i < 18; ++i) wdt[i * 256 + t] = ipw[(size_t)NIP * DM + i * 256 + t];
  float acc[NH] = {};
  for (int k0 = 0; k0 < DM; k0 += 64) {
    __syncthreads();
#pragma unroll
    for (int it = 0; it < 16; ++it) {
      int idx = it * 256 + t;
      int kk = idx >> 6, q4 = (idx & 63) * 4;
      *(float4*)&Ls[kk][q4] = *(const float4*)&u[((size_t)(b * DM + k0 + kk)) * L_ + l0 + q4];
    }
    __syncthreads();
    for (int k = 0; k < 64; ++k) {
      float uv = Ls[k][t];
#pragma unroll
      for (int h = 0; h < NH; ++h)
        acc[h] = fmaf(uv, wdt[h * DM + k0 + k], acc[h]);
    }
  }
  const size_t row = (size_t)bc * 256 + t;
#pragma unroll
  for (int h = 0; h < NH; ++h) {
    float logit = acc[h] + dtb[h];
    float dtv = (logit > 20.f) ? logit : log1pf(expf(logit));
    dt[row * NH + h] = dtv;
    float xv = dtv * (-expf(A_log[h]));
#pragma unroll
    for (int off = 1; off < 64; off <<= 1) {
      float y = __shfl_up(xv, off, 64);
      if (lane >= off) xv += y;
    }
    __syncthreads();
    if (lane == 63) ws4[w] = xv;
    __syncthreads();
    float add = 0.f;
#pragma unroll
    for (int i = 0; i < 4; ++i) if (i < w) add += ws4[i];
    xv += add;
    dAcs[row * NH + h] = xv;
    if (t == 255) cdecay[bc * NH + h] = expf(xv);
  }
}

// 2-stream staging (A, W) of one 128x32 u16 K-tile set
#define STAGE2(bufbase, k0) do {                                                                \
  _Pragma("unroll")                                                                             \
  for (int i_ = 0; i_ < 2; ++i_) {                                                              \
    int S_ = i_ * 256 + t;                                                                      \
    int m_ = S_ >> 2;                                                                           \
    int g_ = (S_ ^ (m_ >> 1)) & 3;                                                              \
    size_t goff_ = (size_t)m_ * DM + (k0) + g_ * 8;                                             \
    __builtin_amdgcn_global_load_lds((const __attribute__((address_space(1))) u32*)(g0 + goff_),\
        (__attribute__((address_space(3))) u32*)(lds + (bufbase) + S_ * 8), 16, 0, 0);          \
    __builtin_amdgcn_global_load_lds((const __attribute__((address_space(1))) u32*)(g2 + goff_),\
        (__attribute__((address_space(3))) u32*)(lds + (bufbase) + 4096 + S_ * 8), 16, 0, 0);   \
  }                                                                                             \
} while (0)

// ---------------- fp16 single MFMA GEMM: in_proj (z fp16, xBC fp16) ----------------
__global__ __launch_bounds__(256) void k_gemm1(
    const u16* __restrict__ Ah,
    const u16* __restrict__ Wh,
    u16* __restrict__ z, u16* __restrict__ xBC)
{
  __shared__ u16 lds[16384];
  const int t = threadIdx.x;
  const int lane = t & 63, wid = t >> 6;
  const int wr = wid >> 1, wc = wid & 1;
  const int gg = lane >> 4, mlo = lane & 15;
  const int m0 = blockIdx.x * 128, n0 = blockIdx.y * 128;
  f32x4 acc[4][4];
#pragma unroll
  for (int i = 0; i < 4; ++i)
#pragma unroll
    for (int j = 0; j < 4; ++j) acc[i][j] = (f32x4){0.f, 0.f, 0.f, 0.f};
  const u16* g0 = Ah + (size_t)m0 * DM;
  const u16* g2 = Wh + (size_t)n0 * DM;
  STAGE2(0, 0);
  __syncthreads();
  int cur = 0;
  for (int kt = 0; kt < DM / 32; ++kt) {
    if (kt + 1 < DM / 32) STAGE2((cur ^ 1) * 8192, (kt + 1) * 32);
    const char* ldsb = (const char*)lds + cur * 16384;
    f16x8 fa[4], fb[4];
#pragma unroll
    for (int mf = 0; mf < 4; ++mf) {
      int m = wr * 64 + mf * 16 + mlo;
      int off = m * 64 + (((gg ^ (m >> 1)) & 3) << 4);
      fa[mf]  = *(const f16x8*)(ldsb + off);
    }
#pragma unroll
    for (int nf = 0; nf < 4; ++nf) {
      int n = wc * 64 + nf * 16 + mlo;
      int off = n * 64 + (((gg ^ (n >> 1)) & 3) << 4);
      fb[nf]  = *(const f16x8*)(ldsb + 8192 + off);
    }
#pragma unroll
    for (int mf = 0; mf < 4; ++mf)
#pragma unroll
      for (int nf = 0; nf < 4; ++nf)
        acc[mf][nf] = __builtin_amdgcn_mfma_f32_16x16x32_f16(fa[mf], fb[nf], acc[mf][nf], 0, 0, 0);
    __syncthreads();
    cur ^= 1;
  }
  const int rb = m0 + wr * 64 + (lane >> 4) * 4;
  const int cb = n0 + wc * 64 + mlo;
#pragma unroll
  for (int mf = 0; mf < 4; ++mf)
#pragma unroll
    for (int nf = 0; nf < 4; ++nf) {
      int col = cb + nf * 16;
#pragma unroll
      for (int r = 0; r < 4; ++r) {
        int row = rb + mf * 16 + r;
        float v = acc[mf][nf][r];
        if (col < DI) z[(size_t)row * DI + col] = f2h(v);
        else xBC[(size_t)row * CONVD + (col - DI)] = f2h(v);
      }
    }
}

// 3-stream staging for gemm2 (yh, yl, W)
#define STAGE3B(bufbase, k0) do {                                                               \
  _Pragma("unroll")                                                                             \
  for (int i_ = 0; i_ < 2; ++i_) {                                                              \
    int S_ = i_ * 256 + t;                                                                      \
    int m_ = S_ >> 2;                                                                           \
    int g_ = (S_ ^ (m_ >> 1)) & 3;                                                              \
    size_t goff_ = (size_t)m_ * DI + (k0) + g_ * 8;                                             \
    __builtin_amdgcn_global_load_lds((const __attribute__((address_space(1))) u32*)(g0 + goff_),\
        (__attribute__((address_space(3))) u32*)(lds + (bufbase) + S_ * 8), 16, 0, 0);          \
    __builtin_amdgcn_global_load_lds((const __attribute__((address_space(1))) u32*)(g1 + goff_),\
        (__attribute__((address_space(3))) u32*)(lds + (bufbase) + 4096 + S_ * 8), 16, 0, 0);   \
    __builtin_amdgcn_global_load_lds((const __attribute__((address_space(1))) u32*)(g2 + goff_),\
        (__attribute__((address_space(3))) u32*)(lds + (bufbase) + 8192 + S_ * 8), 16, 0, 0);   \
  }                                                                                             \
} while (0)

// ---------------- fp16x2 MFMA GEMM: out_proj ----------------
__global__ __launch_bounds__(256) void k_gemm2(
    const u16* __restrict__ Ah, const u16* __restrict__ Al,
    const u16* __restrict__ Bh,
    float* __restrict__ out)
{
  __shared__ u16 lds[24576];
  const int t = threadIdx.x;
  const int lane = t & 63, wid = t >> 6;
  const int wr = wid >> 1, wc = wid & 1;
  const int gg = lane >> 4, mlo = lane & 15;
  const int m0 = blockIdx.x * 128, n0 = blockIdx.y * 128;
  f32x4 acc[4][4];
#pragma unroll
  for (int i = 0; i < 4; ++i)
#pragma unroll
    for (int j = 0; j < 4; ++j) acc[i][j] = (f32x4){0.f, 0.f, 0.f, 0.f};
  const u16* g0 = Ah + (size_t)m0 * DI;
  const u16* g1 = Al + (size_t)m0 * DI;
  const u16* g2 = Bh + (size_t)n0 * DI;
  STAGE3B(0, 0);
  __syncthreads();
  int cur = 0;
  for (int kt = 0; kt < DI / 32; ++kt) {
    if (kt + 1 < DI / 32) STAGE3B((cur ^ 1) * 12288, (kt + 1) * 32);
    const char* ldsb = (const char*)lds + cur * 24576;
    f16x8 fa[4], fal[4], fb[4];
#pragma unroll
    for (int mf = 0; mf < 4; ++mf) {
      int m = wr * 64 + mf * 16 + mlo;
      int off = m * 64 + (((gg ^ (m >> 1)) & 3) << 4);
      fa[mf]  = *(const f16x8*)(ldsb + off);
      fal[mf] = *(const f16x8*)(ldsb + 8192 + off);
    }
#pragma unroll
    for (int nf = 0; nf < 4; ++nf) {
      int n = wc * 64 + nf * 16 + mlo;
      int off = n * 64 + (((gg ^ (n >> 1)) & 3) << 4);
      fb[nf]  = *(const f16x8*)(ldsb + 16384 + off);
    }
#pragma unroll
    for (int mf = 0; mf < 4; ++mf)
#pragma unroll
      for (int nf = 0; nf < 4; ++nf) {
        acc[mf][nf] = __builtin_amdgcn_mfma_f32_16x16x32_f16(fa[mf],  fb[nf], acc[mf][nf], 0, 0, 0);
        acc[mf][nf] = __builtin_amdgcn_mfma_f32_16x16x32_f16(fal[mf], fb[nf], acc[mf][nf], 0, 0, 0);
      }
    __syncthreads();
    cur ^= 1;
  }
  const int rb = m0 + wr * 64 + (lane >> 4) * 4;
  const int cb = n0 + wc * 64 + mlo;
#pragma unroll
  for (int mf = 0; mf < 4; ++mf)
#pragma unroll
    for (int nf = 0; nf < 4; ++nf) {
      int col = cb + nf * 16;
#pragma unroll
      for (int r = 0; r < 4; ++r) {
        int row = rb + mf * 16 + r;
        int b = row >> 10, l = row & 1023;
        out[((size_t)(b * DM + col)) * L_ + l] = acc[mf][nf][r];
      }
    }
}

// ---------------- K2: depthwise conv; x-channels -> pre-swizzled XT fp16 tiles; B/C fp16 ----------------
#define CC 16
__global__ __launch_bounds__(256) void k_conv(
    const u16* __restrict__ xBC, const float* __restrict__ cw,
    const float* __restrict__ cb,
    u16* __restrict__ XTh,
    u16* __restrict__ Bh,
    u16* __restrict__ Chh)
{
  __shared__ float Ls[18][32][CC];
  const int t  = threadIdx.x;
  const int c0 = blockIdx.x * CC;
  const int h0 = blockIdx.y * 16;
  const int b  = blockIdx.z;
#pragma unroll
  for (int k = 0; k < 9; ++k) {
    int f = k * 256 + t;
    int fc4 = f & 3, fw = (f >> 2) & 31, fr = f >> 7;
    int h = h0 + fr - 1;
    U4 v; v.v = make_uint4(0, 0, 0, 0);
    if (h >= 0 && h < 32) {
      uint2 p = *(const uint2*)&xBC[((size_t)(b * 1024 + h * 32 + fw)) * CONVD + c0 + fc4 * 4];
      v.v.x = p.x; v.v.y = p.y;
    }
    Ls[fr][fw][fc4 * 4 + 0] = h2f(v.s[0]);
    Ls[fr][fw][fc4 * 4 + 1] = h2f(v.s[1]);
    Ls[fr][fw][fc4 * 4 + 2] = h2f(v.s[2]);
    Ls[fr][fw][fc4 * 4 + 3] = h2f(v.s[3]);
  }
  const int c4 = t & 3;
  const int w  = (t >> 2) & 31;
  const int hb = t >> 7;
  float wt[4][9];
  float bias[4];
#pragma unroll
  for (int j = 0; j < 4; ++j) {
    int c = c0 + c4 * 4 + j;
    bias[j] = cb[c];
#pragma unroll
    for (int kb = 0; kb < 9; ++kb) wt[j][kb] = cw[c * 9 + kb];
  }
  __syncthreads();
  const bool isx = (c0 < DI);
  u16 xh16[8][4];
#pragma unroll
  for (int k = 0; k < 8; ++k) {
    int h = hb * 8 + k;
    float acc[4] = {bias[0], bias[1], bias[2], bias[3]};
#pragma unroll
    for (int dh = 0; dh < 3; ++dh) {
#pragma unroll
      for (int dw = -1; dw <= 1; ++dw) {
        int ww = w + dw;
        if (ww < 0 || ww > 31) continue;
        const float* p = &Ls[h + dh][ww][c4 * 4];
        int kb = dh * 3 + (dw + 1);
#pragma unroll
        for (int j = 0; j < 4; ++j) acc[j] = fmaf(p[j], wt[j][kb], acc[j]);
      }
    }
    float s4[4];
#pragma unroll
    for (int j = 0; j < 4; ++j) { float v = acc[j]; s4[j] = v / (1.f + expf(-v)); }
    if (isx) {
#pragma unroll
      for (int j = 0; j < 4; ++j) xh16[k][j] = f2h(s4[j]);
    } else {
      size_t row = (size_t)b * 1024 + (h0 + h) * 32 + w;
      u16 hv[4] = {f2h(s4[0]), f2h(s4[1]), f2h(s4[2]), f2h(s4[3])};
      uint2 hp = make_uint2((u32)hv[0] | ((u32)hv[1] << 16), (u32)hv[2] | ((u32)hv[3] << 16));
      int c = c0 + c4 * 4;
      if (c < DI + DS) *(uint2*)&Bh[row * DS + (c - DI)] = hp;
      else             *(uint2*)&Chh[row * DS + (c - DI - DS)] = hp;
    }
  }
  if (isx) {
    __syncthreads();
    u16* Ls2 = (u16*)Ls;
#pragma unroll
    for (int k = 0; k < 8; ++k) {
      int pos = (hb * 8 + k) * 32 + w;
#pragma unroll
      for (int j = 0; j < 4; ++j)
        Ls2[(c4 * 4 + j) * 512 + pos] = xh16[k][j];
    }
    __syncthreads();
    const int hh = c0 >> 6;
    const int pb = c0 & 63;
#pragma unroll
    for (int i = 0; i < 4; ++i) {
      int cid = i * 256 + t;
      int pl = cid >> 6, rem = cid & 63;
      int jbl = rem >> 3, slot = rem & 7;
      int labs = h0 * 32 + jbl * 64;
      size_t tile = ((size_t)(b * 4 + (labs >> 8)) * NH + hh) * 4 + ((labs >> 6) & 3);
      *(uint4*)((char*)XTh + tile * 8192 + SWZ(pb + pl, slot)) =
          *(const uint4*)&Ls2[pl * 512 + jbl * 64 + slot * 8];
    }
  }
}

// stage one pre-swizzled 8KB XT tile into LDS via linear DMA
#define STAGE_XT(tileByte) do {                                                                   \
  _Pragma("unroll")                                                                               \
  for (int i_ = 0; i_ < 2; ++i_) {                                                                \
    int S_ = i_ * 256 + t;                                                                        \
    __builtin_amdgcn_global_load_lds(                                                             \
        (const __attribute__((address_space(1))) u32*)((const char*)XTh + (tileByte) + S_ * 16),  \
        (__attribute__((address_space(3))) u32*)((char*)Xh_t + S_ * 16), 16, 0, 0);               \
  }                                                                                               \
} while (0)

// ---------------- K5: chunk states via MFMA ----------------
__global__ __launch_bounds__(256) void k_states(
    const u16* __restrict__ XTh,
    const u16* __restrict__ Bh,
    const float* __restrict__ dt, const float* __restrict__ dAcs,
    float* __restrict__ states)
{
  __shared__ u16 bpackB[64 * 65];
  __shared__ u16 BTh_t[4096];
  __shared__ u16 Xh_t[4096];
  __shared__ float wall[256];
  const int bc = blockIdx.x;
  const int hh = blockIdx.y;
  const int t  = threadIdx.x;
  const int lane = t & 63, w = t >> 6;
  const int mlo = lane & 15, gg = lane >> 4;
  const int r = t >> 2, q = (t & 3) * 16;
  const size_t base = (size_t)bc * 256;
  const float last = dAcs[(base + 255) * NH + hh];
  wall[t] = __expf(last - dAcs[(base + t) * NH + hh]) * dt[(base + t) * NH + hh];
  f32x4 acc[4];
#pragma unroll
  for (int i = 0; i < 4; ++i) acc[i] = (f32x4){0.f, 0.f, 0.f, 0.f};
  for (int jt = 0; jt < 4; ++jt) {
    const int j0 = jt * 64;
    __syncthreads();
    STAGE_XT(((size_t)(bc * NH + hh) * 4 + jt) * 8192);
    {
      const u16* bhp = &Bh[(size_t)(base + j0 + r) * DS + q];
      U4 H0, H1;
      H0.v = *(const uint4*)bhp; H1.v = *(const uint4*)(bhp + 8);
#pragma unroll
      for (int k = 0; k < 8; ++k) {
        bpackB[r * 65 + q + k]     = H0.s[k];
        bpackB[r * 65 + q + 8 + k] = H1.s[k];
      }
    }
    __syncthreads();
#pragma unroll
    for (int c = 0; c < 2; ++c) {
      U4 BH;
#pragma unroll
      for (int jj = 0; jj < 8; ++jj) {
        int j = q + c * 8 + jj;
        BH.s[jj] = f2h(h2f(bpackB[j * 65 + r]) * wall[j0 + j]);
      }
      *(uint4*)((char*)BTh_t + SWZ(r, (q >> 3) + c)) = BH.v;
    }
    __syncthreads();
#pragma unroll
    for (int s = 0; s < 2; ++s) {
      f16x8 fah = *(const f16x8*)((const char*)Xh_t + SWZ(w * 16 + mlo, s * 4 + gg));
#pragma unroll
      for (int nf = 0; nf < 4; ++nf) {
        f16x8 fbh = *(const f16x8*)((const char*)BTh_t + SWZ(nf * 16 + mlo, s * 4 + gg));
        acc[nf] = __builtin_amdgcn_mfma_f32_16x16x32_f16(fah, fbh, acc[nf], 0, 0, 0);
      }
    }
  }
  const size_t sb = ((size_t)(bc * NH + hh)) << 12;
#pragma unroll
  for (int nf = 0; nf < 4; ++nf)
#pragma unroll
    for (int reg = 0; reg < 4; ++reg) {
      int p = w * 16 + (lane >> 4) * 4 + reg;
      int n = nf * 16 + mlo;
      states[sb + (size_t)p * 64 + n] = acc[nf][reg];
    }
}

// ---------------- K6: inter-chunk scan ----------------
__global__ __launch_bounds__(256) void k_scanc(
    const float* __restrict__ states, const float* __restrict__ cdecay,
    float* __restrict__ prev)
{
  int tid = blockIdx.x * 256 + threadIdx.x;
  int pn  = tid & 4095;
  int rem = tid >> 12;
  int hh  = rem % NH;
  int b   = rem / NH;
  float carry = 0.f;
#pragma unroll
  for (int c = 0; c < 4; ++c) {
    size_t idx = ((size_t)((b * 4 + c) * NH + hh) << 12) + pn;
    prev[idx] = carry;
    carry = carry * cdecay[(b * 4 + c) * NH + hh] + states[idx];
  }
}

// ---------------- K7: y = intra + inter + D*x; i-tile pair per block; fast exp; dt folded into B ----------------
__global__ __launch_bounds__(256) void k_y(
    const u16* __restrict__ XTh,
    const u16* __restrict__ Chg, const u16* __restrict__ Bhg,
    const float* __restrict__ dtp, const float* __restrict__ dAcs,
    const float* __restrict__ prev, const float* __restrict__ Dp,
    u16* __restrict__ y)
{
  __shared__ u16 Pb_t[4096];
  __shared__ u16 Xh_t[4096];
  __shared__ u16 att_t[4096];
  __shared__ float dAc_s[256], dt_s[256], ei_s[128];
  const int bc = blockIdx.x;
  const int hh = blockIdx.y;
  const int z  = blockIdx.z;
  const int it0 = z * 2;
  const int t  = threadIdx.x;
  const int lane = t & 63, w = t >> 6;
  const int mlo = lane & 15, gg = lane >> 4;
  const int r = t >> 2, q = (t & 3) * 16;
  const int slot0 = q >> 3;
  const size_t base = (size_t)bc * 256;
  {
    float da = dAcs[(base + t) * NH + hh];
    dAc_s[t] = da;
    dt_s[t]  = dtp[(base + t) * NH + hh];
    if (t < 128) ei_s[t] = __expf(dAcs[(base + z * 128 + t) * NH + hh]);
  }
  {
    const float* pp = &prev[(((size_t)(bc * NH + hh)) << 12) + (size_t)r * 64 + q];
    U4 H0, H1;
#pragma unroll
    for (int k = 0; k < 16; ++k) {
      u16 h = f2h(pp[k]);
      if (k < 8) H0.s[k] = h; else H1.s[k - 8] = h;
    }
    *(uint4*)((char*)Pb_t + SWZ(r, slot0))     = H0.v;
    *(uint4*)((char*)Pb_t + SWZ(r, slot0 + 1)) = H1.v;
  }
  __syncthreads();
  f16x8 fc[2][2];
#pragma unroll
  for (int iti = 0; iti < 2; ++iti)
#pragma unroll
    for (int s = 0; s < 2; ++s)
      fc[iti][s] = *(const f16x8*)&Chg[(size_t)(base + (it0 + iti) * 64 + w * 16 + mlo) * DS +
                                       (s * 4 + gg) * 8];
  f32x4 accy[2][4];
#pragma unroll
  for (int i = 0; i < 2; ++i)
#pragma unroll
    for (int j = 0; j < 4; ++j) accy[i][j] = (f32x4){0.f, 0.f, 0.f, 0.f};
#pragma unroll
  for (int s = 0; s < 2; ++s)
#pragma unroll
    for (int pf = 0; pf < 4; ++pf) {
      f16x8 fph = *(const f16x8*)((const char*)Pb_t + SWZ(pf * 16 + mlo, s * 4 + gg));
#pragma unroll
      for (int iti = 0; iti < 2; ++iti)
        accy[iti][pf] = __builtin_amdgcn_mfma_f32_16x16x32_f16(fc[iti][s], fph, accy[iti][pf], 0, 0, 0);
    }
  const int ilb = w * 16 + (lane >> 4) * 4;
#pragma unroll
  for (int iti = 0; iti < 2; ++iti)
#pragma unroll
    for (int pf = 0; pf < 4; ++pf)
#pragma unroll
      for (int reg = 0; reg < 4; ++reg)
        accy[iti][pf][reg] *= ei_s[iti * 64 + ilb + reg];

  u32 xdv[2][8];
  for (int jt = 0; jt <= it0 + 1; ++jt) {
    __syncthreads();
    STAGE_XT(((size_t)(bc * NH + hh) * 4 + jt) * 8192);
    {
      // stage B tile with dt_j folded in
      const u16* bh = &Bhg[(size_t)(base + jt * 64 + r) * DS + q];
      U4 V0, V1;
      V0.v = *(const uint4*)bh; V1.v = *(const uint4*)(bh + 8);
      float wj = dt_s[jt * 64 + r];
#pragma unroll
      for (int k = 0; k < 8; ++k) {
        V0.s[k] = f2h(h2f(V0.s[k]) * wj);
        V1.s[k] = f2h(h2f(V1.s[k]) * wj);
      }
      *(uint4*)((char*)Pb_t + SWZ(r, slot0))     = V0.v;
      *(uint4*)((char*)Pb_t + SWZ(r, slot0 + 1)) = V1.v;
    }
    __syncthreads();
#pragma unroll
    for (int iti = 0; iti < 2; ++iti) {
      if (jt == it0 + iti) {
#pragma unroll
        for (int pf = 0; pf < 4; ++pf)
#pragma unroll
          for (int rp = 0; rp < 2; ++rp) {
            int j0l = ilb + rp * 2;
            u16 a = *(const u16*)((const char*)Xh_t + SWZ(pf * 16 + mlo, j0l >> 3) + (j0l & 7) * 2);
            u16 b2 = *(const u16*)((const char*)Xh_t + SWZ(pf * 16 + mlo, (j0l + 1) >> 3) + ((j0l + 1) & 7) * 2);
            xdv[iti][pf * 2 + rp] = (u32)a | ((u32)b2 << 16);
          }
      }
    }
#pragma unroll
    for (int iti = 0; iti < 2; ++iti) {
      const int ita = it0 + iti;
      if (jt > ita) continue;
      f32x4 g[4];
#pragma unroll
      for (int i = 0; i < 4; ++i) g[i] = (f32x4){0.f, 0.f, 0.f, 0.f};
#pragma unroll
      for (int s = 0; s < 2; ++s)
#pragma unroll
        for (int jf = 0; jf < 4; ++jf) {
          f16x8 fbh = *(const f16x8*)((const char*)Pb_t + SWZ(jf * 16 + mlo, s * 4 + gg));
          g[jf] = __builtin_amdgcn_mfma_f32_16x16x32_f16(fc[iti][s], fbh, g[jf], 0, 0, 0);
        }
#pragma unroll
      for (int jf = 0; jf < 4; ++jf)
#pragma unroll
        for (int reg = 0; reg < 4; ++reg) {
          int il = ita * 64 + ilb + reg;
          int jl = jt * 64 + jf * 16 + mlo;
          float av = (jl <= il) ? g[jf][reg] * __expf(dAc_s[il] - dAc_s[jl]) : 0.f;
          *(u16*)((char*)att_t + SWZ(il & 63, (jl & 63) >> 3) + (jl & 7) * 2) = f2h(av);
        }
#pragma unroll
      for (int s = 0; s < 2; ++s) {
        f16x8 fa = *(const f16x8*)((const char*)att_t + SWZ(w * 16 + mlo, s * 4 + gg));
#pragma unroll
        for (int pf = 0; pf < 4; ++pf) {
          f16x8 fxh = *(const f16x8*)((const char*)Xh_t + SWZ(pf * 16 + mlo, s * 4 + gg));
          accy[iti][pf] = __builtin_amdgcn_mfma_f32_16x16x32_f16(fa, fxh, accy[iti][pf], 0, 0, 0);
        }
      }
    }
  }
  const float Dh = Dp[hh];
#pragma unroll
  for (int iti = 0; iti < 2; ++iti)
#pragma unroll
    for (int pf = 0; pf < 4; ++pf)
#pragma unroll
      for (int reg = 0; reg < 4; ++reg) {
        size_t row = base + (it0 + iti) * 64 + ilb + reg;
        int col = hh * HD + pf * 16 + mlo;
        u32 pk = xdv[iti][pf * 2 + (reg >> 1)];
        u16 xv = (reg & 1) ? (u16)(pk >> 16) : (u16)pk;
        y[row * DI + col] = f2h(accy[iti][pf][reg] + Dh * h2f(xv));
      }
}

// ---------------- K8: LayerNorm * z (both fp16 in) -> fp16 hi/lo pair ----------------
__global__ __launch_bounds__(256) void k_norm(
    const u16* __restrict__ z, const float* __restrict__ nw,
    const float* __restrict__ nb, const u16* __restrict__ y,
    u16* __restrict__ yh, u16* __restrict__ yl)
{
  __shared__ float rs[4], rq[4];
  const size_t row = blockIdx.x;
  const int t = threadIdx.x;
  float v[3];
  float s = 0.f, sq = 0.f;
#pragma unroll
  for (int r = 0; r < 3; ++r) {
    v[r] = h2f(y[row * DI + r * 256 + t]);
    s += v[r];
    sq = fmaf(v[r], v[r], sq);
  }
#pragma unroll
  for (int off = 32; off > 0; off >>= 1) {
    s  += __shfl_down(s, off, 64);
    sq += __shfl_down(sq, off, 64);
  }
  const int wid = t >> 6, lane = t & 63;
  if (lane == 0) { rs[wid] = s; rq[wid] = sq; }
  __syncthreads();
  if (t == 0) {
    rs[0] = rs[0] + rs[1] + rs[2] + rs[3];
    rq[0] = rq[0] + rq[1] + rq[2] + rq[3];
  }
  __syncthreads();
  const float mu   = rs[0] * (1.f / DI);
  const float var  = rq[0] * (1.f / DI) - mu * mu;
  const float rstd = 1.f / sqrtf(var + EPS_);
#pragma unroll
  for (int r = 0; r < 3; ++r) {
    int d = r * 256 + t;
    float o = (v[r] - mu) * rstd * nw[d] + nb[d];
    float p = o * h2f(z[row * DI + d]);
    u16 h, l;
    hsplit(p, h, l);
    yh[row * DI + d] = h;
    yl[row * DI + d] = l;
  }
}

extern "C" void kernel_launch(void* const* d_in, const int* in_sizes, int n_in,
                              void* d_out, int out_size, void* d_ws, size_t ws_size,
                              hipStream_t stream)
{
  const float* u    = (const float*)d_in[0];
  const float* ipw  = (const float*)d_in[1];
  const float* cw   = (const float*)d_in[2];
  const float* cb   = (const float*)d_in[3];
  const float* dtb  = (const float*)d_in[4];
  const float* Alog = (const float*)d_in[5];
  const float* Dp   = (const float*)d_in[6];
  const float* nw   = (const float*)d_in[7];
  const float* nb   = (const float*)d_in[8];
  const float* opw  = (const float*)d_in[9];
  float* out = (float*)d_out;

  float* ws = (float*)d_ws;
  size_t off = 0;
  u16*   z16     = (u16*)(ws + off); off += (size_t)B_ * L_ * DI / 2;
  u16*   xBC16   = (u16*)(ws + off); off += (size_t)B_ * L_ * CONVD / 2;
  float* dt_buf  = ws + off; off += (size_t)B_ * L_ * NH;
  float* x_buf   = ws + off; off += (size_t)B_ * L_ * DI;     // alias space only
  u16*   y16     = (u16*)(ws + off); off += (size_t)B_ * L_ * DI / 2;
  u16*   Bh_buf  = (u16*)(ws + off); off += (size_t)B_ * L_ * DS / 2;
  u16*   Ch_buf  = (u16*)(ws + off); off += (size_t)B_ * L_ * DS / 2;
  float* dAcs    = ws + off; off += (size_t)B_ * L_ * NH;
  float* cdec    = ws + off; off += (size_t)B_ * NCH * NH;
  float* st_buf  = ws + off; off += (size_t)B_ * NCH * NH * HD * DS;
  float* pv_buf  = ws + off; off += (size_t)B_ * NCH * NH * HD * DS;
  u16*   Woh     = (u16*)(ws + off); off += (size_t)DM * DI / 2;
  u16*   XTh_buf = (u16*)(ws + off); off += (size_t)B_ * NCH * NH * 4 * 4096 / 2;

  // aliases inside x_buf (dead/live windows don't overlap)
  u16* Ah = (u16*)x_buf;                         // consumed by gemm1
  u16* Whip = Ah + (size_t)B_ * L_ * DM;
  u16* yh = (u16*)x_buf;                         // written by k_norm (after gemm1)
  u16* yl = yh + (size_t)B_ * L_ * DI;

  hipLaunchKernelGGL(k_cvtA, dim3(8, 12, 16), dim3(256), 0, stream, u, Ah);
  hipLaunchKernelGGL(k_cvtWh, dim3((NIP * DM / 4 + 255) / 256), dim3(256), 0, stream,
                     ipw, Whip, NIP * DM / 4);
  hipLaunchKernelGGL(k_cvtWh, dim3((DM * DI / 4 + 255) / 256), dim3(256), 0, stream,
                     opw, Woh, DM * DI / 4);
  hipLaunchKernelGGL(k_dtp, dim3(64), dim3(256), 0, stream,
                     u, ipw, dtb, Alog, dt_buf, dAcs, cdec);
  hipLaunchKernelGGL(k_gemm1, dim3(128, 13), dim3(256), 0, stream,
                     Ah, Whip, z16, xBC16);
  hipLaunchKernelGGL(k_conv, dim3(56, 2, 16), dim3(256), 0, stream,
                     xBC16, cw, cb, XTh_buf, Bh_buf, Ch_buf);
  hipLaunchKernelGGL(k_states, dim3(64, 12), dim3(256), 0, stream,
                     XTh_buf, Bh_buf, dt_buf, dAcs, st_buf);
  hipLaunchKernelGGL(k_scanc, dim3(3072), dim3(256), 0, stream, st_buf, cdec, pv_buf);
  hipLaunchKernelGGL(k_y, dim3(64, 12, 2), dim3(256), 0, stream,
                     XTh_buf, Ch_buf, Bh_buf, dt_buf, dAcs, pv_buf, Dp, y16);
  hipLaunchKernelGGL(k_norm, dim3(16384), dim3(256), 0, stream, z16, nw, nb, y16, yh, yl);
  hipLaunchKernelGGL(k_gemm2, dim3(128, 3), dim3(256), 0, stream, yh, yl, Woh, out);
}

// Round 16
// 205.070 us; speedup vs baseline: 1.7074x; 1.0776x over previous
//
#include <hip/hip_runtime.h>
#include <hip/hip_bf16.h>

#define B_    16
#define L_    1024
#define DM    384
#define DIP   1676
#define NIP   1664
#define DI    768
#define CONVD 896
#define NH    12
#define HD    64
#define DS    64
#define NCH   4
#define CH    256
#define EPS_  1e-5f

typedef unsigned short u16;
typedef unsigned int   u32;
typedef __attribute__((ext_vector_type(8))) _Float16 f16x8;
typedef __attribute__((ext_vector_type(4))) float f32x4;

union U4 { uint4 v; u16 s[8]; };

// byte offset of 16B slot `slot` in row `row` of a [64][64]-16bit LDS tile (128B rows, XOR swizzle)
#define SWZ(row, slot) (((row) << 7) + ((((slot) ^ ((row) & 7)) & 7) << 4))

// ---- fp16 helpers ----
__device__ __forceinline__ u16 f2h(float v) { return __builtin_bit_cast(u16, (_Float16)v); }
__device__ __forceinline__ float h2f(u16 h) { return (float)__builtin_bit_cast(_Float16, h); }
__device__ __forceinline__ void hsplit(float v, u16& h, u16& l) {
  _Float16 hh = (_Float16)v;
  _Float16 ll = (_Float16)(v - (float)hh);
  h = __builtin_bit_cast(u16, hh);
  l = __builtin_bit_cast(u16, ll);
}

// ---------------- converters ----------------
__global__ __launch_bounds__(256) void k_cvtA(const float* __restrict__ u,
                                              u16* __restrict__ Ah)
{
  __shared__ float Ls[32][129];
  const int t  = threadIdx.x;
  const int l0 = blockIdx.x * 128;
  const int k0 = blockIdx.y * 32;
  const int b  = blockIdx.z;
#pragma unroll
  for (int r = 0; r < 4; ++r) {
    int idx = r * 256 + t;
    int kk = idx >> 5, q = idx & 31;
    float4 v = *(const float4*)&u[((size_t)(b * DM + k0 + kk)) * L_ + l0 + q * 4];
    Ls[kk][q * 4 + 0] = v.x; Ls[kk][q * 4 + 1] = v.y;
    Ls[kk][q * 4 + 2] = v.z; Ls[kk][q * 4 + 3] = v.w;
  }
  __syncthreads();
#pragma unroll
  for (int it = 0; it < 2; ++it) {
    int task = it * 256 + t;
    int l = task >> 2, kq = (task & 3) * 8;
    u32 hw[4];
#pragma unroll
    for (int j = 0; j < 4; ++j) {
      u16 h0 = f2h(Ls[kq + 2 * j + 0][l]);
      u16 h1 = f2h(Ls[kq + 2 * j + 1][l]);
      hw[j] = (u32)h0 | ((u32)h1 << 16);
    }
    size_t off = ((size_t)(b * L_ + l0 + l)) * DM + k0 + kq;
    *(uint4*)&Ah[off] = make_uint4(hw[0], hw[1], hw[2], hw[3]);
  }
}

__global__ __launch_bounds__(256) void k_cvtWh(const float* __restrict__ W,
                                               u16* __restrict__ Wh, int total4)
{
  int i = blockIdx.x * 256 + threadIdx.x;
  if (i >= total4) return;
  int e = i * 4;
  float4 v = *(const float4*)&W[e];
  u16 h[4] = {f2h(v.x), f2h(v.y), f2h(v.z), f2h(v.w)};
  *(uint2*)&Wh[e] = make_uint2((u32)h[0] | ((u32)h[1] << 16), (u32)h[2] | ((u32)h[3] << 16));
}

// ---------------- K_dtp: per-(chunk,head) GEMV + softplus + cumsum ----------------
__global__ __launch_bounds__(256) void k_dtp(
    const float* __restrict__ u, const float* __restrict__ ipw,
    const float* __restrict__ dtb, const float* __restrict__ A_log,
    float* __restrict__ dt, float* __restrict__ dAcs, float* __restrict__ cdecay)
{
  __shared__ float wdt[DM];
  __shared__ float ws4[4];
  const int bc = blockIdx.x;           // b*4 + c
  const int h  = blockIdx.y;           // head
  const int b  = bc >> 2, l0 = (bc & 3) * 256;
  const int t  = threadIdx.x;
  const int lane = t & 63, w = t >> 6;
  for (int i = t; i < DM; i += 256) wdt[i] = ipw[(size_t)(NIP + h) * DM + i];
  __syncthreads();
  const float* ub = u + (size_t)b * DM * L_ + l0 + t;
  float acc = 0.f;
#pragma unroll 8
  for (int k = 0; k < DM; ++k)
    acc = fmaf(ub[(size_t)k * L_], wdt[k], acc);
  const size_t row = (size_t)bc * 256 + t;
  float logit = acc + dtb[h];
  float dtv = (logit > 20.f) ? logit : log1pf(expf(logit));
  dt[row * NH + h] = dtv;
  float xv = dtv * (-expf(A_log[h]));
#pragma unroll
  for (int off = 1; off < 64; off <<= 1) {
    float y = __shfl_up(xv, off, 64);
    if (lane >= off) xv += y;
  }
  if (lane == 63) ws4[w] = xv;
  __syncthreads();
  float add = 0.f;
#pragma unroll
  for (int i = 0; i < 4; ++i) if (i < w) add += ws4[i];
  xv += add;
  dAcs[row * NH + h] = xv;
  if (t == 255) cdecay[bc * NH + h] = expf(xv);
}

// 2-stream staging (A, W) of one 128x32 u16 K-tile set
#define STAGE2(bufbase, k0) do {                                                                \
  _Pragma("unroll")                                                                             \
  for (int i_ = 0; i_ < 2; ++i_) {                                                              \
    int S_ = i_ * 256 + t;                                                                      \
    int m_ = S_ >> 2;                                                                           \
    int g_ = (S_ ^ (m_ >> 1)) & 3;                                                              \
    size_t goff_ = (size_t)m_ * DM + (k0) + g_ * 8;                                             \
    __builtin_amdgcn_global_load_lds((const __attribute__((address_space(1))) u32*)(g0 + goff_),\
        (__attribute__((address_space(3))) u32*)(lds + (bufbase) + S_ * 8), 16, 0, 0);          \
    __builtin_amdgcn_global_load_lds((const __attribute__((address_space(1))) u32*)(g2 + goff_),\
        (__attribute__((address_space(3))) u32*)(lds + (bufbase) + 4096 + S_ * 8), 16, 0, 0);   \
  }                                                                                             \
} while (0)

// ---------------- fp16 single MFMA GEMM: in_proj (z fp16, xBC fp16) ----------------
__global__ __launch_bounds__(256) void k_gemm1(
    const u16* __restrict__ Ah,
    const u16* __restrict__ Wh,
    u16* __restrict__ z, u16* __restrict__ xBC)
{
  __shared__ u16 lds[16384];
  const int t = threadIdx.x;
  const int lane = t & 63, wid = t >> 6;
  const int wr = wid >> 1, wc = wid & 1;
  const int gg = lane >> 4, mlo = lane & 15;
  const int m0 = blockIdx.x * 128, n0 = blockIdx.y * 128;
  f32x4 acc[4][4];
#pragma unroll
  for (int i = 0; i < 4; ++i)
#pragma unroll
    for (int j = 0; j < 4; ++j) acc[i][j] = (f32x4){0.f, 0.f, 0.f, 0.f};
  const u16* g0 = Ah + (size_t)m0 * DM;
  const u16* g2 = Wh + (size_t)n0 * DM;
  STAGE2(0, 0);
  __syncthreads();
  int cur = 0;
  for (int kt = 0; kt < DM / 32; ++kt) {
    if (kt + 1 < DM / 32) STAGE2((cur ^ 1) * 8192, (kt + 1) * 32);
    const char* ldsb = (const char*)lds + cur * 16384;
    f16x8 fa[4], fb[4];
#pragma unroll
    for (int mf = 0; mf < 4; ++mf) {
      int m = wr * 64 + mf * 16 + mlo;
      int off = m * 64 + (((gg ^ (m >> 1)) & 3) << 4);
      fa[mf]  = *(const f16x8*)(ldsb + off);
    }
#pragma unroll
    for (int nf = 0; nf < 4; ++nf) {
      int n = wc * 64 + nf * 16 + mlo;
      int off = n * 64 + (((gg ^ (n >> 1)) & 3) << 4);
      fb[nf]  = *(const f16x8*)(ldsb + 8192 + off);
    }
#pragma unroll
    for (int mf = 0; mf < 4; ++mf)
#pragma unroll
      for (int nf = 0; nf < 4; ++nf)
        acc[mf][nf] = __builtin_amdgcn_mfma_f32_16x16x32_f16(fa[mf], fb[nf], acc[mf][nf], 0, 0, 0);
    __syncthreads();
    cur ^= 1;
  }
  const int rb = m0 + wr * 64 + (lane >> 4) * 4;
  const int cb = n0 + wc * 64 + mlo;
#pragma unroll
  for (int mf = 0; mf < 4; ++mf)
#pragma unroll
    for (int nf = 0; nf < 4; ++nf) {
      int col = cb + nf * 16;
#pragma unroll
      for (int r = 0; r < 4; ++r) {
        int row = rb + mf * 16 + r;
        float v = acc[mf][nf][r];
        if (col < DI) z[(size_t)row * DI + col] = f2h(v);
        else xBC[(size_t)row * CONVD + (col - DI)] = f2h(v);
      }
    }
}

// 3-stream staging for gemm2 (yh, yl, W)
#define STAGE3B(bufbase, k0) do {                                                               \
  _Pragma("unroll")                                                                             \
  for (int i_ = 0; i_ < 2; ++i_) {                                                              \
    int S_ = i_ * 256 + t;                                                                      \
    int m_ = S_ >> 2;                                                                           \
    int g_ = (S_ ^ (m_ >> 1)) & 3;                                                              \
    size_t goff_ = (size_t)m_ * DI + (k0) + g_ * 8;                                             \
    __builtin_amdgcn_global_load_lds((const __attribute__((address_space(1))) u32*)(g0 + goff_),\
        (__attribute__((address_space(3))) u32*)(lds + (bufbase) + S_ * 8), 16, 0, 0);          \
    __builtin_amdgcn_global_load_lds((const __attribute__((address_space(1))) u32*)(g1 + goff_),\
        (__attribute__((address_space(3))) u32*)(lds + (bufbase) + 4096 + S_ * 8), 16, 0, 0);   \
    __builtin_amdgcn_global_load_lds((const __attribute__((address_space(1))) u32*)(g2 + goff_),\
        (__attribute__((address_space(3))) u32*)(lds + (bufbase) + 8192 + S_ * 8), 16, 0, 0);   \
  }                                                                                             \
} while (0)

// ---------------- fp16x2 MFMA GEMM: out_proj ----------------
__global__ __launch_bounds__(256) void k_gemm2(
    const u16* __restrict__ Ah, const u16* __restrict__ Al,
    const u16* __restrict__ Bh,
    float* __restrict__ out)
{
  __shared__ u16 lds[24576];
  const int t = threadIdx.x;
  const int lane = t & 63, wid = t >> 6;
  const int wr = wid >> 1, wc = wid & 1;
  const int gg = lane >> 4, mlo = lane & 15;
  const int m0 = blockIdx.x * 128, n0 = blockIdx.y * 128;
  f32x4 acc[4][4];
#pragma unroll
  for (int i = 0; i < 4; ++i)
#pragma unroll
    for (int j = 0; j < 4; ++j) acc[i][j] = (f32x4){0.f, 0.f, 0.f, 0.f};
  const u16* g0 = Ah + (size_t)m0 * DI;
  const u16* g1 = Al + (size_t)m0 * DI;
  const u16* g2 = Bh + (size_t)n0 * DI;
  STAGE3B(0, 0);
  __syncthreads();
  int cur = 0;
  for (int kt = 0; kt < DI / 32; ++kt) {
    if (kt + 1 < DI / 32) STAGE3B((cur ^ 1) * 12288, (kt + 1) * 32);
    const char* ldsb = (const char*)lds + cur * 24576;
    f16x8 fa[4], fal[4], fb[4];
#pragma unroll
    for (int mf = 0; mf < 4; ++mf) {
      int m = wr * 64 + mf * 16 + mlo;
      int off = m * 64 + (((gg ^ (m >> 1)) & 3) << 4);
      fa[mf]  = *(const f16x8*)(ldsb + off);
      fal[mf] = *(const f16x8*)(ldsb + 8192 + off);
    }
#pragma unroll
    for (int nf = 0; nf < 4; ++nf) {
      int n = wc * 64 + nf * 16 + mlo;
      int off = n * 64 + (((gg ^ (n >> 1)) & 3) << 4);
      fb[nf]  = *(const f16x8*)(ldsb + 16384 + off);
    }
#pragma unroll
    for (int mf = 0; mf < 4; ++mf)
#pragma unroll
      for (int nf = 0; nf < 4; ++nf) {
        acc[mf][nf] = __builtin_amdgcn_mfma_f32_16x16x32_f16(fa[mf],  fb[nf], acc[mf][nf], 0, 0, 0);
        acc[mf][nf] = __builtin_amdgcn_mfma_f32_16x16x32_f16(fal[mf], fb[nf], acc[mf][nf], 0, 0, 0);
      }
    __syncthreads();
    cur ^= 1;
  }
  const int rb = m0 + wr * 64 + (lane >> 4) * 4;
  const int cb = n0 + wc * 64 + mlo;
#pragma unroll
  for (int mf = 0; mf < 4; ++mf)
#pragma unroll
    for (int nf = 0; nf < 4; ++nf) {
      int col = cb + nf * 16;
#pragma unroll
      for (int r = 0; r < 4; ++r) {
        int row = rb + mf * 16 + r;
        int b = row >> 10, l = row & 1023;
        out[((size_t)(b * DM + col)) * L_ + l] = acc[mf][nf][r];
      }
    }
}

// ---------------- K2: depthwise conv; x-channels -> pre-swizzled XT fp16 tiles; B/C fp16 ----------------
#define CC 16
__global__ __launch_bounds__(256) void k_conv(
    const u16* __restrict__ xBC, const float* __restrict__ cw,
    const float* __restrict__ cb,
    u16* __restrict__ XTh,
    u16* __restrict__ Bh,
    u16* __restrict__ Chh)
{
  __shared__ float Ls[18][32][CC];
  const int t  = threadIdx.x;
  const int c0 = blockIdx.x * CC;
  const int h0 = blockIdx.y * 16;
  const int b  = blockIdx.z;
#pragma unroll
  for (int k = 0; k < 9; ++k) {
    int f = k * 256 + t;
    int fc4 = f & 3, fw = (f >> 2) & 31, fr = f >> 7;
    int h = h0 + fr - 1;
    U4 v; v.v = make_uint4(0, 0, 0, 0);
    if (h >= 0 && h < 32) {
      uint2 p = *(const uint2*)&xBC[((size_t)(b * 1024 + h * 32 + fw)) * CONVD + c0 + fc4 * 4];
      v.v.x = p.x; v.v.y = p.y;
    }
    Ls[fr][fw][fc4 * 4 + 0] = h2f(v.s[0]);
    Ls[fr][fw][fc4 * 4 + 1] = h2f(v.s[1]);
    Ls[fr][fw][fc4 * 4 + 2] = h2f(v.s[2]);
    Ls[fr][fw][fc4 * 4 + 3] = h2f(v.s[3]);
  }
  const int c4 = t & 3;
  const int w  = (t >> 2) & 31;
  const int hb = t >> 7;
  float wt[4][9];
  float bias[4];
#pragma unroll
  for (int j = 0; j < 4; ++j) {
    int c = c0 + c4 * 4 + j;
    bias[j] = cb[c];
#pragma unroll
    for (int kb = 0; kb < 9; ++kb) wt[j][kb] = cw[c * 9 + kb];
  }
  __syncthreads();
  const bool isx = (c0 < DI);
  u16 xh16[8][4];
#pragma unroll
  for (int k = 0; k < 8; ++k) {
    int h = hb * 8 + k;
    float acc[4] = {bias[0], bias[1], bias[2], bias[3]};
#pragma unroll
    for (int dh = 0; dh < 3; ++dh) {
#pragma unroll
      for (int dw = -1; dw <= 1; ++dw) {
        int ww = w + dw;
        if (ww < 0 || ww > 31) continue;
        const float* p = &Ls[h + dh][ww][c4 * 4];
        int kb = dh * 3 + (dw + 1);
#pragma unroll
        for (int j = 0; j < 4; ++j) acc[j] = fmaf(p[j], wt[j][kb], acc[j]);
      }
    }
    float s4[4];
#pragma unroll
    for (int j = 0; j < 4; ++j) { float v = acc[j]; s4[j] = v / (1.f + expf(-v)); }
    if (isx) {
#pragma unroll
      for (int j = 0; j < 4; ++j) xh16[k][j] = f2h(s4[j]);
    } else {
      size_t row = (size_t)b * 1024 + (h0 + h) * 32 + w;
      u16 hv[4] = {f2h(s4[0]), f2h(s4[1]), f2h(s4[2]), f2h(s4[3])};
      uint2 hp = make_uint2((u32)hv[0] | ((u32)hv[1] << 16), (u32)hv[2] | ((u32)hv[3] << 16));
      int c = c0 + c4 * 4;
      if (c < DI + DS) *(uint2*)&Bh[row * DS + (c - DI)] = hp;
      else             *(uint2*)&Chh[row * DS + (c - DI - DS)] = hp;
    }
  }
  if (isx) {
    __syncthreads();
    u16* Ls2 = (u16*)Ls;
#pragma unroll
    for (int k = 0; k < 8; ++k) {
      int pos = (hb * 8 + k) * 32 + w;
#pragma unroll
      for (int j = 0; j < 4; ++j)
        Ls2[(c4 * 4 + j) * 512 + pos] = xh16[k][j];
    }
    __syncthreads();
    const int hh = c0 >> 6;
    const int pb = c0 & 63;
#pragma unroll
    for (int i = 0; i < 4; ++i) {
      int cid = i * 256 + t;
      int pl = cid >> 6, rem = cid & 63;
      int jbl = rem >> 3, slot = rem & 7;
      int labs = h0 * 32 + jbl * 64;
      size_t tile = ((size_t)(b * 4 + (labs >> 8)) * NH + hh) * 4 + ((labs >> 6) & 3);
      *(uint4*)((char*)XTh + tile * 8192 + SWZ(pb + pl, slot)) =
          *(const uint4*)&Ls2[pl * 512 + jbl * 64 + slot * 8];
    }
  }
}

// stage one pre-swizzled 8KB XT tile into LDS via linear DMA
#define STAGE_XT(tileByte) do {                                                                   \
  _Pragma("unroll")                                                                               \
  for (int i_ = 0; i_ < 2; ++i_) {                                                                \
    int S_ = i_ * 256 + t;                                                                        \
    __builtin_amdgcn_global_load_lds(                                                             \
        (const __attribute__((address_space(1))) u32*)((const char*)XTh + (tileByte) + S_ * 16),  \
        (__attribute__((address_space(3))) u32*)((char*)Xh_t + S_ * 16), 16, 0, 0);               \
  }                                                                                               \
} while (0)

// ---------------- K5: chunk states via MFMA ----------------
__global__ __launch_bounds__(256) void k_states(
    const u16* __restrict__ XTh,
    const u16* __restrict__ Bh,
    const float* __restrict__ dt, const float* __restrict__ dAcs,
    float* __restrict__ states)
{
  __shared__ u16 bpackB[64 * 65];
  __shared__ u16 BTh_t[4096];
  __shared__ u16 Xh_t[4096];
  __shared__ float wall[256];
  const int bc = blockIdx.x;
  const int hh = blockIdx.y;
  const int t  = threadIdx.x;
  const int lane = t & 63, w = t >> 6;
  const int mlo = lane & 15, gg = lane >> 4;
  const int r = t >> 2, q = (t & 3) * 16;
  const size_t base = (size_t)bc * 256;
  const float last = dAcs[(base + 255) * NH + hh];
  wall[t] = __expf(last - dAcs[(base + t) * NH + hh]) * dt[(base + t) * NH + hh];
  f32x4 acc[4];
#pragma unroll
  for (int i = 0; i < 4; ++i) acc[i] = (f32x4){0.f, 0.f, 0.f, 0.f};
  for (int jt = 0; jt < 4; ++jt) {
    const int j0 = jt * 64;
    __syncthreads();
    STAGE_XT(((size_t)(bc * NH + hh) * 4 + jt) * 8192);
    {
      const u16* bhp = &Bh[(size_t)(base + j0 + r) * DS + q];
      U4 H0, H1;
      H0.v = *(const uint4*)bhp; H1.v = *(const uint4*)(bhp + 8);
#pragma unroll
      for (int k = 0; k < 8; ++k) {
        bpackB[r * 65 + q + k]     = H0.s[k];
        bpackB[r * 65 + q + 8 + k] = H1.s[k];
      }
    }
    __syncthreads();
#pragma unroll
    for (int c = 0; c < 2; ++c) {
      U4 BH;
#pragma unroll
      for (int jj = 0; jj < 8; ++jj) {
        int j = q + c * 8 + jj;
        BH.s[jj] = f2h(h2f(bpackB[j * 65 + r]) * wall[j0 + j]);
      }
      *(uint4*)((char*)BTh_t + SWZ(r, (q >> 3) + c)) = BH.v;
    }
    __syncthreads();
#pragma unroll
    for (int s = 0; s < 2; ++s) {
      f16x8 fah = *(const f16x8*)((const char*)Xh_t + SWZ(w * 16 + mlo, s * 4 + gg));
#pragma unroll
      for (int nf = 0; nf < 4; ++nf) {
        f16x8 fbh = *(const f16x8*)((const char*)BTh_t + SWZ(nf * 16 + mlo, s * 4 + gg));
        acc[nf] = __builtin_amdgcn_mfma_f32_16x16x32_f16(fah, fbh, acc[nf], 0, 0, 0);
      }
    }
  }
  const size_t sb = ((size_t)(bc * NH + hh)) << 12;
#pragma unroll
  for (int nf = 0; nf < 4; ++nf)
#pragma unroll
    for (int reg = 0; reg < 4; ++reg) {
      int p = w * 16 + (lane >> 4) * 4 + reg;
      int n = nf * 16 + mlo;
      states[sb + (size_t)p * 64 + n] = acc[nf][reg];
    }
}

// ---------------- K6: inter-chunk scan ----------------
__global__ __launch_bounds__(256) void k_scanc(
    const float* __restrict__ states, const float* __restrict__ cdecay,
    float* __restrict__ prev)
{
  int tid = blockIdx.x * 256 + threadIdx.x;
  int pn  = tid & 4095;
  int rem = tid >> 12;
  int hh  = rem % NH;
  int b   = rem / NH;
  float carry = 0.f;
#pragma unroll
  for (int c = 0; c < 4; ++c) {
    size_t idx = ((size_t)((b * 4 + c) * NH + hh) << 12) + pn;
    prev[idx] = carry;
    carry = carry * cdecay[(b * 4 + c) * NH + hh] + states[idx];
  }
}

// ---------------- K7: y = intra + inter + D*x; i-tile pair per block; fast exp; dt folded into B ----------------
__global__ __launch_bounds__(256) void k_y(
    const u16* __restrict__ XTh,
    const u16* __restrict__ Chg, const u16* __restrict__ Bhg,
    const float* __restrict__ dtp, const float* __restrict__ dAcs,
    const float* __restrict__ prev, const float* __restrict__ Dp,
    u16* __restrict__ y)
{
  __shared__ u16 Pb_t[4096];
  __shared__ u16 Xh_t[4096];
  __shared__ u16 att_t[4096];
  __shared__ float dAc_s[256], dt_s[256], ei_s[128];
  const int bc = blockIdx.x;
  const int hh = blockIdx.y;
  const int z  = blockIdx.z;
  const int it0 = z * 2;
  const int t  = threadIdx.x;
  const int lane = t & 63, w = t >> 6;
  const int mlo = lane & 15, gg = lane >> 4;
  const int r = t >> 2, q = (t & 3) * 16;
  const int slot0 = q >> 3;
  const size_t base = (size_t)bc * 256;
  {
    float da = dAcs[(base + t) * NH + hh];
    dAc_s[t] = da;
    dt_s[t]  = dtp[(base + t) * NH + hh];
    if (t < 128) ei_s[t] = __expf(dAcs[(base + z * 128 + t) * NH + hh]);
  }
  {
    const float* pp = &prev[(((size_t)(bc * NH + hh)) << 12) + (size_t)r * 64 + q];
    U4 H0, H1;
#pragma unroll
    for (int k = 0; k < 16; ++k) {
      u16 h = f2h(pp[k]);
      if (k < 8) H0.s[k] = h; else H1.s[k - 8] = h;
    }
    *(uint4*)((char*)Pb_t + SWZ(r, slot0))     = H0.v;
    *(uint4*)((char*)Pb_t + SWZ(r, slot0 + 1)) = H1.v;
  }
  __syncthreads();
  f16x8 fc[2][2];
#pragma unroll
  for (int iti = 0; iti < 2; ++iti)
#pragma unroll
    for (int s = 0; s < 2; ++s)
      fc[iti][s] = *(const f16x8*)&Chg[(size_t)(base + (it0 + iti) * 64 + w * 16 + mlo) * DS +
                                       (s * 4 + gg) * 8];
  f32x4 accy[2][4];
#pragma unroll
  for (int i = 0; i < 2; ++i)
#pragma unroll
    for (int j = 0; j < 4; ++j) accy[i][j] = (f32x4){0.f, 0.f, 0.f, 0.f};
#pragma unroll
  for (int s = 0; s < 2; ++s)
#pragma unroll
    for (int pf = 0; pf < 4; ++pf) {
      f16x8 fph = *(const f16x8*)((const char*)Pb_t + SWZ(pf * 16 + mlo, s * 4 + gg));
#pragma unroll
      for (int iti = 0; iti < 2; ++iti)
        accy[iti][pf] = __builtin_amdgcn_mfma_f32_16x16x32_f16(fc[iti][s], fph, accy[iti][pf], 0, 0, 0);
    }
  const int ilb = w * 16 + (lane >> 4) * 4;
#pragma unroll
  for (int iti = 0; iti < 2; ++iti)
#pragma unroll
    for (int pf = 0; pf < 4; ++pf)
#pragma unroll
      for (int reg = 0; reg < 4; ++reg)
        accy[iti][pf][reg] *= ei_s[iti * 64 + ilb + reg];

  u32 xdv[2][8];
  for (int jt = 0; jt <= it0 + 1; ++jt) {
    __syncthreads();
    STAGE_XT(((size_t)(bc * NH + hh) * 4 + jt) * 8192);
    {
      const u16* bh = &Bhg[(size_t)(base + jt * 64 + r) * DS + q];
      U4 V0, V1;
      V0.v = *(const uint4*)bh; V1.v = *(const uint4*)(bh + 8);
      float wj = dt_s[jt * 64 + r];
#pragma unroll
      for (int k = 0; k < 8; ++k) {
        V0.s[k] = f2h(h2f(V0.s[k]) * wj);
        V1.s[k] = f2h(h2f(V1.s[k]) * wj);
      }
      *(uint4*)((char*)Pb_t + SWZ(r, slot0))     = V0.v;
      *(uint4*)((char*)Pb_t + SWZ(r, slot0 + 1)) = V1.v;
    }
    __syncthreads();
#pragma unroll
    for (int iti = 0; iti < 2; ++iti) {
      if (jt == it0 + iti) {
#pragma unroll
        for (int pf = 0; pf < 4; ++pf)
#pragma unroll
          for (int rp = 0; rp < 2; ++rp) {
            int j0l = ilb + rp * 2;
            u16 a = *(const u16*)((const char*)Xh_t + SWZ(pf * 16 + mlo, j0l >> 3) + (j0l & 7) * 2);
            u16 b2 = *(const u16*)((const char*)Xh_t + SWZ(pf * 16 + mlo, (j0l + 1) >> 3) + ((j0l + 1) & 7) * 2);
            xdv[iti][pf * 2 + rp] = (u32)a | ((u32)b2 << 16);
          }
      }
    }
#pragma unroll
    for (int iti = 0; iti < 2; ++iti) {
      const int ita = it0 + iti;
      if (jt > ita) continue;
      f32x4 g[4];
#pragma unroll
      for (int i = 0; i < 4; ++i) g[i] = (f32x4){0.f, 0.f, 0.f, 0.f};
#pragma unroll
      for (int s = 0; s < 2; ++s)
#pragma unroll
        for (int jf = 0; jf < 4; ++jf) {
          f16x8 fbh = *(const f16x8*)((const char*)Pb_t + SWZ(jf * 16 + mlo, s * 4 + gg));
          g[jf] = __builtin_amdgcn_mfma_f32_16x16x32_f16(fc[iti][s], fbh, g[jf], 0, 0, 0);
        }
#pragma unroll
      for (int jf = 0; jf < 4; ++jf)
#pragma unroll
        for (int reg = 0; reg < 4; ++reg) {
          int il = ita * 64 + ilb + reg;
          int jl = jt * 64 + jf * 16 + mlo;
          float av = (jl <= il) ? g[jf][reg] * __expf(dAc_s[il] - dAc_s[jl]) : 0.f;
          *(u16*)((char*)att_t + SWZ(il & 63, (jl & 63) >> 3) + (jl & 7) * 2) = f2h(av);
        }
#pragma unroll
      for (int s = 0; s < 2; ++s) {
        f16x8 fa = *(const f16x8*)((const char*)att_t + SWZ(w * 16 + mlo, s * 4 + gg));
#pragma unroll
        for (int pf = 0; pf < 4; ++pf) {
          f16x8 fxh = *(const f16x8*)((const char*)Xh_t + SWZ(pf * 16 + mlo, s * 4 + gg));
          accy[iti][pf] = __builtin_amdgcn_mfma_f32_16x16x32_f16(fa, fxh, accy[iti][pf], 0, 0, 0);
        }
      }
    }
  }
  const float Dh = Dp[hh];
#pragma unroll
  for (int iti = 0; iti < 2; ++iti)
#pragma unroll
    for (int pf = 0; pf < 4; ++pf)
#pragma unroll
      for (int reg = 0; reg < 4; ++reg) {
        size_t row = base + (it0 + iti) * 64 + ilb + reg;
        int col = hh * HD + pf * 16 + mlo;
        u32 pk = xdv[iti][pf * 2 + (reg >> 1)];
        u16 xv = (reg & 1) ? (u16)(pk >> 16) : (u16)pk;
        y[row * DI + col] = f2h(accy[iti][pf][reg] + Dh * h2f(xv));
      }
}

// ---------------- K8: LayerNorm * z (both fp16 in) -> fp16 hi/lo pair ----------------
__global__ __launch_bounds__(256) void k_norm(
    const u16* __restrict__ z, const float* __restrict__ nw,
    const float* __restrict__ nb, const u16* __restrict__ y,
    u16* __restrict__ yh, u16* __restrict__ yl)
{
  __shared__ float rs[4], rq[4];
  const size_t row = blockIdx.x;
  const int t = threadIdx.x;
  float v[3];
  float s = 0.f, sq = 0.f;
#pragma unroll
  for (int r = 0; r < 3; ++r) {
    v[r] = h2f(y[row * DI + r * 256 + t]);
    s += v[r];
    sq = fmaf(v[r], v[r], sq);
  }
#pragma unroll
  for (int off = 32; off > 0; off >>= 1) {
    s  += __shfl_down(s, off, 64);
    sq += __shfl_down(sq, off, 64);
  }
  const int wid = t >> 6, lane = t & 63;
  if (lane == 0) { rs[wid] = s; rq[wid] = sq; }
  __syncthreads();
  if (t == 0) {
    rs[0] = rs[0] + rs[1] + rs[2] + rs[3];
    rq[0] = rq[0] + rq[1] + rq[2] + rq[3];
  }
  __syncthreads();
  const float mu   = rs[0] * (1.f / DI);
  const float var  = rq[0] * (1.f / DI) - mu * mu;
  const float rstd = 1.f / sqrtf(var + EPS_);
#pragma unroll
  for (int r = 0; r < 3; ++r) {
    int d = r * 256 + t;
    float o = (v[r] - mu) * rstd * nw[d] + nb[d];
    float p = o * h2f(z[row * DI + d]);
    u16 h, l;
    hsplit(p, h, l);
    yh[row * DI + d] = h;
    yl[row * DI + d] = l;
  }
}

extern "C" void kernel_launch(void* const* d_in, const int* in_sizes, int n_in,
                              void* d_out, int out_size, void* d_ws, size_t ws_size,
                              hipStream_t stream)
{
  const float* u    = (const float*)d_in[0];
  const float* ipw  = (const float*)d_in[1];
  const float* cw   = (const float*)d_in[2];
  const float* cb   = (const float*)d_in[3];
  const float* dtb  = (const float*)d_in[4];
  const float* Alog = (const float*)d_in[5];
  const float* Dp   = (const float*)d_in[6];
  const float* nw   = (const float*)d_in[7];
  const float* nb   = (const float*)d_in[8];
  const float* opw  = (const float*)d_in[9];
  float* out = (float*)d_out;

  float* ws = (float*)d_ws;
  size_t off = 0;
  u16*   z16     = (u16*)(ws + off); off += (size_t)B_ * L_ * DI / 2;
  u16*   xBC16   = (u16*)(ws + off); off += (size_t)B_ * L_ * CONVD / 2;
  float* dt_buf  = ws + off; off += (size_t)B_ * L_ * NH;
  float* x_buf   = ws + off; off += (size_t)B_ * L_ * DI;     // alias space only
  u16*   y16     = (u16*)(ws + off); off += (size_t)B_ * L_ * DI / 2;
  u16*   Bh_buf  = (u16*)(ws + off); off += (size_t)B_ * L_ * DS / 2;
  u16*   Ch_buf  = (u16*)(ws + off); off += (size_t)B_ * L_ * DS / 2;
  float* dAcs    = ws + off; off += (size_t)B_ * L_ * NH;
  float* cdec    = ws + off; off += (size_t)B_ * NCH * NH;
  float* st_buf  = ws + off; off += (size_t)B_ * NCH * NH * HD * DS;
  float* pv_buf  = ws + off; off += (size_t)B_ * NCH * NH * HD * DS;
  u16*   Woh     = (u16*)(ws + off); off += (size_t)DM * DI / 2;
  u16*   XTh_buf = (u16*)(ws + off); off += (size_t)B_ * NCH * NH * 4 * 4096 / 2;

  // aliases inside x_buf (dead/live windows don't overlap)
  u16* Ah = (u16*)x_buf;                         // consumed by gemm1
  u16* Whip = Ah + (size_t)B_ * L_ * DM;
  u16* yh = (u16*)x_buf;                         // written by k_norm (after gemm1)
  u16* yl = yh + (size_t)B_ * L_ * DI;

  hipLaunchKernelGGL(k_cvtA, dim3(8, 12, 16), dim3(256), 0, stream, u, Ah);
  hipLaunchKernelGGL(k_cvtWh, dim3((NIP * DM / 4 + 255) / 256), dim3(256), 0, stream,
                     ipw, Whip, NIP * DM / 4);
  hipLaunchKernelGGL(k_cvtWh, dim3((DM * DI / 4 + 255) / 256), dim3(256), 0, stream,
                     opw, Woh, DM * DI / 4);
  hipLaunchKernelGGL(k_dtp, dim3(64, 12), dim3(256), 0, stream,
                     u, ipw, dtb, Alog, dt_buf, dAcs, cdec);
  hipLaunchKernelGGL(k_gemm1, dim3(128, 13), dim3(256), 0, stream,
                     Ah, Whip, z16, xBC16);
  hipLaunchKernelGGL(k_conv, dim3(56, 2, 16), dim3(256), 0, stream,
                     xBC16, cw, cb, XTh_buf, Bh_buf, Ch_buf);
  hipLaunchKernelGGL(k_states, dim3(64, 12), dim3(256), 0, stream,
                     XTh_buf, Bh_buf, dt_buf, dAcs, st_buf);
  hipLaunchKernelGGL(k_scanc, dim3(3072), dim3(256), 0, stream, st_buf, cdec, pv_buf);
  hipLaunchKernelGGL(k_y, dim3(64, 12, 2), dim3(256), 0, stream,
                     XTh_buf, Ch_buf, Bh_buf, dt_buf, dAcs, pv_buf, Dp, y16);
  hipLaunchKernelGGL(k_norm, dim3(16384), dim3(256), 0, stream, z16, nw, nb, y16, yh, yl);
  hipLaunchKernelGGL(k_gemm2, dim3(128, 3), dim3(256), 0, stream, yh, yl, Woh, out);
}